// Round 1
// baseline (3997.807 us; speedup 1.0000x reference)
//
#include <hip/hip_runtime.h>

#define NN 50000
#define NE 800000
#define D 64
#define LNEPS 1e-5f

// agg[dst] += relu(x[src] + e)   (layer-0 aggregation)
__global__ __launch_bounds__(256) void scatter_kernel(
    const float* __restrict__ x, const float* __restrict__ e,
    const int* __restrict__ src, const int* __restrict__ dst,
    float* __restrict__ agg) {
  int tid = blockIdx.x * blockDim.x + threadIdx.x;  // NE*16 threads
  if (tid >= NE * 16) return;
  int eid = tid >> 4, q = tid & 15;
  int s = src[eid], d = dst[eid];
  float4 xv = ((const float4*)(x + (size_t)s * D))[q];
  float4 ev = ((const float4*)(e + (size_t)eid * D))[q];
  float* a = agg + (size_t)d * D + q * 4;
  atomicAdd(a + 0, fmaxf(xv.x + ev.x, 0.f));
  atomicAdd(a + 1, fmaxf(xv.y + ev.y, 0.f));
  atomicAdd(a + 2, fmaxf(xv.z + ev.z, 0.f));
  atomicAdd(a + 3, fmaxf(xv.w + ev.w, 0.f));
}

// x_out = relu(LN( relu((x+agg)@w1+b1)@w2+b2 ))
__global__ __launch_bounds__(256) void node_mlp_kernel(
    const float* __restrict__ x, const float* __restrict__ agg,
    const float* __restrict__ w1, const float* __restrict__ b1,
    const float* __restrict__ w2, const float* __restrict__ b2,
    const float* __restrict__ g, const float* __restrict__ bln,
    float* __restrict__ xo) {
  int nid = blockIdx.x * blockDim.x + threadIdx.x;
  if (nid >= NN) return;
  const float* xr = x + (size_t)nid * D;
  const float* ar = agg + (size_t)nid * D;

  float h[D];
#pragma unroll
  for (int j = 0; j < D; ++j) h[j] = b1[j];
  for (int k = 0; k < D; ++k) {
    float v = xr[k] + ar[k];
    const float* w = w1 + k * D;
#pragma unroll
    for (int j = 0; j < D; ++j) h[j] = fmaf(v, w[j], h[j]);
  }
  float o[D];
#pragma unroll
  for (int j = 0; j < D; ++j) o[j] = b2[j];
  for (int k = 0; k < D; ++k) {
    float v = fmaxf(h[k], 0.f);
    const float* w = w2 + k * D;
#pragma unroll
    for (int j = 0; j < D; ++j) o[j] = fmaf(v, w[j], o[j]);
  }
  // LayerNorm (biased var) + affine + relu
  float mu = 0.f;
#pragma unroll
  for (int j = 0; j < D; ++j) mu += o[j];
  mu *= (1.f / D);
  float var = 0.f;
#pragma unroll
  for (int j = 0; j < D; ++j) { float dd = o[j] - mu; var = fmaf(dd, dd, var); }
  var *= (1.f / D);
  float rs = rsqrtf(var + LNEPS);
  float* xw = xo + (size_t)nid * D;
#pragma unroll
  for (int j = 0; j < D; ++j)
    xw[j] = fmaxf(fmaf((o[j] - mu) * rs, g[j], bln[j]), 0.f);
}

// fused: e1 = e + 0.5*MLP(cat[x[src],x[dst],e]);  agg[dst] += relu(x[src]+e1)
// (e1 is never stored -- its only consumer is the layer-1 aggregation)
__global__ __launch_bounds__(256) void edge_mlp_scatter_kernel(
    const float* __restrict__ x, const float* __restrict__ e,
    const int* __restrict__ src, const int* __restrict__ dst,
    const float* __restrict__ w1, const float* __restrict__ b1,
    const float* __restrict__ w2, const float* __restrict__ b2,
    float* __restrict__ agg) {
  int eid = blockIdx.x * blockDim.x + threadIdx.x;
  if (eid >= NE) return;
  int s = src[eid], d = dst[eid];
  const float* xs = x + (size_t)s * D;
  const float* xd = x + (size_t)d * D;
  const float* er = e + (size_t)eid * D;

  float hid[D];
#pragma unroll
  for (int j = 0; j < D; ++j) hid[j] = b1[j];
  for (int k = 0; k < D; ++k) {
    float v = xs[k];
    const float* w = w1 + k * D;
#pragma unroll
    for (int j = 0; j < D; ++j) hid[j] = fmaf(v, w[j], hid[j]);
  }
  for (int k = 0; k < D; ++k) {
    float v = xd[k];
    const float* w = w1 + (D + k) * D;
#pragma unroll
    for (int j = 0; j < D; ++j) hid[j] = fmaf(v, w[j], hid[j]);
  }
  for (int k = 0; k < D; ++k) {
    float v = er[k];
    const float* w = w1 + (2 * D + k) * D;
#pragma unroll
    for (int j = 0; j < D; ++j) hid[j] = fmaf(v, w[j], hid[j]);
  }
  float o[D];
#pragma unroll
  for (int j = 0; j < D; ++j) o[j] = b2[j];
  for (int k = 0; k < D; ++k) {
    float v = fmaxf(hid[k], 0.f);
    const float* w = w2 + k * D;
#pragma unroll
    for (int j = 0; j < D; ++j) o[j] = fmaf(v, w[j], o[j]);
  }
  float* a = agg + (size_t)d * D;
#pragma unroll
  for (int j = 0; j < D; ++j) {
    float e1 = fmaf(0.5f, o[j], er[j]);
    float m = fmaxf(xs[j] + e1, 0.f);
    atomicAdd(a + j, m);
  }
}

// out = x @ head_w + head_b   (D x 2)
__global__ __launch_bounds__(256) void head_kernel(
    const float* __restrict__ x, const float* __restrict__ w,
    const float* __restrict__ b, float* __restrict__ out) {
  int nid = blockIdx.x * blockDim.x + threadIdx.x;
  if (nid >= NN) return;
  const float* xr = x + (size_t)nid * D;
  float a0 = b[0], a1 = b[1];
  for (int k = 0; k < D; ++k) {
    float v = xr[k];
    a0 = fmaf(v, w[k * 2 + 0], a0);
    a1 = fmaf(v, w[k * 2 + 1], a1);
  }
  out[nid * 2 + 0] = a0;
  out[nid * 2 + 1] = a1;
}

extern "C" void kernel_launch(void* const* d_in, const int* in_sizes, int n_in,
                              void* d_out, int out_size, void* d_ws, size_t ws_size,
                              hipStream_t stream) {
  const float* x0  = (const float*)d_in[0];
  const float* e0  = (const float*)d_in[1];
  const int*   ei  = (const int*)d_in[2];
  const float* gw1 = (const float*)d_in[3];
  const float* gb1 = (const float*)d_in[4];
  const float* gw2 = (const float*)d_in[5];
  const float* gb2 = (const float*)d_in[6];
  const float* ew1 = (const float*)d_in[7];
  const float* eb1 = (const float*)d_in[8];
  const float* ew2 = (const float*)d_in[9];
  const float* eb2 = (const float*)d_in[10];
  const float* lng = (const float*)d_in[11];
  const float* lnb = (const float*)d_in[12];
  const float* hw  = (const float*)d_in[13];
  const float* hb  = (const float*)d_in[14];
  float* out = (float*)d_out;

  float* x1  = (float*)d_ws;            // NN*D
  float* x2  = x1 + (size_t)NN * D;     // NN*D
  float* agg = x2 + (size_t)NN * D;     // NN*D

  const int* src = ei;
  const int* dst = ei + NE;

  // ---- layer 0 ----
  hipMemsetAsync(agg, 0, (size_t)NN * D * sizeof(float), stream);
  scatter_kernel<<<(NE * 16 + 255) / 256, 256, 0, stream>>>(x0, e0, src, dst, agg);
  node_mlp_kernel<<<(NN + 255) / 256, 256, 0, stream>>>(
      x0, agg, gw1, gb1, gw2, gb2, lng, lnb, x1);

  // ---- layer 0 edge update fused with layer 1 aggregation ----
  hipMemsetAsync(agg, 0, (size_t)NN * D * sizeof(float), stream);
  edge_mlp_scatter_kernel<<<(NE + 255) / 256, 256, 0, stream>>>(
      x1, e0, src, dst, ew1, eb1, ew2, eb2, agg);

  // ---- layer 1 node update (layer-1 edge update is dead code: skipped) ----
  node_mlp_kernel<<<(NN + 255) / 256, 256, 0, stream>>>(
      x1, agg, gw1 + D * D, gb1 + D, gw2 + D * D, gb2 + D, lng + D, lnb + D, x2);

  // ---- head ----
  head_kernel<<<(NN + 255) / 256, 256, 0, stream>>>(x2, hw, hb, out);
}

// Round 2
// 1631.115 us; speedup vs baseline: 2.4510x; 2.4510x over previous
//
#include <hip/hip_runtime.h>

#define NN 50000
#define NE 800000
#define D 64
#define K3 (3 * D)
#define LNEPS 1e-5f
#define STR 68  // LDS row stride in floats: multiple of 4 (keeps ds_read_b128 aligned)

// a_m accumulates row t0+m (j0..j0+3); v = IN[k][t0..t0+3]; w = W[k][j0..j0+3]
#define FMA4x4(v, w)                                                  \
  a0.x = fmaf(v.x, w.x, a0.x); a0.y = fmaf(v.x, w.y, a0.y);           \
  a0.z = fmaf(v.x, w.z, a0.z); a0.w = fmaf(v.x, w.w, a0.w);           \
  a1.x = fmaf(v.y, w.x, a1.x); a1.y = fmaf(v.y, w.y, a1.y);           \
  a1.z = fmaf(v.y, w.z, a1.z); a1.w = fmaf(v.y, w.w, a1.w);           \
  a2.x = fmaf(v.z, w.x, a2.x); a2.y = fmaf(v.z, w.y, a2.y);           \
  a2.z = fmaf(v.z, w.z, a2.z); a2.w = fmaf(v.z, w.w, a2.w);           \
  a3.x = fmaf(v.w, w.x, a3.x); a3.y = fmaf(v.w, w.y, a3.y);           \
  a3.z = fmaf(v.w, w.z, a3.z); a3.w = fmaf(v.w, w.w, a3.w);

// store relu(acc) transposed into buf[k2][t] (k2 = j of this GEMM)
#define HSTORE_RELU(buf)                                              \
  buf[(j0+0)*STR + t0+0] = fmaxf(a0.x, 0.f);                          \
  buf[(j0+1)*STR + t0+0] = fmaxf(a0.y, 0.f);                          \
  buf[(j0+2)*STR + t0+0] = fmaxf(a0.z, 0.f);                          \
  buf[(j0+3)*STR + t0+0] = fmaxf(a0.w, 0.f);                          \
  buf[(j0+0)*STR + t0+1] = fmaxf(a1.x, 0.f);                          \
  buf[(j0+1)*STR + t0+1] = fmaxf(a1.y, 0.f);                          \
  buf[(j0+2)*STR + t0+1] = fmaxf(a1.z, 0.f);                          \
  buf[(j0+3)*STR + t0+1] = fmaxf(a1.w, 0.f);                          \
  buf[(j0+0)*STR + t0+2] = fmaxf(a2.x, 0.f);                          \
  buf[(j0+1)*STR + t0+2] = fmaxf(a2.y, 0.f);                          \
  buf[(j0+2)*STR + t0+2] = fmaxf(a2.z, 0.f);                          \
  buf[(j0+3)*STR + t0+2] = fmaxf(a2.w, 0.f);                          \
  buf[(j0+0)*STR + t0+3] = fmaxf(a3.x, 0.f);                          \
  buf[(j0+1)*STR + t0+3] = fmaxf(a3.y, 0.f);                          \
  buf[(j0+2)*STR + t0+3] = fmaxf(a3.z, 0.f);                          \
  buf[(j0+3)*STR + t0+3] = fmaxf(a3.w, 0.f);

// ---------------- layer-0 aggregation: agg[dst] += relu(x[src] + e) ----------------
__global__ __launch_bounds__(256) void scatter_kernel(
    const float* __restrict__ x, const float* __restrict__ e,
    const int* __restrict__ src, const int* __restrict__ dst,
    float* __restrict__ agg) {
  int tid = blockIdx.x * blockDim.x + threadIdx.x;  // NE*16 threads
  if (tid >= NE * 16) return;
  int eid = tid >> 4, q = tid & 15;
  int s = src[eid], d = dst[eid];
  float4 xv = ((const float4*)(x + (size_t)s * D))[q];
  float4 ev = ((const float4*)(e + (size_t)eid * D))[q];
  float* a = agg + (size_t)d * D + q * 4;
  atomicAdd(a + 0, fmaxf(xv.x + ev.x, 0.f));
  atomicAdd(a + 1, fmaxf(xv.y + ev.y, 0.f));
  atomicAdd(a + 2, fmaxf(xv.z + ev.z, 0.f));
  atomicAdd(a + 3, fmaxf(xv.w + ev.w, 0.f));
}

// ---------------- tiled node MLP: xo = relu(LN(relu((x+agg)@w1+b1)@w2+b2)) ----------------
// block = 64 nodes, 256 threads, 4x4 register blocking. No per-thread arrays.
__global__ __launch_bounds__(256) void node_mlp_kernel(
    const float* __restrict__ x, const float* __restrict__ agg,
    const float* __restrict__ w1, const float* __restrict__ b1,
    const float* __restrict__ w2, const float* __restrict__ b2,
    const float* __restrict__ g, const float* __restrict__ bln,
    float* __restrict__ xo) {
  __shared__ float sIN[D * STR];   // IN[k][t]
  __shared__ float sH[D * STR];    // H[k2][t], later reused as O[t][j]
  __shared__ float sPS[256], sPQ[256], sMu[64], sRs[64];

  const int tid = threadIdx.x;
  const int n0 = blockIdx.x * 64;

  // ---- stage: IN[k][t] = x[n0+t][k] + agg[n0+t][k]
  {
    const int t = tid & 63, p = tid >> 6;
    int node = n0 + t;
    int cn = node < NN ? node : 0;
    const float* xr = x + (size_t)cn * D + p * 16;
    const float* ar = agg + (size_t)cn * D + p * 16;
#pragma unroll
    for (int i = 0; i < 4; ++i) {
      float4 xv = ((const float4*)xr)[i];
      float4 av = ((const float4*)ar)[i];
      int k = p * 16 + i * 4;
      sIN[(k + 0) * STR + t] = xv.x + av.x;
      sIN[(k + 1) * STR + t] = xv.y + av.y;
      sIN[(k + 2) * STR + t] = xv.z + av.z;
      sIN[(k + 3) * STR + t] = xv.w + av.w;
    }
  }
  __syncthreads();

  const int tj = tid & 15, tt = tid >> 4;
  const int j0 = tj * 4, t0 = tt * 4;
  float4 a0, a1, a2, a3;

  // ---- GEMM1 (K=64): h = IN^T @ w1 + b1, relu -> sH transposed
  {
    float4 bv = *(const float4*)(b1 + j0);
    a0 = a1 = a2 = a3 = bv;
    for (int k = 0; k < D; ++k) {
      float4 w = *(const float4*)(w1 + k * D + j0);
      float4 v = *(const float4*)&sIN[k * STR + t0];
      FMA4x4(v, w)
    }
  }
  HSTORE_RELU(sH)
  __syncthreads();

  // ---- GEMM2 (K=64): o = H^T @ w2 + b2
  {
    float4 bv = *(const float4*)(b2 + j0);
    a0 = a1 = a2 = a3 = bv;
    for (int k = 0; k < D; ++k) {
      float4 w = *(const float4*)(w2 + k * D + j0);
      float4 v = *(const float4*)&sH[k * STR + t0];
      FMA4x4(v, w)
    }
  }
  __syncthreads();  // all GEMM2 reads of sH done before overwrite
  // store O[t][j] (pre-LN) into sH
  *(float4*)&sH[(t0 + 0) * STR + j0] = a0;
  *(float4*)&sH[(t0 + 1) * STR + j0] = a1;
  *(float4*)&sH[(t0 + 2) * STR + j0] = a2;
  *(float4*)&sH[(t0 + 3) * STR + j0] = a3;
  __syncthreads();

  // ---- LayerNorm stats (biased var) per node
  {
    const int t = tid & 63, p = tid >> 6;
    const float* r = &sH[t * STR + p * 16];
    float s = 0.f, q = 0.f;
#pragma unroll
    for (int i = 0; i < 16; ++i) { float v = r[i]; s += v; q = fmaf(v, v, q); }
    sPS[p * 64 + t] = s;
    sPQ[p * 64 + t] = q;
  }
  __syncthreads();
  if (tid < 64) {
    float s = sPS[tid] + sPS[64 + tid] + sPS[128 + tid] + sPS[192 + tid];
    float q = sPQ[tid] + sPQ[64 + tid] + sPQ[128 + tid] + sPQ[192 + tid];
    float mu = s * (1.f / 64.f);
    float var = q * (1.f / 64.f) - mu * mu;
    sMu[tid] = mu;
    sRs[tid] = rsqrtf(var + LNEPS);
  }
  __syncthreads();

  // ---- affine + relu + store
  {
    const int t = tid >> 2, c = (tid & 3) * 16;
    int node = n0 + t;
    if (node < NN) {
      float mu = sMu[t], rs = sRs[t];
      float* o = xo + (size_t)node * D + c;
#pragma unroll
      for (int i = 0; i < 4; ++i) {
        float4 v = *(const float4*)&sH[t * STR + c + i * 4];
        float4 gv = *(const float4*)(g + c + i * 4);
        float4 bv = *(const float4*)(bln + c + i * 4);
        float4 r;
        r.x = fmaxf(fmaf((v.x - mu) * rs, gv.x, bv.x), 0.f);
        r.y = fmaxf(fmaf((v.y - mu) * rs, gv.y, bv.y), 0.f);
        r.z = fmaxf(fmaf((v.z - mu) * rs, gv.z, bv.z), 0.f);
        r.w = fmaxf(fmaf((v.w - mu) * rs, gv.w, bv.w), 0.f);
        ((float4*)o)[i] = r;
      }
    }
  }
}

// ---------------- tiled fused edge MLP + layer-1 aggregation ----------------
// e1 = e + 0.5*MLP(cat[x[src],x[dst],e]);  agg[dst] += relu(x[src]+e1). e1 never stored.
__global__ __launch_bounds__(256) void edge_mlp_scatter_kernel(
    const float* __restrict__ x, const float* __restrict__ e,
    const int* __restrict__ src, const int* __restrict__ dst,
    const float* __restrict__ w1, const float* __restrict__ b1,
    const float* __restrict__ w2, const float* __restrict__ b2,
    float* __restrict__ agg) {
  __shared__ float sIN[K3 * STR];  // 52224 B: cat inputs transposed [k][t]
  __shared__ float sH[D * STR];    // 17408 B: hidden transposed [k2][t]

  const int tid = threadIdx.x;
  const int e0 = blockIdx.x * 64;

  // ---- stage cat[x[src], x[dst], e] transposed
  {
    const int t = tid & 63, p = tid >> 6;
    int eid = e0 + t;
    int sN = src[eid], dN = dst[eid];
    const float* base0 = x + (size_t)sN * D + p * 16;
    const float* base1 = x + (size_t)dN * D + p * 16;
    const float* base2 = e + (size_t)eid * D + p * 16;
#pragma unroll
    for (int i = 0; i < 4; ++i) {
      int k = p * 16 + i * 4;
      float4 v0 = ((const float4*)base0)[i];
      sIN[(k + 0) * STR + t] = v0.x; sIN[(k + 1) * STR + t] = v0.y;
      sIN[(k + 2) * STR + t] = v0.z; sIN[(k + 3) * STR + t] = v0.w;
      float4 v1 = ((const float4*)base1)[i];
      sIN[(64 + k + 0) * STR + t] = v1.x; sIN[(64 + k + 1) * STR + t] = v1.y;
      sIN[(64 + k + 2) * STR + t] = v1.z; sIN[(64 + k + 3) * STR + t] = v1.w;
      float4 v2 = ((const float4*)base2)[i];
      sIN[(128 + k + 0) * STR + t] = v2.x; sIN[(128 + k + 1) * STR + t] = v2.y;
      sIN[(128 + k + 2) * STR + t] = v2.z; sIN[(128 + k + 3) * STR + t] = v2.w;
    }
  }
  __syncthreads();

  const int tj = tid & 15, tt = tid >> 4;
  const int j0 = tj * 4, t0 = tt * 4;
  float4 a0, a1, a2, a3;

  // ---- GEMM1 (K=192)
  {
    float4 bv = *(const float4*)(b1 + j0);
    a0 = a1 = a2 = a3 = bv;
    for (int k = 0; k < K3; ++k) {
      float4 w = *(const float4*)(w1 + k * D + j0);
      float4 v = *(const float4*)&sIN[k * STR + t0];
      FMA4x4(v, w)
    }
  }
  HSTORE_RELU(sH)
  __syncthreads();

  // ---- GEMM2 (K=64)
  {
    float4 bv = *(const float4*)(b2 + j0);
    a0 = a1 = a2 = a3 = bv;
    for (int k = 0; k < D; ++k) {
      float4 w = *(const float4*)(w2 + k * D + j0);
      float4 v = *(const float4*)&sH[k * STR + t0];
      FMA4x4(v, w)
    }
  }

  // ---- epilogue: msg = relu(x[src] + e + 0.5*o); atomicAdd into agg[dst]
#pragma unroll
  for (int m = 0; m < 4; ++m) {
    int t = t0 + m;
    int eid = e0 + t;
    int dN = dst[eid];
    float4 ev = *(const float4*)(e + (size_t)eid * D + j0);
    float4 o = (m == 0) ? a0 : (m == 1) ? a1 : (m == 2) ? a2 : a3;
    float xs0 = sIN[(j0 + 0) * STR + t];
    float xs1 = sIN[(j0 + 1) * STR + t];
    float xs2 = sIN[(j0 + 2) * STR + t];
    float xs3 = sIN[(j0 + 3) * STR + t];
    float* a = agg + (size_t)dN * D + j0;
    atomicAdd(a + 0, fmaxf(xs0 + fmaf(0.5f, o.x, ev.x), 0.f));
    atomicAdd(a + 1, fmaxf(xs1 + fmaf(0.5f, o.y, ev.y), 0.f));
    atomicAdd(a + 2, fmaxf(xs2 + fmaf(0.5f, o.z, ev.z), 0.f));
    atomicAdd(a + 3, fmaxf(xs3 + fmaf(0.5f, o.w, ev.w), 0.f));
  }
}

// ---------------- head: out = x @ head_w + head_b ----------------
__global__ __launch_bounds__(256) void head_kernel(
    const float* __restrict__ x, const float* __restrict__ w,
    const float* __restrict__ b, float* __restrict__ out) {
  int nid = blockIdx.x * blockDim.x + threadIdx.x;
  if (nid >= NN) return;
  const float* xr = x + (size_t)nid * D;
  float a0 = b[0], a1 = b[1];
  for (int k = 0; k < D; ++k) {
    float v = xr[k];
    a0 = fmaf(v, w[k * 2 + 0], a0);
    a1 = fmaf(v, w[k * 2 + 1], a1);
  }
  out[nid * 2 + 0] = a0;
  out[nid * 2 + 1] = a1;
}

extern "C" void kernel_launch(void* const* d_in, const int* in_sizes, int n_in,
                              void* d_out, int out_size, void* d_ws, size_t ws_size,
                              hipStream_t stream) {
  const float* x0  = (const float*)d_in[0];
  const float* e0  = (const float*)d_in[1];
  const int*   ei  = (const int*)d_in[2];
  const float* gw1 = (const float*)d_in[3];
  const float* gb1 = (const float*)d_in[4];
  const float* gw2 = (const float*)d_in[5];
  const float* gb2 = (const float*)d_in[6];
  const float* ew1 = (const float*)d_in[7];
  const float* eb1 = (const float*)d_in[8];
  const float* ew2 = (const float*)d_in[9];
  const float* eb2 = (const float*)d_in[10];
  const float* lng = (const float*)d_in[11];
  const float* lnb = (const float*)d_in[12];
  const float* hw  = (const float*)d_in[13];
  const float* hb  = (const float*)d_in[14];
  float* out = (float*)d_out;

  float* x1  = (float*)d_ws;          // NN*D
  float* x2  = x1 + (size_t)NN * D;   // NN*D
  float* agg = x2 + (size_t)NN * D;   // NN*D

  const int* src = ei;
  const int* dst = ei + NE;

  const int nodeBlocks = (NN + 63) / 64;   // 782
  const int edgeBlocks = NE / 64;          // 12500

  // ---- layer 0 ----
  hipMemsetAsync(agg, 0, (size_t)NN * D * sizeof(float), stream);
  scatter_kernel<<<(NE * 16 + 255) / 256, 256, 0, stream>>>(x0, e0, src, dst, agg);
  node_mlp_kernel<<<nodeBlocks, 256, 0, stream>>>(
      x0, agg, gw1, gb1, gw2, gb2, lng, lnb, x1);

  // ---- layer-0 edge update fused with layer-1 aggregation ----
  hipMemsetAsync(agg, 0, (size_t)NN * D * sizeof(float), stream);
  edge_mlp_scatter_kernel<<<edgeBlocks, 256, 0, stream>>>(
      x1, e0, src, dst, ew1, eb1, ew2, eb2, agg);

  // ---- layer 1 node update (layer-1 edge update is dead code) ----
  node_mlp_kernel<<<nodeBlocks, 256, 0, stream>>>(
      x1, agg, gw1 + D * D, gb1 + D, gw2 + D * D, gb2 + D, lng + D, lnb + D, x2);

  // ---- head ----
  head_kernel<<<(NN + 255) / 256, 256, 0, stream>>>(x2, hw, hb, out);
}

// Round 3
// 1001.358 us; speedup vs baseline: 3.9924x; 1.6289x over previous
//
#include <hip/hip_runtime.h>

#define NN 50000
#define NE 800000
#define D 64
#define K3 (3 * D)
#define LNEPS 1e-5f
#define STR 68    // f32 LDS row stride (node kernel)
#define SINB 200  // bf16 LDS row stride, edge input tile (400 B = 25 x 16B)
#define SHB 72    // bf16 LDS row stride, edge hidden tile (144 B = 9 x 16B)

typedef __attribute__((ext_vector_type(8))) short bf16x8;
typedef __attribute__((ext_vector_type(4))) float f32x4;

__device__ __forceinline__ unsigned short f2bf(float f) {
  unsigned u = __float_as_uint(f);
  u += 0x7FFF + ((u >> 16) & 1);  // RNE
  return (unsigned short)(u >> 16);
}

// a_m accumulates row t0+m (j0..j0+3); v = IN[k][t0..t0+3]; w = W[k][j0..j0+3]
#define FMA4x4(v, w)                                                  \
  a0.x = fmaf(v.x, w.x, a0.x); a0.y = fmaf(v.x, w.y, a0.y);           \
  a0.z = fmaf(v.x, w.z, a0.z); a0.w = fmaf(v.x, w.w, a0.w);           \
  a1.x = fmaf(v.y, w.x, a1.x); a1.y = fmaf(v.y, w.y, a1.y);           \
  a1.z = fmaf(v.y, w.z, a1.z); a1.w = fmaf(v.y, w.w, a1.w);           \
  a2.x = fmaf(v.z, w.x, a2.x); a2.y = fmaf(v.z, w.y, a2.y);           \
  a2.z = fmaf(v.z, w.z, a2.z); a2.w = fmaf(v.z, w.w, a2.w);           \
  a3.x = fmaf(v.w, w.x, a3.x); a3.y = fmaf(v.w, w.y, a3.y);           \
  a3.z = fmaf(v.w, w.z, a3.z); a3.w = fmaf(v.w, w.w, a3.w);

#define HSTORE_RELU(buf)                                              \
  buf[(j0+0)*STR + t0+0] = fmaxf(a0.x, 0.f);                          \
  buf[(j0+1)*STR + t0+0] = fmaxf(a0.y, 0.f);                          \
  buf[(j0+2)*STR + t0+0] = fmaxf(a0.z, 0.f);                          \
  buf[(j0+3)*STR + t0+0] = fmaxf(a0.w, 0.f);                          \
  buf[(j0+0)*STR + t0+1] = fmaxf(a1.x, 0.f);                          \
  buf[(j0+1)*STR + t0+1] = fmaxf(a1.y, 0.f);                          \
  buf[(j0+2)*STR + t0+1] = fmaxf(a1.z, 0.f);                          \
  buf[(j0+3)*STR + t0+1] = fmaxf(a1.w, 0.f);                          \
  buf[(j0+0)*STR + t0+2] = fmaxf(a2.x, 0.f);                          \
  buf[(j0+1)*STR + t0+2] = fmaxf(a2.y, 0.f);                          \
  buf[(j0+2)*STR + t0+2] = fmaxf(a2.z, 0.f);                          \
  buf[(j0+3)*STR + t0+2] = fmaxf(a2.w, 0.f);                          \
  buf[(j0+0)*STR + t0+3] = fmaxf(a3.x, 0.f);                          \
  buf[(j0+1)*STR + t0+3] = fmaxf(a3.y, 0.f);                          \
  buf[(j0+2)*STR + t0+3] = fmaxf(a3.z, 0.f);                          \
  buf[(j0+3)*STR + t0+3] = fmaxf(a3.w, 0.f);

// ---------------- pack edge-MLP weights into bf16 MFMA B-fragment order ----------------
// wB1[((nt*6+kk)*64 + lane)*8 + i] = bf16(w1[(kk*32 + (lane>>4)*8 + i)*64 + nt*16 + (lane&15)])
// wB2[((nt*2+kk)*64 + lane)*8 + i] = bf16(w2[(kk*32 + (lane>>4)*8 + i)*64 + nt*16 + (lane&15)])
__global__ __launch_bounds__(256) void pack_weights_kernel(
    const float* __restrict__ w1, const float* __restrict__ w2,
    unsigned short* __restrict__ wB1, unsigned short* __restrict__ wB2) {
  int tid = blockIdx.x * 256 + threadIdx.x;  // 2048 threads
  const float* wsrc;
  unsigned short* wdst;
  int kb, j, slot;
  if (tid < 1536) {
    int nt = tid / 384, kk = (tid / 64) % 6, l = tid & 63;
    kb = kk * 32 + (l >> 4) * 8;
    j = nt * 16 + (l & 15);
    wsrc = w1; wdst = wB1; slot = tid;
  } else {
    int t = tid - 1536;
    int nt = t / 128, kk = (t / 64) & 1, l = t & 63;
    kb = kk * 32 + (l >> 4) * 8;
    j = nt * 16 + (l & 15);
    wsrc = w2; wdst = wB2; slot = t;
  }
  unsigned short b[8];
#pragma unroll
  for (int i = 0; i < 8; ++i) b[i] = f2bf(wsrc[(kb + i) * D + j]);
  uint4 v;
  v.x = (unsigned)b[0] | ((unsigned)b[1] << 16);
  v.y = (unsigned)b[2] | ((unsigned)b[3] << 16);
  v.z = (unsigned)b[4] | ((unsigned)b[5] << 16);
  v.w = (unsigned)b[6] | ((unsigned)b[7] << 16);
  *(uint4*)(wdst + (size_t)slot * 8) = v;
}

// ---------------- layer-0 aggregation: agg[dst] += relu(x[src] + e) ----------------
__global__ __launch_bounds__(256) void scatter_kernel(
    const float* __restrict__ x, const float* __restrict__ e,
    const int* __restrict__ src, const int* __restrict__ dst,
    float* __restrict__ agg) {
  int tid = blockIdx.x * blockDim.x + threadIdx.x;
  if (tid >= NE * 16) return;
  int eid = tid >> 4, q = tid & 15;
  int s = src[eid], d = dst[eid];
  float4 xv = ((const float4*)(x + (size_t)s * D))[q];
  float4 ev = ((const float4*)(e + (size_t)eid * D))[q];
  float* a = agg + (size_t)d * D + q * 4;
  atomicAdd(a + 0, fmaxf(xv.x + ev.x, 0.f));
  atomicAdd(a + 1, fmaxf(xv.y + ev.y, 0.f));
  atomicAdd(a + 2, fmaxf(xv.z + ev.z, 0.f));
  atomicAdd(a + 3, fmaxf(xv.w + ev.w, 0.f));
}

// ---------------- tiled node MLP (f32 VALU): xo = relu(LN(relu((x+agg)@w1+b1)@w2+b2)) ----------------
__global__ __launch_bounds__(256) void node_mlp_kernel(
    const float* __restrict__ x, const float* __restrict__ agg,
    const float* __restrict__ w1, const float* __restrict__ b1,
    const float* __restrict__ w2, const float* __restrict__ b2,
    const float* __restrict__ g, const float* __restrict__ bln,
    float* __restrict__ xo) {
  __shared__ float sIN[D * STR];
  __shared__ float sH[D * STR];
  __shared__ float sPS[256], sPQ[256], sMu[64], sRs[64];

  const int tid = threadIdx.x;
  const int n0 = blockIdx.x * 64;

  {
    const int t = tid & 63, p = tid >> 6;
    int node = n0 + t;
    int cn = node < NN ? node : 0;
    const float* xr = x + (size_t)cn * D + p * 16;
    const float* ar = agg + (size_t)cn * D + p * 16;
#pragma unroll
    for (int i = 0; i < 4; ++i) {
      float4 xv = ((const float4*)xr)[i];
      float4 av = ((const float4*)ar)[i];
      int k = p * 16 + i * 4;
      sIN[(k + 0) * STR + t] = xv.x + av.x;
      sIN[(k + 1) * STR + t] = xv.y + av.y;
      sIN[(k + 2) * STR + t] = xv.z + av.z;
      sIN[(k + 3) * STR + t] = xv.w + av.w;
    }
  }
  __syncthreads();

  const int tj = tid & 15, tt = tid >> 4;
  const int j0 = tj * 4, t0 = tt * 4;
  float4 a0, a1, a2, a3;

  {
    float4 bv = *(const float4*)(b1 + j0);
    a0 = a1 = a2 = a3 = bv;
    for (int k = 0; k < D; ++k) {
      float4 w = *(const float4*)(w1 + k * D + j0);
      float4 v = *(const float4*)&sIN[k * STR + t0];
      FMA4x4(v, w)
    }
  }
  HSTORE_RELU(sH)
  __syncthreads();

  {
    float4 bv = *(const float4*)(b2 + j0);
    a0 = a1 = a2 = a3 = bv;
    for (int k = 0; k < D; ++k) {
      float4 w = *(const float4*)(w2 + k * D + j0);
      float4 v = *(const float4*)&sH[k * STR + t0];
      FMA4x4(v, w)
    }
  }
  __syncthreads();
  *(float4*)&sH[(t0 + 0) * STR + j0] = a0;
  *(float4*)&sH[(t0 + 1) * STR + j0] = a1;
  *(float4*)&sH[(t0 + 2) * STR + j0] = a2;
  *(float4*)&sH[(t0 + 3) * STR + j0] = a3;
  __syncthreads();

  {
    const int t = tid & 63, p = tid >> 6;
    const float* r = &sH[t * STR + p * 16];
    float s = 0.f, q = 0.f;
#pragma unroll
    for (int i = 0; i < 16; ++i) { float v = r[i]; s += v; q = fmaf(v, v, q); }
    sPS[p * 64 + t] = s;
    sPQ[p * 64 + t] = q;
  }
  __syncthreads();
  if (tid < 64) {
    float s = sPS[tid] + sPS[64 + tid] + sPS[128 + tid] + sPS[192 + tid];
    float q = sPQ[tid] + sPQ[64 + tid] + sPQ[128 + tid] + sPQ[192 + tid];
    float mu = s * (1.f / 64.f);
    float var = q * (1.f / 64.f) - mu * mu;
    sMu[tid] = mu;
    sRs[tid] = rsqrtf(var + LNEPS);
  }
  __syncthreads();

  {
    const int t = tid >> 2, c = (tid & 3) * 16;
    int node = n0 + t;
    if (node < NN) {
      float mu = sMu[t], rs = sRs[t];
      float* o = xo + (size_t)node * D + c;
#pragma unroll
      for (int i = 0; i < 4; ++i) {
        float4 v = *(const float4*)&sH[t * STR + c + i * 4];
        float4 gv = *(const float4*)(g + c + i * 4);
        float4 bv = *(const float4*)(bln + c + i * 4);
        float4 r;
        r.x = fmaxf(fmaf((v.x - mu) * rs, gv.x, bv.x), 0.f);
        r.y = fmaxf(fmaf((v.y - mu) * rs, gv.y, bv.y), 0.f);
        r.z = fmaxf(fmaf((v.z - mu) * rs, gv.z, bv.z), 0.f);
        r.w = fmaxf(fmaf((v.w - mu) * rs, gv.w, bv.w), 0.f);
        ((float4*)o)[i] = r;
      }
    }
  }
}

// ---------------- MFMA edge MLP + fused layer-1 aggregation ----------------
// e1 = e + 0.5*MLP(cat[x[src],x[dst],e]);  agg[dst] += relu(x[src]+e1). e1 never stored.
// GEMM operands in bf16 (MFMA, f32 accum); epilogue uses f32 x/e from global.
__global__ __launch_bounds__(256) void edge_mfma_scatter_kernel(
    const float* __restrict__ x, const float* __restrict__ e,
    const int* __restrict__ src, const int* __restrict__ dst,
    const unsigned short* __restrict__ wB1, const float* __restrict__ b1,
    const unsigned short* __restrict__ wB2, const float* __restrict__ b2,
    float* __restrict__ agg) {
  __shared__ unsigned short sIN[64 * SINB];  // 25600 B: cat inputs bf16 [t][k]
  __shared__ unsigned short sH[64 * SHB];    //  9216 B: relu(h) bf16 [t][k2]

  const int tid = threadIdx.x;
  const int e0 = blockIdx.x * 64;
  const int lane = tid & 63;
  const int mt = tid >> 6;        // wave id = m-tile
  const int hl = lane >> 4;       // 0..3
  const int ll = lane & 15;

  // ---- stage cat[x[src], x[dst], e] as bf16, row-major [t][0..191]
  {
    const int t = tid & 63, p = tid >> 6;
    int eid = e0 + t;
    int sN = src[eid], dN = dst[eid];
    const float* g0 = x + (size_t)sN * D + p * 16;
    const float* g1 = x + (size_t)dN * D + p * 16;
    const float* g2 = e + (size_t)eid * D + p * 16;
    unsigned short* row = sIN + t * SINB + p * 16;
#pragma unroll
    for (int i = 0; i < 4; ++i) {
      float4 v0 = ((const float4*)g0)[i];
      float4 v1 = ((const float4*)g1)[i];
      float4 v2 = ((const float4*)g2)[i];
      uint2 u;
      u.x = (unsigned)f2bf(v0.x) | ((unsigned)f2bf(v0.y) << 16);
      u.y = (unsigned)f2bf(v0.z) | ((unsigned)f2bf(v0.w) << 16);
      *(uint2*)(row + i * 4) = u;
      u.x = (unsigned)f2bf(v1.x) | ((unsigned)f2bf(v1.y) << 16);
      u.y = (unsigned)f2bf(v1.z) | ((unsigned)f2bf(v1.w) << 16);
      *(uint2*)(row + 64 + i * 4) = u;
      u.x = (unsigned)f2bf(v2.x) | ((unsigned)f2bf(v2.y) << 16);
      u.y = (unsigned)f2bf(v2.z) | ((unsigned)f2bf(v2.w) << 16);
      *(uint2*)(row + 128 + i * 4) = u;
    }
  }
  __syncthreads();

  // ---- GEMM1: h[64 x 64] = IN[64 x 192] @ w1, bf16 MFMA 16x16x32
  f32x4 acc[4];
#pragma unroll
  for (int nt = 0; nt < 4; ++nt) {
    float b = b1[nt * 16 + ll];
    acc[nt].x = b; acc[nt].y = b; acc[nt].z = b; acc[nt].w = b;
  }
  {
    const unsigned short* aBase = sIN + (mt * 16 + ll) * SINB + hl * 8;
#pragma unroll
    for (int kk = 0; kk < 6; ++kk) {
      bf16x8 af = *(const bf16x8*)(aBase + kk * 32);
#pragma unroll
      for (int nt = 0; nt < 4; ++nt) {
        bf16x8 bf = *(const bf16x8*)(wB1 + ((size_t)(nt * 6 + kk) * 64 + lane) * 8);
        acc[nt] = __builtin_amdgcn_mfma_f32_16x16x32_bf16(af, bf, acc[nt], 0, 0, 0);
      }
    }
  }
  // relu -> bf16 -> sH[t][k2]; rows mt*16..mt*16+15 are wave-local
#pragma unroll
  for (int nt = 0; nt < 4; ++nt)
#pragma unroll
    for (int r = 0; r < 4; ++r)
      sH[(mt * 16 + hl * 4 + r) * SHB + nt * 16 + ll] = f2bf(fmaxf(acc[nt][r], 0.f));
  __syncthreads();

  // ---- GEMM2: o[64 x 64] = relu(h) @ w2
  f32x4 acc2[4];
#pragma unroll
  for (int nt = 0; nt < 4; ++nt) {
    float b = b2[nt * 16 + ll];
    acc2[nt].x = b; acc2[nt].y = b; acc2[nt].z = b; acc2[nt].w = b;
  }
  {
    const unsigned short* hBase = sH + (mt * 16 + ll) * SHB + hl * 8;
#pragma unroll
    for (int kk = 0; kk < 2; ++kk) {
      bf16x8 af = *(const bf16x8*)(hBase + kk * 32);
#pragma unroll
      for (int nt = 0; nt < 4; ++nt) {
        bf16x8 bf = *(const bf16x8*)(wB2 + ((size_t)(nt * 2 + kk) * 64 + lane) * 8);
        acc2[nt] = __builtin_amdgcn_mfma_f32_16x16x32_bf16(af, bf, acc2[nt], 0, 0, 0);
      }
    }
  }

  // ---- epilogue straight from C-layout: row t = mt*16+hl*4+r, col j = nt*16+ll
#pragma unroll
  for (int r = 0; r < 4; ++r) {
    int t = mt * 16 + hl * 4 + r;
    int eid = e0 + t;
    int sN = src[eid], dN = dst[eid];
    const float* er = e + (size_t)eid * D;
    const float* xr = x + (size_t)sN * D;
    float* ar = agg + (size_t)dN * D;
#pragma unroll
    for (int nt = 0; nt < 4; ++nt) {
      int j = nt * 16 + ll;
      float msg = fmaxf(xr[j] + fmaf(0.5f, acc2[nt][r], er[j]), 0.f);
      atomicAdd(ar + j, msg);
    }
  }
}

// ---------------- head: out = x @ head_w + head_b ----------------
__global__ __launch_bounds__(256) void head_kernel(
    const float* __restrict__ x, const float* __restrict__ w,
    const float* __restrict__ b, float* __restrict__ out) {
  int nid = blockIdx.x * blockDim.x + threadIdx.x;
  if (nid >= NN) return;
  const float* xr = x + (size_t)nid * D;
  float a0 = b[0], a1 = b[1];
  for (int k = 0; k < D; ++k) {
    float v = xr[k];
    a0 = fmaf(v, w[k * 2 + 0], a0);
    a1 = fmaf(v, w[k * 2 + 1], a1);
  }
  out[nid * 2 + 0] = a0;
  out[nid * 2 + 1] = a1;
}

extern "C" void kernel_launch(void* const* d_in, const int* in_sizes, int n_in,
                              void* d_out, int out_size, void* d_ws, size_t ws_size,
                              hipStream_t stream) {
  const float* x0  = (const float*)d_in[0];
  const float* e0  = (const float*)d_in[1];
  const int*   ei  = (const int*)d_in[2];
  const float* gw1 = (const float*)d_in[3];
  const float* gb1 = (const float*)d_in[4];
  const float* gw2 = (const float*)d_in[5];
  const float* gb2 = (const float*)d_in[6];
  const float* ew1 = (const float*)d_in[7];
  const float* eb1 = (const float*)d_in[8];
  const float* ew2 = (const float*)d_in[9];
  const float* eb2 = (const float*)d_in[10];
  const float* lng = (const float*)d_in[11];
  const float* lnb = (const float*)d_in[12];
  const float* hw  = (const float*)d_in[13];
  const float* hb  = (const float*)d_in[14];
  float* out = (float*)d_out;

  float* x1  = (float*)d_ws;          // NN*D f32
  float* x2  = x1 + (size_t)NN * D;   // NN*D f32
  float* agg = x2 + (size_t)NN * D;   // NN*D f32
  unsigned short* wB1 = (unsigned short*)(agg + (size_t)NN * D);  // 12288 bf16
  unsigned short* wB2 = wB1 + 12288;                              //  4096 bf16

  const int* src = ei;
  const int* dst = ei + NE;

  const int nodeBlocks = (NN + 63) / 64;   // 782
  const int edgeBlocks = NE / 64;          // 12500

  // ---- pack edge-MLP weights (bf16 B-fragments) ----
  pack_weights_kernel<<<8, 256, 0, stream>>>(ew1, ew2, wB1, wB2);

  // ---- layer 0 ----
  hipMemsetAsync(agg, 0, (size_t)NN * D * sizeof(float), stream);
  scatter_kernel<<<(NE * 16 + 255) / 256, 256, 0, stream>>>(x0, e0, src, dst, agg);
  node_mlp_kernel<<<nodeBlocks, 256, 0, stream>>>(
      x0, agg, gw1, gb1, gw2, gb2, lng, lnb, x1);

  // ---- layer-0 edge update fused with layer-1 aggregation (MFMA) ----
  hipMemsetAsync(agg, 0, (size_t)NN * D * sizeof(float), stream);
  edge_mfma_scatter_kernel<<<edgeBlocks, 256, 0, stream>>>(
      x1, e0, src, dst, wB1, eb1, wB2, eb2, agg);

  // ---- layer 1 node update (layer-1 edge update is dead code) ----
  node_mlp_kernel<<<nodeBlocks, 256, 0, stream>>>(
      x1, agg, gw1 + D * D, gb1 + D, gw2 + D * D, gb2 + D, lng + D, lnb + D, x2);

  // ---- head ----
  head_kernel<<<(NN + 255) / 256, 256, 0, stream>>>(x2, hw, hb, out);
}

// Round 4
// 754.235 us; speedup vs baseline: 5.3005x; 1.3276x over previous
//
#include <hip/hip_runtime.h>

#define NN 50000
#define NE 800000
#define D 64
#define K3 (3 * D)
#define LNEPS 1e-5f
#define STR 68    // f32 LDS row stride (node kernel)
#define SINB 200  // bf16 LDS row stride, edge input tile
#define SHB 72    // bf16 LDS row stride, edge hidden tile

typedef __attribute__((ext_vector_type(8))) short bf16x8;
typedef __attribute__((ext_vector_type(4))) float f32x4;

__device__ __forceinline__ unsigned short f2bf(float f) {
  unsigned u = __float_as_uint(f);
  u += 0x7FFF + ((u >> 16) & 1);  // RNE
  return (unsigned short)(u >> 16);
}

#define FMA4x4(v, w)                                                  \
  a0.x = fmaf(v.x, w.x, a0.x); a0.y = fmaf(v.x, w.y, a0.y);           \
  a0.z = fmaf(v.x, w.z, a0.z); a0.w = fmaf(v.x, w.w, a0.w);           \
  a1.x = fmaf(v.y, w.x, a1.x); a1.y = fmaf(v.y, w.y, a1.y);           \
  a1.z = fmaf(v.y, w.z, a1.z); a1.w = fmaf(v.y, w.w, a1.w);           \
  a2.x = fmaf(v.z, w.x, a2.x); a2.y = fmaf(v.z, w.y, a2.y);           \
  a2.z = fmaf(v.z, w.z, a2.z); a2.w = fmaf(v.z, w.w, a2.w);           \
  a3.x = fmaf(v.w, w.x, a3.x); a3.y = fmaf(v.w, w.y, a3.y);           \
  a3.z = fmaf(v.w, w.z, a3.z); a3.w = fmaf(v.w, w.w, a3.w);

#define HSTORE_RELU(buf)                                              \
  buf[(j0+0)*STR + t0+0] = fmaxf(a0.x, 0.f);                          \
  buf[(j0+1)*STR + t0+0] = fmaxf(a0.y, 0.f);                          \
  buf[(j0+2)*STR + t0+0] = fmaxf(a0.z, 0.f);                          \
  buf[(j0+3)*STR + t0+0] = fmaxf(a0.w, 0.f);                          \
  buf[(j0+0)*STR + t0+1] = fmaxf(a1.x, 0.f);                          \
  buf[(j0+1)*STR + t0+1] = fmaxf(a1.y, 0.f);                          \
  buf[(j0+2)*STR + t0+1] = fmaxf(a1.z, 0.f);                          \
  buf[(j0+3)*STR + t0+1] = fmaxf(a1.w, 0.f);                          \
  buf[(j0+0)*STR + t0+2] = fmaxf(a2.x, 0.f);                          \
  buf[(j0+1)*STR + t0+2] = fmaxf(a2.y, 0.f);                          \
  buf[(j0+2)*STR + t0+2] = fmaxf(a2.z, 0.f);                          \
  buf[(j0+3)*STR + t0+2] = fmaxf(a2.w, 0.f);                          \
  buf[(j0+0)*STR + t0+3] = fmaxf(a3.x, 0.f);                          \
  buf[(j0+1)*STR + t0+3] = fmaxf(a3.y, 0.f);                          \
  buf[(j0+2)*STR + t0+3] = fmaxf(a3.z, 0.f);                          \
  buf[(j0+3)*STR + t0+3] = fmaxf(a3.w, 0.f);

// ---------------- CSR build ----------------
__global__ __launch_bounds__(256) void count_kernel(
    const int* __restrict__ dst, int* __restrict__ deg) {
  int e = blockIdx.x * 256 + threadIdx.x;
  if (e < NE) atomicAdd(&deg[dst[e]], 1);
}

__global__ __launch_bounds__(1024) void scan_kernel(
    const int* __restrict__ deg, int* __restrict__ off, int* __restrict__ cur) {
  __shared__ int sS[1024];
  const int t = threadIdx.x;
  const int CH = (NN + 1023) / 1024;  // 49
  int b = t * CH;
  int e = b + CH < NN ? b + CH : NN;
  int s = 0;
  for (int i = b; i < e; ++i) s += deg[i];
  sS[t] = s;
  __syncthreads();
  for (int st = 1; st < 1024; st <<= 1) {
    int v = (t >= st) ? sS[t - st] : 0;
    __syncthreads();
    sS[t] += v;
    __syncthreads();
  }
  int run = (t == 0) ? 0 : sS[t - 1];
  for (int i = b; i < e; ++i) {
    off[i] = run;
    cur[i] = run;
    run += deg[i];
  }
  if (t == 1023) off[NN] = NE;
}

__global__ __launch_bounds__(256) void fill_kernel(
    const int* __restrict__ dst, int* __restrict__ cur, int* __restrict__ eidx) {
  int e = blockIdx.x * 256 + threadIdx.x;
  if (e < NE) {
    int p = atomicAdd(&cur[dst[e]], 1);
    eidx[p] = e;
  }
}

// ---------------- layer-0 aggregation (gather): agg[n] = sum relu(x[src]+e) ----------------
// wave per node, lane = feature j; each edge row read is one coalesced 256B transaction
__global__ __launch_bounds__(256) void gather0_kernel(
    const float* __restrict__ x, const float* __restrict__ e,
    const int* __restrict__ src, const int* __restrict__ eidx,
    const int* __restrict__ off, float* __restrict__ agg) {
  int node = blockIdx.x * 4 + (threadIdx.x >> 6);
  if (node >= NN) return;
  int j = threadIdx.x & 63;
  int beg = off[node], end = off[node + 1];
  float acc = 0.f;
  for (int i = beg; i < end; ++i) {
    int eid = eidx[i];
    int s = src[eid];
    acc += fmaxf(x[(size_t)s * D + j] + e[(size_t)eid * D + j], 0.f);
  }
  agg[(size_t)node * D + j] = acc;
}

// ---------------- layer-1 aggregation (gather): agg[n] = sum msg[eid] ----------------
__global__ __launch_bounds__(256) void gather1_kernel(
    const float* __restrict__ msg, const int* __restrict__ eidx,
    const int* __restrict__ off, float* __restrict__ agg) {
  int node = blockIdx.x * 4 + (threadIdx.x >> 6);
  if (node >= NN) return;
  int j = threadIdx.x & 63;
  int beg = off[node], end = off[node + 1];
  float acc = 0.f;
  for (int i = beg; i < end; ++i) {
    int eid = eidx[i];
    acc += msg[(size_t)eid * D + j];
  }
  agg[(size_t)node * D + j] = acc;
}

// ---------------- pack edge-MLP weights into bf16 MFMA B-fragment order ----------------
__global__ __launch_bounds__(256) void pack_weights_kernel(
    const float* __restrict__ w1, const float* __restrict__ w2,
    unsigned short* __restrict__ wB1, unsigned short* __restrict__ wB2) {
  int tid = blockIdx.x * 256 + threadIdx.x;  // 2048 threads
  const float* wsrc;
  unsigned short* wdst;
  int kb, j, slot;
  if (tid < 1536) {
    int nt = tid / 384, kk = (tid / 64) % 6, l = tid & 63;
    kb = kk * 32 + (l >> 4) * 8;
    j = nt * 16 + (l & 15);
    wsrc = w1; wdst = wB1; slot = tid;
  } else {
    int t = tid - 1536;
    int nt = t / 128, kk = (t / 64) & 1, l = t & 63;
    kb = kk * 32 + (l >> 4) * 8;
    j = nt * 16 + (l & 15);
    wsrc = w2; wdst = wB2; slot = t;
  }
  unsigned short b[8];
#pragma unroll
  for (int i = 0; i < 8; ++i) b[i] = f2bf(wsrc[(kb + i) * D + j]);
  uint4 v;
  v.x = (unsigned)b[0] | ((unsigned)b[1] << 16);
  v.y = (unsigned)b[2] | ((unsigned)b[3] << 16);
  v.z = (unsigned)b[4] | ((unsigned)b[5] << 16);
  v.w = (unsigned)b[6] | ((unsigned)b[7] << 16);
  *(uint4*)(wdst + (size_t)slot * 8) = v;
}

// ---------------- legacy atomic scatter (tier-C fallback) ----------------
__global__ __launch_bounds__(256) void scatter_kernel(
    const float* __restrict__ x, const float* __restrict__ e,
    const int* __restrict__ src, const int* __restrict__ dst,
    float* __restrict__ agg) {
  int tid = blockIdx.x * blockDim.x + threadIdx.x;
  if (tid >= NE * 16) return;
  int eid = tid >> 4, q = tid & 15;
  int s = src[eid], d = dst[eid];
  float4 xv = ((const float4*)(x + (size_t)s * D))[q];
  float4 ev = ((const float4*)(e + (size_t)eid * D))[q];
  float* a = agg + (size_t)d * D + q * 4;
  atomicAdd(a + 0, fmaxf(xv.x + ev.x, 0.f));
  atomicAdd(a + 1, fmaxf(xv.y + ev.y, 0.f));
  atomicAdd(a + 2, fmaxf(xv.z + ev.z, 0.f));
  atomicAdd(a + 3, fmaxf(xv.w + ev.w, 0.f));
}

// ---------------- tiled node MLP (f32 VALU) ----------------
__global__ __launch_bounds__(256) void node_mlp_kernel(
    const float* __restrict__ x, const float* __restrict__ agg,
    const float* __restrict__ w1, const float* __restrict__ b1,
    const float* __restrict__ w2, const float* __restrict__ b2,
    const float* __restrict__ g, const float* __restrict__ bln,
    float* __restrict__ xo) {
  __shared__ float sIN[D * STR];
  __shared__ float sH[D * STR];
  __shared__ float sPS[256], sPQ[256], sMu[64], sRs[64];

  const int tid = threadIdx.x;
  const int n0 = blockIdx.x * 64;

  {
    const int t = tid & 63, p = tid >> 6;
    int node = n0 + t;
    int cn = node < NN ? node : 0;
    const float* xr = x + (size_t)cn * D + p * 16;
    const float* ar = agg + (size_t)cn * D + p * 16;
#pragma unroll
    for (int i = 0; i < 4; ++i) {
      float4 xv = ((const float4*)xr)[i];
      float4 av = ((const float4*)ar)[i];
      int k = p * 16 + i * 4;
      sIN[(k + 0) * STR + t] = xv.x + av.x;
      sIN[(k + 1) * STR + t] = xv.y + av.y;
      sIN[(k + 2) * STR + t] = xv.z + av.z;
      sIN[(k + 3) * STR + t] = xv.w + av.w;
    }
  }
  __syncthreads();

  const int tj = tid & 15, tt = tid >> 4;
  const int j0 = tj * 4, t0 = tt * 4;
  float4 a0, a1, a2, a3;

  {
    float4 bv = *(const float4*)(b1 + j0);
    a0 = a1 = a2 = a3 = bv;
    for (int k = 0; k < D; ++k) {
      float4 w = *(const float4*)(w1 + k * D + j0);
      float4 v = *(const float4*)&sIN[k * STR + t0];
      FMA4x4(v, w)
    }
  }
  HSTORE_RELU(sH)
  __syncthreads();

  {
    float4 bv = *(const float4*)(b2 + j0);
    a0 = a1 = a2 = a3 = bv;
    for (int k = 0; k < D; ++k) {
      float4 w = *(const float4*)(w2 + k * D + j0);
      float4 v = *(const float4*)&sH[k * STR + t0];
      FMA4x4(v, w)
    }
  }
  __syncthreads();
  *(float4*)&sH[(t0 + 0) * STR + j0] = a0;
  *(float4*)&sH[(t0 + 1) * STR + j0] = a1;
  *(float4*)&sH[(t0 + 2) * STR + j0] = a2;
  *(float4*)&sH[(t0 + 3) * STR + j0] = a3;
  __syncthreads();

  {
    const int t = tid & 63, p = tid >> 6;
    const float* r = &sH[t * STR + p * 16];
    float s = 0.f, q = 0.f;
#pragma unroll
    for (int i = 0; i < 16; ++i) { float v = r[i]; s += v; q = fmaf(v, v, q); }
    sPS[p * 64 + t] = s;
    sPQ[p * 64 + t] = q;
  }
  __syncthreads();
  if (tid < 64) {
    float s = sPS[tid] + sPS[64 + tid] + sPS[128 + tid] + sPS[192 + tid];
    float q = sPQ[tid] + sPQ[64 + tid] + sPQ[128 + tid] + sPQ[192 + tid];
    float mu = s * (1.f / 64.f);
    float var = q * (1.f / 64.f) - mu * mu;
    sMu[tid] = mu;
    sRs[tid] = rsqrtf(var + LNEPS);
  }
  __syncthreads();

  {
    const int t = tid >> 2, c = (tid & 3) * 16;
    int node = n0 + t;
    if (node < NN) {
      float mu = sMu[t], rs = sRs[t];
      float* o = xo + (size_t)node * D + c;
#pragma unroll
      for (int i = 0; i < 4; ++i) {
        float4 v = *(const float4*)&sH[t * STR + c + i * 4];
        float4 gv = *(const float4*)(g + c + i * 4);
        float4 bv = *(const float4*)(bln + c + i * 4);
        float4 r;
        r.x = fmaxf(fmaf((v.x - mu) * rs, gv.x, bv.x), 0.f);
        r.y = fmaxf(fmaf((v.y - mu) * rs, gv.y, bv.y), 0.f);
        r.z = fmaxf(fmaf((v.z - mu) * rs, gv.z, bv.z), 0.f);
        r.w = fmaxf(fmaf((v.w - mu) * rs, gv.w, bv.w), 0.f);
        ((float4*)o)[i] = r;
      }
    }
  }
}

// ---------------- MFMA edge MLP; epilogue either stores msg or atomics into agg ----------------
template <bool STORE_MSG>
__global__ __launch_bounds__(256) void edge_mfma_kernel(
    const float* __restrict__ x, const float* __restrict__ e,
    const int* __restrict__ src, const int* __restrict__ dst,
    const unsigned short* __restrict__ wB1, const float* __restrict__ b1,
    const unsigned short* __restrict__ wB2, const float* __restrict__ b2,
    float* __restrict__ outbuf) {  // msg if STORE_MSG else agg
  __shared__ unsigned short sIN[64 * SINB];
  __shared__ unsigned short sH[64 * SHB];

  const int tid = threadIdx.x;
  const int e0 = blockIdx.x * 64;
  const int lane = tid & 63;
  const int mt = tid >> 6;
  const int hl = lane >> 4;
  const int ll = lane & 15;

  {
    const int t = tid & 63, p = tid >> 6;
    int eid = e0 + t;
    int sN = src[eid], dN = dst[eid];
    const float* g0 = x + (size_t)sN * D + p * 16;
    const float* g1 = x + (size_t)dN * D + p * 16;
    const float* g2 = e + (size_t)eid * D + p * 16;
    unsigned short* row = sIN + t * SINB + p * 16;
#pragma unroll
    for (int i = 0; i < 4; ++i) {
      float4 v0 = ((const float4*)g0)[i];
      float4 v1 = ((const float4*)g1)[i];
      float4 v2 = ((const float4*)g2)[i];
      uint2 u;
      u.x = (unsigned)f2bf(v0.x) | ((unsigned)f2bf(v0.y) << 16);
      u.y = (unsigned)f2bf(v0.z) | ((unsigned)f2bf(v0.w) << 16);
      *(uint2*)(row + i * 4) = u;
      u.x = (unsigned)f2bf(v1.x) | ((unsigned)f2bf(v1.y) << 16);
      u.y = (unsigned)f2bf(v1.z) | ((unsigned)f2bf(v1.w) << 16);
      *(uint2*)(row + 64 + i * 4) = u;
      u.x = (unsigned)f2bf(v2.x) | ((unsigned)f2bf(v2.y) << 16);
      u.y = (unsigned)f2bf(v2.z) | ((unsigned)f2bf(v2.w) << 16);
      *(uint2*)(row + 128 + i * 4) = u;
    }
  }
  __syncthreads();

  f32x4 acc[4];
#pragma unroll
  for (int nt = 0; nt < 4; ++nt) {
    float b = b1[nt * 16 + ll];
    acc[nt].x = b; acc[nt].y = b; acc[nt].z = b; acc[nt].w = b;
  }
  {
    const unsigned short* aBase = sIN + (mt * 16 + ll) * SINB + hl * 8;
#pragma unroll
    for (int kk = 0; kk < 6; ++kk) {
      bf16x8 af = *(const bf16x8*)(aBase + kk * 32);
#pragma unroll
      for (int nt = 0; nt < 4; ++nt) {
        bf16x8 bf = *(const bf16x8*)(wB1 + ((size_t)(nt * 6 + kk) * 64 + lane) * 8);
        acc[nt] = __builtin_amdgcn_mfma_f32_16x16x32_bf16(af, bf, acc[nt], 0, 0, 0);
      }
    }
  }
#pragma unroll
  for (int nt = 0; nt < 4; ++nt)
#pragma unroll
    for (int r = 0; r < 4; ++r)
      sH[(mt * 16 + hl * 4 + r) * SHB + nt * 16 + ll] = f2bf(fmaxf(acc[nt][r], 0.f));
  __syncthreads();

  f32x4 acc2[4];
#pragma unroll
  for (int nt = 0; nt < 4; ++nt) {
    float b = b2[nt * 16 + ll];
    acc2[nt].x = b; acc2[nt].y = b; acc2[nt].z = b; acc2[nt].w = b;
  }
  {
    const unsigned short* hBase = sH + (mt * 16 + ll) * SHB + hl * 8;
#pragma unroll
    for (int kk = 0; kk < 2; ++kk) {
      bf16x8 af = *(const bf16x8*)(hBase + kk * 32);
#pragma unroll
      for (int nt = 0; nt < 4; ++nt) {
        bf16x8 bf = *(const bf16x8*)(wB2 + ((size_t)(nt * 2 + kk) * 64 + lane) * 8);
        acc2[nt] = __builtin_amdgcn_mfma_f32_16x16x32_bf16(af, bf, acc2[nt], 0, 0, 0);
      }
    }
  }

#pragma unroll
  for (int r = 0; r < 4; ++r) {
    int t = mt * 16 + hl * 4 + r;
    int eid = e0 + t;
    int sN = src[eid];
    const float* er = e + (size_t)eid * D;
    const float* xr = x + (size_t)sN * D;
    if (STORE_MSG) {
      float* mr = outbuf + (size_t)eid * D;
#pragma unroll
      for (int nt = 0; nt < 4; ++nt) {
        int j = nt * 16 + ll;
        mr[j] = fmaxf(xr[j] + fmaf(0.5f, acc2[nt][r], er[j]), 0.f);
      }
    } else {
      int dN = dst[eid];
      float* ar = outbuf + (size_t)dN * D;
#pragma unroll
      for (int nt = 0; nt < 4; ++nt) {
        int j = nt * 16 + ll;
        atomicAdd(ar + j, fmaxf(xr[j] + fmaf(0.5f, acc2[nt][r], er[j]), 0.f));
      }
    }
  }
}

// ---------------- head ----------------
__global__ __launch_bounds__(256) void head_kernel(
    const float* __restrict__ x, const float* __restrict__ w,
    const float* __restrict__ b, float* __restrict__ out) {
  int nid = blockIdx.x * blockDim.x + threadIdx.x;
  if (nid >= NN) return;
  const float* xr = x + (size_t)nid * D;
  float a0 = b[0], a1 = b[1];
  for (int k = 0; k < D; ++k) {
    float v = xr[k];
    a0 = fmaf(v, w[k * 2 + 0], a0);
    a1 = fmaf(v, w[k * 2 + 1], a1);
  }
  out[nid * 2 + 0] = a0;
  out[nid * 2 + 1] = a1;
}

extern "C" void kernel_launch(void* const* d_in, const int* in_sizes, int n_in,
                              void* d_out, int out_size, void* d_ws, size_t ws_size,
                              hipStream_t stream) {
  const float* x0  = (const float*)d_in[0];
  const float* e0  = (const float*)d_in[1];
  const int*   ei  = (const int*)d_in[2];
  const float* gw1 = (const float*)d_in[3];
  const float* gb1 = (const float*)d_in[4];
  const float* gw2 = (const float*)d_in[5];
  const float* gb2 = (const float*)d_in[6];
  const float* ew1 = (const float*)d_in[7];
  const float* eb1 = (const float*)d_in[8];
  const float* ew2 = (const float*)d_in[9];
  const float* eb2 = (const float*)d_in[10];
  const float* lng = (const float*)d_in[11];
  const float* lnb = (const float*)d_in[12];
  const float* hw  = (const float*)d_in[13];
  const float* hb  = (const float*)d_in[14];
  float* out = (float*)d_out;

  char* ws = (char*)d_ws;
  // workspace layout (byte offsets)
  const size_t OFF_X1   = 0;
  const size_t OFF_X2   = OFF_X1 + (size_t)NN * D * 4;       // 12.8 MB
  const size_t OFF_AGG  = OFF_X2 + (size_t)NN * D * 4;
  const size_t OFF_WB1  = OFF_AGG + (size_t)NN * D * 4;
  const size_t OFF_WB2  = OFF_WB1 + 12288 * 2;
  const size_t OFF_DEG  = OFF_WB2 + 4096 * 2;
  const size_t OFF_OFFS = OFF_DEG + 200192;                  // NN ints padded
  const size_t OFF_CUR  = OFF_OFFS + 200192;                 // NN+1 ints padded
  const size_t OFF_EIDX = OFF_CUR + 200192;
  const size_t OFF_MSG  = OFF_EIDX + (size_t)NE * 4;
  const size_t NEED_B   = OFF_MSG;                            // ~42.2 MB
  const size_t NEED_A   = OFF_MSG + (size_t)NE * D * 4;       // ~247 MB

  float* x1   = (float*)(ws + OFF_X1);
  float* x2   = (float*)(ws + OFF_X2);
  float* agg  = (float*)(ws + OFF_AGG);
  unsigned short* wB1 = (unsigned short*)(ws + OFF_WB1);
  unsigned short* wB2 = (unsigned short*)(ws + OFF_WB2);
  int* deg  = (int*)(ws + OFF_DEG);
  int* offs = (int*)(ws + OFF_OFFS);
  int* cur  = (int*)(ws + OFF_CUR);
  int* eidx = (int*)(ws + OFF_EIDX);
  float* msg = (float*)(ws + OFF_MSG);

  const int* src = ei;
  const int* dst = ei + NE;

  const int nodeBlocks = (NN + 63) / 64;   // 782
  const int edgeBlocks = NE / 64;          // 12500
  const int gBlocks = (NN + 3) / 4;        // 12500

  const bool tierA = ws_size >= NEED_A;
  const bool tierB = ws_size >= NEED_B;

  pack_weights_kernel<<<8, 256, 0, stream>>>(ew1, ew2, wB1, wB2);

  if (tierB) {
    // ---- CSR build (by dst) ----
    hipMemsetAsync(deg, 0, (size_t)NN * 4, stream);
    count_kernel<<<(NE + 255) / 256, 256, 0, stream>>>(dst, deg);
    scan_kernel<<<1, 1024, 0, stream>>>(deg, offs, cur);
    fill_kernel<<<(NE + 255) / 256, 256, 0, stream>>>(dst, cur, eidx);

    // ---- layer 0: gather aggregation + node MLP ----
    gather0_kernel<<<gBlocks, 256, 0, stream>>>(x0, e0, src, eidx, offs, agg);
    node_mlp_kernel<<<nodeBlocks, 256, 0, stream>>>(
        x0, agg, gw1, gb1, gw2, gb2, lng, lnb, x1);

    // ---- layer-0 edge update fused with layer-1 aggregation ----
    if (tierA) {
      edge_mfma_kernel<true><<<edgeBlocks, 256, 0, stream>>>(
          x1, e0, src, dst, wB1, eb1, wB2, eb2, msg);
      gather1_kernel<<<gBlocks, 256, 0, stream>>>(msg, eidx, offs, agg);
    } else {
      hipMemsetAsync(agg, 0, (size_t)NN * D * 4, stream);
      edge_mfma_kernel<false><<<edgeBlocks, 256, 0, stream>>>(
          x1, e0, src, dst, wB1, eb1, wB2, eb2, agg);
    }
  } else {
    // ---- tier C: legacy atomic path ----
    hipMemsetAsync(agg, 0, (size_t)NN * D * 4, stream);
    scatter_kernel<<<(NE * 16 + 255) / 256, 256, 0, stream>>>(x0, e0, src, dst, agg);
    node_mlp_kernel<<<nodeBlocks, 256, 0, stream>>>(
        x0, agg, gw1, gb1, gw2, gb2, lng, lnb, x1);
    hipMemsetAsync(agg, 0, (size_t)NN * D * 4, stream);
    edge_mfma_kernel<false><<<edgeBlocks, 256, 0, stream>>>(
        x1, e0, src, dst, wB1, eb1, wB2, eb2, agg);
  }

  // ---- layer 1 node update (layer-1 edge update is dead code) ----
  node_mlp_kernel<<<nodeBlocks, 256, 0, stream>>>(
      x1, agg, gw1 + D * D, gb1 + D, gw2 + D * D, gb2 + D, lng + D, lnb + D, x2);

  // ---- head ----
  head_kernel<<<(NN + 255) / 256, 256, 0, stream>>>(x2, hw, hb, out);
}

// Round 5
// 671.142 us; speedup vs baseline: 5.9567x; 1.1238x over previous
//
#include <hip/hip_runtime.h>

#define NN 50000
#define NE 800000
#define D 64
#define K3 (3 * D)
#define LNEPS 1e-5f
#define STR 68    // f32 LDS row stride (node kernels)
#define SINB 200  // bf16 LDS row stride, edge input tile
#define SHB 72    // bf16 LDS row stride, edge hidden tile
#define SEB 68    // f32 LDS row stride, edge e-tile (16B aligned, 2-way banks = free)

typedef __attribute__((ext_vector_type(8))) short bf16x8;
typedef __attribute__((ext_vector_type(4))) float f32x4;

__device__ __forceinline__ unsigned short f2bf(float f) {
  unsigned u = __float_as_uint(f);
  u += 0x7FFF + ((u >> 16) & 1);  // RNE
  return (unsigned short)(u >> 16);
}

#define FMA4x4(v, w)                                                  \
  a0.x = fmaf(v.x, w.x, a0.x); a0.y = fmaf(v.x, w.y, a0.y);           \
  a0.z = fmaf(v.x, w.z, a0.z); a0.w = fmaf(v.x, w.w, a0.w);           \
  a1.x = fmaf(v.y, w.x, a1.x); a1.y = fmaf(v.y, w.y, a1.y);           \
  a1.z = fmaf(v.y, w.z, a1.z); a1.w = fmaf(v.y, w.w, a1.w);           \
  a2.x = fmaf(v.z, w.x, a2.x); a2.y = fmaf(v.z, w.y, a2.y);           \
  a2.z = fmaf(v.z, w.z, a2.z); a2.w = fmaf(v.z, w.w, a2.w);           \
  a3.x = fmaf(v.w, w.x, a3.x); a3.y = fmaf(v.w, w.y, a3.y);           \
  a3.z = fmaf(v.w, w.z, a3.z); a3.w = fmaf(v.w, w.w, a3.w);

#define HSTORE_RELU(buf)                                              \
  buf[(j0+0)*STR + t0+0] = fmaxf(a0.x, 0.f);                          \
  buf[(j0+1)*STR + t0+0] = fmaxf(a0.y, 0.f);                          \
  buf[(j0+2)*STR + t0+0] = fmaxf(a0.z, 0.f);                          \
  buf[(j0+3)*STR + t0+0] = fmaxf(a0.w, 0.f);                          \
  buf[(j0+0)*STR + t0+1] = fmaxf(a1.x, 0.f);                          \
  buf[(j0+1)*STR + t0+1] = fmaxf(a1.y, 0.f);                          \
  buf[(j0+2)*STR + t0+1] = fmaxf(a1.z, 0.f);                          \
  buf[(j0+3)*STR + t0+1] = fmaxf(a1.w, 0.f);                          \
  buf[(j0+0)*STR + t0+2] = fmaxf(a2.x, 0.f);                          \
  buf[(j0+1)*STR + t0+2] = fmaxf(a2.y, 0.f);                          \
  buf[(j0+2)*STR + t0+2] = fmaxf(a2.z, 0.f);                          \
  buf[(j0+3)*STR + t0+2] = fmaxf(a2.w, 0.f);                          \
  buf[(j0+0)*STR + t0+3] = fmaxf(a3.x, 0.f);                          \
  buf[(j0+1)*STR + t0+3] = fmaxf(a3.y, 0.f);                          \
  buf[(j0+2)*STR + t0+3] = fmaxf(a3.z, 0.f);                          \
  buf[(j0+3)*STR + t0+3] = fmaxf(a3.w, 0.f);

// ---------------- CSR build ----------------
__global__ __launch_bounds__(256) void count_kernel(
    const int* __restrict__ dst, int* __restrict__ deg) {
  int e = blockIdx.x * 256 + threadIdx.x;
  if (e < NE) atomicAdd(&deg[dst[e]], 1);
}

// coalesced block reduce: bsum[b] = sum deg[b*1024 .. b*1024+1023]
__global__ __launch_bounds__(1024) void scan_reduce_kernel(
    const int* __restrict__ deg, int* __restrict__ bsum) {
  __shared__ int sS[16];
  int i = blockIdx.x * 1024 + threadIdx.x;
  int v = (i < NN) ? deg[i] : 0;
#pragma unroll
  for (int o = 32; o > 0; o >>= 1) v += __shfl_down(v, o, 64);
  if ((threadIdx.x & 63) == 0) sS[threadIdx.x >> 6] = v;
  __syncthreads();
  if (threadIdx.x == 0) {
    int s = 0;
#pragma unroll
    for (int k = 0; k < 16; ++k) s += sS[k];
    bsum[blockIdx.x] = s;
  }
}

// per-block coalesced scan; base = serial sum of prior bsums (<=48 reads)
__global__ __launch_bounds__(1024) void scan_final_kernel(
    const int* __restrict__ deg, const int* __restrict__ bsum,
    int* __restrict__ off, int* __restrict__ cur) {
  __shared__ int sD[1024];
  __shared__ int sOfs;
  const int t = threadIdx.x;
  const int b = blockIdx.x;
  int i = b * 1024 + t;
  int v = (i < NN) ? deg[i] : 0;
  sD[t] = v;
  if (t == 0) {
    int o = 0;
    for (int k = 0; k < b; ++k) o += bsum[k];
    sOfs = o;
  }
  __syncthreads();
  for (int st = 1; st < 1024; st <<= 1) {
    int add = (t >= st) ? sD[t - st] : 0;
    __syncthreads();
    sD[t] += add;
    __syncthreads();
  }
  if (i < NN) {
    int excl = sOfs + sD[t] - v;
    off[i] = excl;
    cur[i] = excl;
    if (i == NN - 1) off[NN] = NE;
  }
}

__global__ __launch_bounds__(256) void fill_kernel(
    const int* __restrict__ dst, int* __restrict__ cur,
    int* __restrict__ eidx, int* __restrict__ pos) {
  int e = blockIdx.x * 256 + threadIdx.x;
  if (e < NE) {
    int p = atomicAdd(&cur[dst[e]], 1);
    eidx[p] = e;
    pos[e] = p;
  }
}

// ---------------- pack edge-MLP weights into bf16 MFMA B-fragment order ----------------
__global__ __launch_bounds__(256) void pack_weights_kernel(
    const float* __restrict__ w1, const float* __restrict__ w2,
    unsigned short* __restrict__ wB1, unsigned short* __restrict__ wB2) {
  int tid = blockIdx.x * 256 + threadIdx.x;  // 2048 threads
  const float* wsrc;
  unsigned short* wdst;
  int kb, j, slot;
  if (tid < 1536) {
    int nt = tid / 384, kk = (tid / 64) % 6, l = tid & 63;
    kb = kk * 32 + (l >> 4) * 8;
    j = nt * 16 + (l & 15);
    wsrc = w1; wdst = wB1; slot = tid;
  } else {
    int t = tid - 1536;
    int nt = t / 128, kk = (t / 64) & 1, l = t & 63;
    kb = kk * 32 + (l >> 4) * 8;
    j = nt * 16 + (l & 15);
    wsrc = w2; wdst = wB2; slot = t;
  }
  unsigned short b[8];
#pragma unroll
  for (int i = 0; i < 8; ++i) b[i] = f2bf(wsrc[(kb + i) * D + j]);
  uint4 v;
  v.x = (unsigned)b[0] | ((unsigned)b[1] << 16);
  v.y = (unsigned)b[2] | ((unsigned)b[3] << 16);
  v.z = (unsigned)b[4] | ((unsigned)b[5] << 16);
  v.w = (unsigned)b[6] | ((unsigned)b[7] << 16);
  *(uint4*)(wdst + (size_t)slot * 8) = v;
}

// ---------------- shared MLP tail: GEMM1 -> relu -> GEMM2 -> LN -> relu -> store ----------------
__device__ __forceinline__ void mlp_tail(
    float* sIN, float* sH, float* sPS, float* sPQ, float* sMu, float* sRs,
    const float* __restrict__ w1, const float* __restrict__ b1,
    const float* __restrict__ w2, const float* __restrict__ b2,
    const float* __restrict__ g, const float* __restrict__ bln,
    float* __restrict__ xo, int n0, int tid) {
  __syncthreads();
  const int tj = tid & 15, tt = tid >> 4;
  const int j0 = tj * 4, t0 = tt * 4;
  float4 a0, a1, a2, a3;

  {
    float4 bv = *(const float4*)(b1 + j0);
    a0 = a1 = a2 = a3 = bv;
    for (int k = 0; k < D; ++k) {
      float4 w = *(const float4*)(w1 + k * D + j0);
      float4 v = *(const float4*)&sIN[k * STR + t0];
      FMA4x4(v, w)
    }
  }
  HSTORE_RELU(sH)
  __syncthreads();

  {
    float4 bv = *(const float4*)(b2 + j0);
    a0 = a1 = a2 = a3 = bv;
    for (int k = 0; k < D; ++k) {
      float4 w = *(const float4*)(w2 + k * D + j0);
      float4 v = *(const float4*)&sH[k * STR + t0];
      FMA4x4(v, w)
    }
  }
  __syncthreads();
  *(float4*)&sH[(t0 + 0) * STR + j0] = a0;
  *(float4*)&sH[(t0 + 1) * STR + j0] = a1;
  *(float4*)&sH[(t0 + 2) * STR + j0] = a2;
  *(float4*)&sH[(t0 + 3) * STR + j0] = a3;
  __syncthreads();

  {
    const int t = tid & 63, p = tid >> 6;
    const float* r = &sH[t * STR + p * 16];
    float s = 0.f, q = 0.f;
#pragma unroll
    for (int i = 0; i < 16; ++i) { float v = r[i]; s += v; q = fmaf(v, v, q); }
    sPS[p * 64 + t] = s;
    sPQ[p * 64 + t] = q;
  }
  __syncthreads();
  if (tid < 64) {
    float s = sPS[tid] + sPS[64 + tid] + sPS[128 + tid] + sPS[192 + tid];
    float q = sPQ[tid] + sPQ[64 + tid] + sPQ[128 + tid] + sPQ[192 + tid];
    float mu = s * (1.f / 64.f);
    float var = q * (1.f / 64.f) - mu * mu;
    sMu[tid] = mu;
    sRs[tid] = rsqrtf(var + LNEPS);
  }
  __syncthreads();

  {
    const int t = tid >> 2, c = (tid & 3) * 16;
    int node = n0 + t;
    if (node < NN) {
      float mu = sMu[t], rs = sRs[t];
      float* o = xo + (size_t)node * D + c;
#pragma unroll
      for (int i = 0; i < 4; ++i) {
        float4 v = *(const float4*)&sH[t * STR + c + i * 4];
        float4 gv = *(const float4*)(g + c + i * 4);
        float4 bv = *(const float4*)(bln + c + i * 4);
        float4 r;
        r.x = fmaxf(fmaf((v.x - mu) * rs, gv.x, bv.x), 0.f);
        r.y = fmaxf(fmaf((v.y - mu) * rs, gv.y, bv.y), 0.f);
        r.z = fmaxf(fmaf((v.z - mu) * rs, gv.z, bv.z), 0.f);
        r.w = fmaxf(fmaf((v.w - mu) * rs, gv.w, bv.w), 0.f);
        ((float4*)o)[i] = r;
      }
    }
  }
}

// ---------------- layer-0: fused CSR gather + node MLP ----------------
__global__ __launch_bounds__(256) void node_mlp_g0_kernel(
    const float* __restrict__ x, const float* __restrict__ e,
    const int* __restrict__ src, const int* __restrict__ eidx,
    const int* __restrict__ off,
    const float* __restrict__ w1, const float* __restrict__ b1,
    const float* __restrict__ w2, const float* __restrict__ b2,
    const float* __restrict__ g, const float* __restrict__ bln,
    float* __restrict__ xo) {
  __shared__ float sIN[D * STR];
  __shared__ float sH[D * STR];
  __shared__ float sPS[256], sPQ[256], sMu[64], sRs[64];
  const int tid = threadIdx.x;
  const int n0 = blockIdx.x * 64;
  const int wv = tid >> 6, lane = tid & 63;
  // wave wv gathers nodes wv*16..wv*16+15; lane = feature
  for (int q = 0; q < 16; ++q) {
    int t = wv * 16 + q;
    int node = n0 + t;
    float acc = 0.f;
    if (node < NN) {
      acc = x[(size_t)node * D + lane];  // self term
      int beg = off[node], end = off[node + 1];
      int i = beg;
      if (i < end) {
        int eid = eidx[i], s = src[eid];
        for (; i + 1 < end; ++i) {
          int eid2 = eidx[i + 1];  // software-pipeline the index chain
          int s2 = src[eid2];
          acc += fmaxf(x[(size_t)s * D + lane] + e[(size_t)eid * D + lane], 0.f);
          eid = eid2; s = s2;
        }
        acc += fmaxf(x[(size_t)s * D + lane] + e[(size_t)eid * D + lane], 0.f);
      }
    }
    sIN[lane * STR + t] = acc;
  }
  mlp_tail(sIN, sH, sPS, sPQ, sMu, sRs, w1, b1, w2, b2, g, bln, xo, n0, tid);
}

// ---------------- layer-1: fused streaming gather (CSR-ordered msg) + node MLP ----------------
__global__ __launch_bounds__(256) void node_mlp_g1_kernel(
    const float* __restrict__ x, const float* __restrict__ msg,
    const int* __restrict__ off,
    const float* __restrict__ w1, const float* __restrict__ b1,
    const float* __restrict__ w2, const float* __restrict__ b2,
    const float* __restrict__ g, const float* __restrict__ bln,
    float* __restrict__ xo) {
  __shared__ float sIN[D * STR];
  __shared__ float sH[D * STR];
  __shared__ float sPS[256], sPQ[256], sMu[64], sRs[64];
  const int tid = threadIdx.x;
  const int n0 = blockIdx.x * 64;
  const int wv = tid >> 6, lane = tid & 63;
  for (int q = 0; q < 16; ++q) {
    int t = wv * 16 + q;
    int node = n0 + t;
    float acc = 0.f;
    if (node < NN) {
      acc = x[(size_t)node * D + lane];
      int beg = off[node], end = off[node + 1];
      const float* mr = msg + (size_t)beg * D + lane;
      for (int i = beg; i < end; ++i, mr += D) acc += *mr;  // contiguous stream
    }
    sIN[lane * STR + t] = acc;
  }
  mlp_tail(sIN, sH, sPS, sPQ, sMu, sRs, w1, b1, w2, b2, g, bln, xo, n0, tid);
}

// ---------------- legacy kernels (tier-C fallback) ----------------
__global__ __launch_bounds__(256) void scatter_kernel(
    const float* __restrict__ x, const float* __restrict__ e,
    const int* __restrict__ src, const int* __restrict__ dst,
    float* __restrict__ agg) {
  int tid = blockIdx.x * blockDim.x + threadIdx.x;
  if (tid >= NE * 16) return;
  int eid = tid >> 4, q = tid & 15;
  int s = src[eid], d = dst[eid];
  float4 xv = ((const float4*)(x + (size_t)s * D))[q];
  float4 ev = ((const float4*)(e + (size_t)eid * D))[q];
  float* a = agg + (size_t)d * D + q * 4;
  atomicAdd(a + 0, fmaxf(xv.x + ev.x, 0.f));
  atomicAdd(a + 1, fmaxf(xv.y + ev.y, 0.f));
  atomicAdd(a + 2, fmaxf(xv.z + ev.z, 0.f));
  atomicAdd(a + 3, fmaxf(xv.w + ev.w, 0.f));
}

__global__ __launch_bounds__(256) void node_mlp_kernel(
    const float* __restrict__ x, const float* __restrict__ agg,
    const float* __restrict__ w1, const float* __restrict__ b1,
    const float* __restrict__ w2, const float* __restrict__ b2,
    const float* __restrict__ g, const float* __restrict__ bln,
    float* __restrict__ xo) {
  __shared__ float sIN[D * STR];
  __shared__ float sH[D * STR];
  __shared__ float sPS[256], sPQ[256], sMu[64], sRs[64];
  const int tid = threadIdx.x;
  const int n0 = blockIdx.x * 64;
  {
    const int t = tid & 63, p = tid >> 6;
    int node = n0 + t;
    int cn = node < NN ? node : 0;
    const float* xr = x + (size_t)cn * D + p * 16;
    const float* ar = agg + (size_t)cn * D + p * 16;
#pragma unroll
    for (int i = 0; i < 4; ++i) {
      float4 xv = ((const float4*)xr)[i];
      float4 av = ((const float4*)ar)[i];
      int k = p * 16 + i * 4;
      sIN[(k + 0) * STR + t] = xv.x + av.x;
      sIN[(k + 1) * STR + t] = xv.y + av.y;
      sIN[(k + 2) * STR + t] = xv.z + av.z;
      sIN[(k + 3) * STR + t] = xv.w + av.w;
    }
  }
  mlp_tail(sIN, sH, sPS, sPQ, sMu, sRs, w1, b1, w2, b2, g, bln, xo, n0, tid);
}

// ---------------- MFMA edge MLP; stores msg CSR-permuted (or atomics, fallback) ----------------
template <bool STORE_MSG>
__global__ __launch_bounds__(256) void edge_mfma_kernel(
    const float* __restrict__ x, const float* __restrict__ e,
    const int* __restrict__ src, const int* __restrict__ dst,
    const int* __restrict__ pos,
    const unsigned short* __restrict__ wB1, const float* __restrict__ b1,
    const unsigned short* __restrict__ wB2, const float* __restrict__ b2,
    float* __restrict__ outbuf) {  // msg (CSR order) if STORE_MSG else agg
  __shared__ unsigned short sIN[64 * SINB];  // bf16 cat inputs [t][k]
  __shared__ unsigned short sH[64 * SHB];    // bf16 relu(h) [t][k2]
  __shared__ float sE[64 * SEB];             // f32 e tile [t][j] (epilogue reuse)

  const int tid = threadIdx.x;
  const int e0 = blockIdx.x * 64;
  const int lane = tid & 63;
  const int mt = tid >> 6;
  const int hl = lane >> 4;
  const int ll = lane & 15;

  {
    const int t = tid & 63, p = tid >> 6;
    int eid = e0 + t;
    int sN = src[eid], dN = dst[eid];
    const float* g0 = x + (size_t)sN * D + p * 16;
    const float* g1 = x + (size_t)dN * D + p * 16;
    const float* g2 = e + (size_t)eid * D + p * 16;
    unsigned short* row = sIN + t * SINB + p * 16;
#pragma unroll
    for (int i = 0; i < 4; ++i) {
      float4 v0 = ((const float4*)g0)[i];
      float4 v1 = ((const float4*)g1)[i];
      float4 v2 = ((const float4*)g2)[i];
      uint2 u;
      u.x = (unsigned)f2bf(v0.x) | ((unsigned)f2bf(v0.y) << 16);
      u.y = (unsigned)f2bf(v0.z) | ((unsigned)f2bf(v0.w) << 16);
      *(uint2*)(row + i * 4) = u;
      u.x = (unsigned)f2bf(v1.x) | ((unsigned)f2bf(v1.y) << 16);
      u.y = (unsigned)f2bf(v1.z) | ((unsigned)f2bf(v1.w) << 16);
      *(uint2*)(row + 64 + i * 4) = u;
      u.x = (unsigned)f2bf(v2.x) | ((unsigned)f2bf(v2.y) << 16);
      u.y = (unsigned)f2bf(v2.z) | ((unsigned)f2bf(v2.w) << 16);
      *(uint2*)(row + 128 + i * 4) = u;
      *(float4*)&sE[t * SEB + p * 16 + i * 4] = v2;  // keep f32 e for epilogue
    }
  }
  __syncthreads();

  f32x4 acc[4];
#pragma unroll
  for (int nt = 0; nt < 4; ++nt) {
    float b = b1[nt * 16 + ll];
    acc[nt].x = b; acc[nt].y = b; acc[nt].z = b; acc[nt].w = b;
  }
  {
    const unsigned short* aBase = sIN + (mt * 16 + ll) * SINB + hl * 8;
#pragma unroll
    for (int kk = 0; kk < 6; ++kk) {
      bf16x8 af = *(const bf16x8*)(aBase + kk * 32);
#pragma unroll
      for (int nt = 0; nt < 4; ++nt) {
        bf16x8 bf = *(const bf16x8*)(wB1 + ((size_t)(nt * 6 + kk) * 64 + lane) * 8);
        acc[nt] = __builtin_amdgcn_mfma_f32_16x16x32_bf16(af, bf, acc[nt], 0, 0, 0);
      }
    }
  }
#pragma unroll
  for (int nt = 0; nt < 4; ++nt)
#pragma unroll
    for (int r = 0; r < 4; ++r)
      sH[(mt * 16 + hl * 4 + r) * SHB + nt * 16 + ll] = f2bf(fmaxf(acc[nt][r], 0.f));
  __syncthreads();

  f32x4 acc2[4];
#pragma unroll
  for (int nt = 0; nt < 4; ++nt) {
    float b = b2[nt * 16 + ll];
    acc2[nt].x = b; acc2[nt].y = b; acc2[nt].z = b; acc2[nt].w = b;
  }
  {
    const unsigned short* hBase = sH + (mt * 16 + ll) * SHB + hl * 8;
#pragma unroll
    for (int kk = 0; kk < 2; ++kk) {
      bf16x8 af = *(const bf16x8*)(hBase + kk * 32);
#pragma unroll
      for (int nt = 0; nt < 4; ++nt) {
        bf16x8 bf = *(const bf16x8*)(wB2 + ((size_t)(nt * 2 + kk) * 64 + lane) * 8);
        acc2[nt] = __builtin_amdgcn_mfma_f32_16x16x32_bf16(af, bf, acc2[nt], 0, 0, 0);
      }
    }
  }

#pragma unroll
  for (int r = 0; r < 4; ++r) {
    int t = mt * 16 + hl * 4 + r;
    int eid = e0 + t;
    int sN = src[eid];
    const float* xr = x + (size_t)sN * D;
    const float* er = &sE[t * SEB];
    if (STORE_MSG) {
      int p = pos[eid];
      float* mr = outbuf + (size_t)p * D;
#pragma unroll
      for (int nt = 0; nt < 4; ++nt) {
        int j = nt * 16 + ll;
        mr[j] = fmaxf(xr[j] + fmaf(0.5f, acc2[nt][r], er[j]), 0.f);
      }
    } else {
      int dN = dst[eid];
      float* ar = outbuf + (size_t)dN * D;
#pragma unroll
      for (int nt = 0; nt < 4; ++nt) {
        int j = nt * 16 + ll;
        atomicAdd(ar + j, fmaxf(xr[j] + fmaf(0.5f, acc2[nt][r], er[j]), 0.f));
      }
    }
  }
}

// ---------------- head ----------------
__global__ __launch_bounds__(256) void head_kernel(
    const float* __restrict__ x, const float* __restrict__ w,
    const float* __restrict__ b, float* __restrict__ out) {
  int nid = blockIdx.x * blockDim.x + threadIdx.x;
  if (nid >= NN) return;
  const float* xr = x + (size_t)nid * D;
  float a0 = b[0], a1 = b[1];
  for (int k = 0; k < D; ++k) {
    float v = xr[k];
    a0 = fmaf(v, w[k * 2 + 0], a0);
    a1 = fmaf(v, w[k * 2 + 1], a1);
  }
  out[nid * 2 + 0] = a0;
  out[nid * 2 + 1] = a1;
}

extern "C" void kernel_launch(void* const* d_in, const int* in_sizes, int n_in,
                              void* d_out, int out_size, void* d_ws, size_t ws_size,
                              hipStream_t stream) {
  const float* x0  = (const float*)d_in[0];
  const float* e0  = (const float*)d_in[1];
  const int*   ei  = (const int*)d_in[2];
  const float* gw1 = (const float*)d_in[3];
  const float* gb1 = (const float*)d_in[4];
  const float* gw2 = (const float*)d_in[5];
  const float* gb2 = (const float*)d_in[6];
  const float* ew1 = (const float*)d_in[7];
  const float* eb1 = (const float*)d_in[8];
  const float* ew2 = (const float*)d_in[9];
  const float* eb2 = (const float*)d_in[10];
  const float* lng = (const float*)d_in[11];
  const float* lnb = (const float*)d_in[12];
  const float* hw  = (const float*)d_in[13];
  const float* hb  = (const float*)d_in[14];
  float* out = (float*)d_out;

  char* ws = (char*)d_ws;
  const size_t SZ_X    = (size_t)NN * D * 4;          // 12.8 MB
  const size_t OFF_X1   = 0;
  const size_t OFF_X2   = OFF_X1 + SZ_X;
  const size_t OFF_WB1  = OFF_X2 + SZ_X;
  const size_t OFF_WB2  = OFF_WB1 + 24576;
  const size_t OFF_DEG  = OFF_WB2 + 8192;
  const size_t OFF_OFFS = OFF_DEG + 200704;
  const size_t OFF_CUR  = OFF_OFFS + 200704;
  const size_t OFF_EIDX = OFF_CUR + 200704;
  const size_t OFF_POS  = OFF_EIDX + (size_t)NE * 4;
  const size_t OFF_MSG  = OFF_POS + (size_t)NE * 4;
  const size_t NEED_A   = OFF_MSG + (size_t)NE * D * 4;  // ~237 MB

  float* x1   = (float*)(ws + OFF_X1);
  float* x2   = (float*)(ws + OFF_X2);
  unsigned short* wB1 = (unsigned short*)(ws + OFF_WB1);
  unsigned short* wB2 = (unsigned short*)(ws + OFF_WB2);
  int* deg  = (int*)(ws + OFF_DEG);
  int* offs = (int*)(ws + OFF_OFFS);
  int* cur  = (int*)(ws + OFF_CUR);
  int* eidx = (int*)(ws + OFF_EIDX);
  int* pos  = (int*)(ws + OFF_POS);
  float* msg = (float*)(ws + OFF_MSG);

  const int* src = ei;
  const int* dst = ei + NE;

  const int nodeBlocks = (NN + 63) / 64;     // 782
  const int edgeBlocks = NE / 64;            // 12500
  const int scanBlocks = (NN + 1023) / 1024; // 49

  pack_weights_kernel<<<8, 256, 0, stream>>>(ew1, ew2, wB1, wB2);

  if (ws_size >= NEED_A) {
    // ---- CSR build (by dst), also records pos[e] ----
    hipMemsetAsync(deg, 0, (size_t)NN * 4, stream);
    count_kernel<<<(NE + 255) / 256, 256, 0, stream>>>(dst, deg);
    scan_reduce_kernel<<<scanBlocks, 1024, 0, stream>>>(deg, cur);  // cur = bsum temp
    scan_final_kernel<<<scanBlocks, 1024, 0, stream>>>(deg, cur, offs, cur);
    fill_kernel<<<(NE + 255) / 256, 256, 0, stream>>>(dst, cur, eidx, pos);

    // ---- layer 0: fused gather + node MLP ----
    node_mlp_g0_kernel<<<nodeBlocks, 256, 0, stream>>>(
        x0, e0, src, eidx, offs, gw1, gb1, gw2, gb2, lng, lnb, x1);

    // ---- layer-0 edge update (MFMA), msg written in CSR order ----
    edge_mfma_kernel<true><<<edgeBlocks, 256, 0, stream>>>(
        x1, e0, src, dst, pos, wB1, eb1, wB2, eb2, msg);

    // ---- layer 1: fused streaming gather + node MLP ----
    node_mlp_g1_kernel<<<nodeBlocks, 256, 0, stream>>>(
        x1, msg, offs, gw1 + D * D, gb1 + D, gw2 + D * D, gb2 + D,
        lng + D, lnb + D, x2);
  } else {
    // ---- fallback: atomic path (no CSR) ----
    float* agg = (float*)(ws + OFF_EIDX);
    hipMemsetAsync(agg, 0, SZ_X, stream);
    scatter_kernel<<<(NE * 16 + 255) / 256, 256, 0, stream>>>(x0, e0, src, dst, agg);
    node_mlp_kernel<<<nodeBlocks, 256, 0, stream>>>(
        x0, agg, gw1, gb1, gw2, gb2, lng, lnb, x1);
    hipMemsetAsync(agg, 0, SZ_X, stream);
    edge_mfma_kernel<false><<<edgeBlocks, 256, 0, stream>>>(
        x1, e0, src, dst, nullptr, wB1, eb1, wB2, eb2, agg);
    node_mlp_kernel<<<nodeBlocks, 256, 0, stream>>>(
        x1, agg, gw1 + D * D, gb1 + D, gw2 + D * D, gb2 + D, lng + D, lnb + D, x2);
  }

  // ---- head ----
  head_kernel<<<(NN + 255) / 256, 256, 0, stream>>>(x2, hw, hb, out);
}

// Round 6
// 495.369 us; speedup vs baseline: 8.0704x; 1.3548x over previous
//
#include <hip/hip_runtime.h>

#define NN 50000
#define NE 800000
#define D 64
#define K3 (3 * D)
#define LNEPS 1e-5f
#define STR 68    // f32 LDS row stride (node kernels)
#define SINB 200  // bf16 LDS row stride, edge input tile
#define SHB 72    // bf16 LDS row stride, edge hidden tile
#define SEB 68    // f32 LDS row stride, edge e-tile

typedef __attribute__((ext_vector_type(8))) short bf16x8;
typedef __attribute__((ext_vector_type(4))) float f32x4;

__device__ __forceinline__ unsigned short f2bf(float f) {
  unsigned u = __float_as_uint(f);
  u += 0x7FFF + ((u >> 16) & 1);  // RNE
  return (unsigned short)(u >> 16);
}

#define FMA4x4(v, w)                                                  \
  a0.x = fmaf(v.x, w.x, a0.x); a0.y = fmaf(v.x, w.y, a0.y);           \
  a0.z = fmaf(v.x, w.z, a0.z); a0.w = fmaf(v.x, w.w, a0.w);           \
  a1.x = fmaf(v.y, w.x, a1.x); a1.y = fmaf(v.y, w.y, a1.y);           \
  a1.z = fmaf(v.y, w.z, a1.z); a1.w = fmaf(v.y, w.w, a1.w);           \
  a2.x = fmaf(v.z, w.x, a2.x); a2.y = fmaf(v.z, w.y, a2.y);           \
  a2.z = fmaf(v.z, w.z, a2.z); a2.w = fmaf(v.z, w.w, a2.w);           \
  a3.x = fmaf(v.w, w.x, a3.x); a3.y = fmaf(v.w, w.y, a3.y);           \
  a3.z = fmaf(v.w, w.z, a3.z); a3.w = fmaf(v.w, w.w, a3.w);

// 2-row variant (512-thread blocks): a0,a1 accumulate rows t0,t0+1
#define FMA2x4(v, w)                                                  \
  a0.x = fmaf(v.x, w.x, a0.x); a0.y = fmaf(v.x, w.y, a0.y);           \
  a0.z = fmaf(v.x, w.z, a0.z); a0.w = fmaf(v.x, w.w, a0.w);           \
  a1.x = fmaf(v.y, w.x, a1.x); a1.y = fmaf(v.y, w.y, a1.y);           \
  a1.z = fmaf(v.y, w.z, a1.z); a1.w = fmaf(v.y, w.w, a1.w);

#define HSTORE_RELU(buf)                                              \
  buf[(j0+0)*STR + t0+0] = fmaxf(a0.x, 0.f);                          \
  buf[(j0+1)*STR + t0+0] = fmaxf(a0.y, 0.f);                          \
  buf[(j0+2)*STR + t0+0] = fmaxf(a0.z, 0.f);                          \
  buf[(j0+3)*STR + t0+0] = fmaxf(a0.w, 0.f);                          \
  buf[(j0+0)*STR + t0+1] = fmaxf(a1.x, 0.f);                          \
  buf[(j0+1)*STR + t0+1] = fmaxf(a1.y, 0.f);                          \
  buf[(j0+2)*STR + t0+1] = fmaxf(a1.z, 0.f);                          \
  buf[(j0+3)*STR + t0+1] = fmaxf(a1.w, 0.f);                          \
  buf[(j0+0)*STR + t0+2] = fmaxf(a2.x, 0.f);                          \
  buf[(j0+1)*STR + t0+2] = fmaxf(a2.y, 0.f);                          \
  buf[(j0+2)*STR + t0+2] = fmaxf(a2.z, 0.f);                          \
  buf[(j0+3)*STR + t0+2] = fmaxf(a2.w, 0.f);                          \
  buf[(j0+0)*STR + t0+3] = fmaxf(a3.x, 0.f);                          \
  buf[(j0+1)*STR + t0+3] = fmaxf(a3.y, 0.f);                          \
  buf[(j0+2)*STR + t0+3] = fmaxf(a3.z, 0.f);                          \
  buf[(j0+3)*STR + t0+3] = fmaxf(a3.w, 0.f);

// ---------------- CSR build ----------------
__global__ __launch_bounds__(256) void count_kernel(
    const int* __restrict__ dst, int* __restrict__ deg) {
  int e = blockIdx.x * 256 + threadIdx.x;
  if (e < NE) atomicAdd(&deg[dst[e]], 1);
}

__global__ __launch_bounds__(1024) void scan_reduce_kernel(
    const int* __restrict__ deg, int* __restrict__ bsum) {
  __shared__ int sS[16];
  int i = blockIdx.x * 1024 + threadIdx.x;
  int v = (i < NN) ? deg[i] : 0;
#pragma unroll
  for (int o = 32; o > 0; o >>= 1) v += __shfl_down(v, o, 64);
  if ((threadIdx.x & 63) == 0) sS[threadIdx.x >> 6] = v;
  __syncthreads();
  if (threadIdx.x == 0) {
    int s = 0;
#pragma unroll
    for (int k = 0; k < 16; ++k) s += sS[k];
    bsum[blockIdx.x] = s;
  }
}

__global__ __launch_bounds__(1024) void scan_final_kernel(
    const int* __restrict__ deg, const int* __restrict__ bsum,
    int* __restrict__ off, int* __restrict__ cur) {
  __shared__ int sD[1024];
  __shared__ int sOfs;
  const int t = threadIdx.x;
  const int b = blockIdx.x;
  int i = b * 1024 + t;
  int v = (i < NN) ? deg[i] : 0;
  sD[t] = v;
  if (t == 0) {
    int o = 0;
    for (int k = 0; k < b; ++k) o += bsum[k];
    sOfs = o;
  }
  __syncthreads();
  for (int st = 1; st < 1024; st <<= 1) {
    int add = (t >= st) ? sD[t - st] : 0;
    __syncthreads();
    sD[t] += add;
    __syncthreads();
  }
  if (i < NN) {
    int excl = sOfs + sD[t] - v;
    off[i] = excl;
    cur[i] = excl;
    if (i == NN - 1) off[NN] = NE;
  }
}

__global__ __launch_bounds__(256) void fill_kernel(
    const int* __restrict__ src, const int* __restrict__ dst,
    int* __restrict__ cur, int* __restrict__ eidx, int* __restrict__ gsrc) {
  int e = blockIdx.x * 256 + threadIdx.x;
  if (e < NE) {
    int p = atomicAdd(&cur[dst[e]], 1);
    eidx[p] = e;
    gsrc[p] = src[e];
  }
}

// ---------------- pack edge-MLP weights into bf16 MFMA B-fragment order ----------------
__global__ __launch_bounds__(256) void pack_weights_kernel(
    const float* __restrict__ w1, const float* __restrict__ w2,
    unsigned short* __restrict__ wB1, unsigned short* __restrict__ wB2) {
  int tid = blockIdx.x * 256 + threadIdx.x;
  const float* wsrc;
  unsigned short* wdst;
  int kb, j, slot;
  if (tid < 1536) {
    int nt = tid / 384, kk = (tid / 64) % 6, l = tid & 63;
    kb = kk * 32 + (l >> 4) * 8;
    j = nt * 16 + (l & 15);
    wsrc = w1; wdst = wB1; slot = tid;
  } else {
    int t = tid - 1536;
    int nt = t / 128, kk = (t / 64) & 1, l = t & 63;
    kb = kk * 32 + (l >> 4) * 8;
    j = nt * 16 + (l & 15);
    wsrc = w2; wdst = wB2; slot = t;
  }
  unsigned short b[8];
#pragma unroll
  for (int i = 0; i < 8; ++i) b[i] = f2bf(wsrc[(kb + i) * D + j]);
  uint4 v;
  v.x = (unsigned)b[0] | ((unsigned)b[1] << 16);
  v.y = (unsigned)b[2] | ((unsigned)b[3] << 16);
  v.z = (unsigned)b[4] | ((unsigned)b[5] << 16);
  v.w = (unsigned)b[6] | ((unsigned)b[7] << 16);
  *(uint4*)(wdst + (size_t)slot * 8) = v;
}

// ---------------- 512-thread MLP tail ----------------
__device__ __forceinline__ void mlp_tail512(
    float* sIN, float* sH, float* sPS, float* sPQ, float* sMu, float* sRs,
    const float* __restrict__ w1, const float* __restrict__ b1,
    const float* __restrict__ w2, const float* __restrict__ b2,
    const float* __restrict__ g, const float* __restrict__ bln,
    float* __restrict__ xo, int n0, int tid) {
  __syncthreads();
  const int tj = tid & 15, tt = tid >> 4;   // 16 x 32
  const int j0 = tj * 4, t0 = tt * 2;
  float4 a0, a1;

  {
    float4 bv = *(const float4*)(b1 + j0);
    a0 = a1 = bv;
    for (int k = 0; k < D; ++k) {
      float4 w = *(const float4*)(w1 + k * D + j0);
      float2 v = *(const float2*)&sIN[k * STR + t0];
      FMA2x4(v, w)
    }
  }
  sH[(j0 + 0) * STR + t0 + 0] = fmaxf(a0.x, 0.f);
  sH[(j0 + 1) * STR + t0 + 0] = fmaxf(a0.y, 0.f);
  sH[(j0 + 2) * STR + t0 + 0] = fmaxf(a0.z, 0.f);
  sH[(j0 + 3) * STR + t0 + 0] = fmaxf(a0.w, 0.f);
  sH[(j0 + 0) * STR + t0 + 1] = fmaxf(a1.x, 0.f);
  sH[(j0 + 1) * STR + t0 + 1] = fmaxf(a1.y, 0.f);
  sH[(j0 + 2) * STR + t0 + 1] = fmaxf(a1.z, 0.f);
  sH[(j0 + 3) * STR + t0 + 1] = fmaxf(a1.w, 0.f);
  __syncthreads();

  {
    float4 bv = *(const float4*)(b2 + j0);
    a0 = a1 = bv;
    for (int k = 0; k < D; ++k) {
      float4 w = *(const float4*)(w2 + k * D + j0);
      float2 v = *(const float2*)&sH[k * STR + t0];
      FMA2x4(v, w)
    }
  }
  __syncthreads();
  *(float4*)&sH[(t0 + 0) * STR + j0] = a0;
  *(float4*)&sH[(t0 + 1) * STR + j0] = a1;
  __syncthreads();

  {
    const int t = tid & 63, p = tid >> 6;   // p = 0..7, 8 feats each
    const float* r = &sH[t * STR + p * 8];
    float s = 0.f, q = 0.f;
#pragma unroll
    for (int i = 0; i < 8; ++i) { float v = r[i]; s += v; q = fmaf(v, v, q); }
    sPS[p * 64 + t] = s;
    sPQ[p * 64 + t] = q;
  }
  __syncthreads();
  if (tid < 64) {
    float s = 0.f, q = 0.f;
#pragma unroll
    for (int p = 0; p < 8; ++p) { s += sPS[p * 64 + tid]; q += sPQ[p * 64 + tid]; }
    float mu = s * (1.f / 64.f);
    float var = q * (1.f / 64.f) - mu * mu;
    sMu[tid] = mu;
    sRs[tid] = rsqrtf(var + LNEPS);
  }
  __syncthreads();

  {
    const int t = tid >> 3, c = (tid & 7) * 8;
    int node = n0 + t;
    if (node < NN) {
      float mu = sMu[t], rs = sRs[t];
      float* o = xo + (size_t)node * D + c;
#pragma unroll
      for (int i = 0; i < 2; ++i) {
        float4 v = *(const float4*)&sH[t * STR + c + i * 4];
        float4 gv = *(const float4*)(g + c + i * 4);
        float4 bv = *(const float4*)(bln + c + i * 4);
        float4 r;
        r.x = fmaxf(fmaf((v.x - mu) * rs, gv.x, bv.x), 0.f);
        r.y = fmaxf(fmaf((v.y - mu) * rs, gv.y, bv.y), 0.f);
        r.z = fmaxf(fmaf((v.z - mu) * rs, gv.z, bv.z), 0.f);
        r.w = fmaxf(fmaf((v.w - mu) * rs, gv.w, bv.w), 0.f);
        ((float4*)o)[i] = r;
      }
    }
  }
}

// ---------------- layer-0: fused CSR gather + node MLP (512 threads) ----------------
__global__ __launch_bounds__(512) void node_mlp_g0_kernel(
    const float* __restrict__ x, const float* __restrict__ e,
    const int* __restrict__ gsrc, const int* __restrict__ eidx,
    const int* __restrict__ off,
    const float* __restrict__ w1, const float* __restrict__ b1,
    const float* __restrict__ w2, const float* __restrict__ b2,
    const float* __restrict__ g, const float* __restrict__ bln,
    float* __restrict__ xo) {
  __shared__ float sIN[D * STR];
  __shared__ float sH[D * STR];
  __shared__ float sPS[512], sPQ[512], sMu[64], sRs[64];
  const int tid = threadIdx.x;
  const int n0 = blockIdx.x * 64;
  const int wv = tid >> 6, lane = tid & 63;  // 8 waves x 8 nodes
  for (int q = 0; q < 8; ++q) {
    int t = wv * 8 + q;
    int node = n0 + t;
    float acc = 0.f;
    if (node < NN) {
      acc = x[(size_t)node * D + lane];  // self term
      int beg = off[node], end = off[node + 1];
      int i = beg;
      for (; i + 1 < end; i += 2) {
        int ea = eidx[i],     sa = gsrc[i];
        int eb = eidx[i + 1], sb = gsrc[i + 1];
        float xa = x[(size_t)sa * D + lane];
        float va = e[(size_t)ea * D + lane];
        float xb = x[(size_t)sb * D + lane];
        float vb = e[(size_t)eb * D + lane];
        acc += fmaxf(xa + va, 0.f) + fmaxf(xb + vb, 0.f);
      }
      if (i < end) {
        int ea = eidx[i], sa = gsrc[i];
        acc += fmaxf(x[(size_t)sa * D + lane] + e[(size_t)ea * D + lane], 0.f);
      }
    }
    sIN[lane * STR + t] = acc;
  }
  mlp_tail512(sIN, sH, sPS, sPQ, sMu, sRs, w1, b1, w2, b2, g, bln, xo, n0, tid);
}

// ---------------- layer-1: fused streaming gather + node MLP (512 threads) ----------------
__global__ __launch_bounds__(512) void node_mlp_g1_kernel(
    const float* __restrict__ x, const float* __restrict__ msg,
    const int* __restrict__ off,
    const float* __restrict__ w1, const float* __restrict__ b1,
    const float* __restrict__ w2, const float* __restrict__ b2,
    const float* __restrict__ g, const float* __restrict__ bln,
    float* __restrict__ xo) {
  __shared__ float sIN[D * STR];
  __shared__ float sH[D * STR];
  __shared__ float sPS[512], sPQ[512], sMu[64], sRs[64];
  const int tid = threadIdx.x;
  const int n0 = blockIdx.x * 64;
  const int wv = tid >> 6, lane = tid & 63;
  for (int q = 0; q < 8; ++q) {
    int t = wv * 8 + q;
    int node = n0 + t;
    float acc = 0.f;
    if (node < NN) {
      acc = x[(size_t)node * D + lane];
      int beg = off[node], end = off[node + 1];
      const float* mr = msg + (size_t)beg * D + lane;
      int cnt = end - beg, i = 0;
      for (; i + 3 < cnt; i += 4) {
        float m0 = mr[(size_t)(i + 0) * D];
        float m1 = mr[(size_t)(i + 1) * D];
        float m2 = mr[(size_t)(i + 2) * D];
        float m3 = mr[(size_t)(i + 3) * D];
        acc += (m0 + m1) + (m2 + m3);
      }
      for (; i < cnt; ++i) acc += mr[(size_t)i * D];
    }
    sIN[lane * STR + t] = acc;
  }
  mlp_tail512(sIN, sH, sPS, sPQ, sMu, sRs, w1, b1, w2, b2, g, bln, xo, n0, tid);
}

// ---------------- MFMA edge MLP over CSR slots; msg[slot] contiguous ----------------
__global__ __launch_bounds__(256) void edge_mfma_csr_kernel(
    const float* __restrict__ x, const float* __restrict__ e,
    const int* __restrict__ eidx, const int* __restrict__ gsrc,
    const int* __restrict__ dst,
    const unsigned short* __restrict__ wB1, const float* __restrict__ b1,
    const unsigned short* __restrict__ wB2, const float* __restrict__ b2,
    float* __restrict__ msg) {
  __shared__ unsigned short sIN[64 * SINB];
  __shared__ unsigned short sH[64 * SHB];
  __shared__ float sE[64 * SEB];

  const int tid = threadIdx.x;
  const int e0 = blockIdx.x * 64;  // CSR slot base
  const int lane = tid & 63;
  const int mt = tid >> 6;
  const int hl = lane >> 4;
  const int ll = lane & 15;

  {
    const int t = tid & 63, p = tid >> 6;
    int slot = e0 + t;
    int eid = eidx[slot];
    int sN = gsrc[slot], dN = dst[eid];
    const float* g0 = x + (size_t)sN * D + p * 16;
    const float* g1 = x + (size_t)dN * D + p * 16;
    const float* g2 = e + (size_t)eid * D + p * 16;
    unsigned short* row = sIN + t * SINB + p * 16;
#pragma unroll
    for (int i = 0; i < 4; ++i) {
      float4 v0 = ((const float4*)g0)[i];
      float4 v1 = ((const float4*)g1)[i];
      float4 v2 = ((const float4*)g2)[i];
      uint2 u;
      u.x = (unsigned)f2bf(v0.x) | ((unsigned)f2bf(v0.y) << 16);
      u.y = (unsigned)f2bf(v0.z) | ((unsigned)f2bf(v0.w) << 16);
      *(uint2*)(row + i * 4) = u;
      u.x = (unsigned)f2bf(v1.x) | ((unsigned)f2bf(v1.y) << 16);
      u.y = (unsigned)f2bf(v1.z) | ((unsigned)f2bf(v1.w) << 16);
      *(uint2*)(row + 64 + i * 4) = u;
      u.x = (unsigned)f2bf(v2.x) | ((unsigned)f2bf(v2.y) << 16);
      u.y = (unsigned)f2bf(v2.z) | ((unsigned)f2bf(v2.w) << 16);
      *(uint2*)(row + 128 + i * 4) = u;
      *(float4*)&sE[t * SEB + p * 16 + i * 4] = v2;
    }
  }
  __syncthreads();

  f32x4 acc[4];
#pragma unroll
  for (int nt = 0; nt < 4; ++nt) {
    float b = b1[nt * 16 + ll];
    acc[nt].x = b; acc[nt].y = b; acc[nt].z = b; acc[nt].w = b;
  }
  {
    const unsigned short* aBase = sIN + (mt * 16 + ll) * SINB + hl * 8;
#pragma unroll
    for (int kk = 0; kk < 6; ++kk) {
      bf16x8 af = *(const bf16x8*)(aBase + kk * 32);
#pragma unroll
      for (int nt = 0; nt < 4; ++nt) {
        bf16x8 bf = *(const bf16x8*)(wB1 + ((size_t)(nt * 6 + kk) * 64 + lane) * 8);
        acc[nt] = __builtin_amdgcn_mfma_f32_16x16x32_bf16(af, bf, acc[nt], 0, 0, 0);
      }
    }
  }
#pragma unroll
  for (int nt = 0; nt < 4; ++nt)
#pragma unroll
    for (int r = 0; r < 4; ++r)
      sH[(mt * 16 + hl * 4 + r) * SHB + nt * 16 + ll] = f2bf(fmaxf(acc[nt][r], 0.f));
  __syncthreads();

  f32x4 acc2[4];
#pragma unroll
  for (int nt = 0; nt < 4; ++nt) {
    float b = b2[nt * 16 + ll];
    acc2[nt].x = b; acc2[nt].y = b; acc2[nt].z = b; acc2[nt].w = b;
  }
  {
    const unsigned short* hBase = sH + (mt * 16 + ll) * SHB + hl * 8;
#pragma unroll
    for (int kk = 0; kk < 2; ++kk) {
      bf16x8 af = *(const bf16x8*)(hBase + kk * 32);
#pragma unroll
      for (int nt = 0; nt < 4; ++nt) {
        bf16x8 bf = *(const bf16x8*)(wB2 + ((size_t)(nt * 2 + kk) * 64 + lane) * 8);
        acc2[nt] = __builtin_amdgcn_mfma_f32_16x16x32_bf16(af, bf, acc2[nt], 0, 0, 0);
      }
    }
  }

#pragma unroll
  for (int r = 0; r < 4; ++r) {
    int t = mt * 16 + hl * 4 + r;
    int slot = e0 + t;
    int sN = gsrc[slot];
    const float* xr = x + (size_t)sN * D;
    const float* er = &sE[t * SEB];
    float* mr = msg + (size_t)slot * D;
#pragma unroll
    for (int nt = 0; nt < 4; ++nt) {
      int j = nt * 16 + ll;
      mr[j] = fmaxf(xr[j] + fmaf(0.5f, acc2[nt][r], er[j]), 0.f);
    }
  }
}

// ---------------- legacy kernels (fallback tier) ----------------
__global__ __launch_bounds__(256) void scatter_kernel(
    const float* __restrict__ x, const float* __restrict__ e,
    const int* __restrict__ src, const int* __restrict__ dst,
    float* __restrict__ agg) {
  int tid = blockIdx.x * blockDim.x + threadIdx.x;
  if (tid >= NE * 16) return;
  int eid = tid >> 4, q = tid & 15;
  int s = src[eid], d = dst[eid];
  float4 xv = ((const float4*)(x + (size_t)s * D))[q];
  float4 ev = ((const float4*)(e + (size_t)eid * D))[q];
  float* a = agg + (size_t)d * D + q * 4;
  atomicAdd(a + 0, fmaxf(xv.x + ev.x, 0.f));
  atomicAdd(a + 1, fmaxf(xv.y + ev.y, 0.f));
  atomicAdd(a + 2, fmaxf(xv.z + ev.z, 0.f));
  atomicAdd(a + 3, fmaxf(xv.w + ev.w, 0.f));
}

__device__ __forceinline__ void mlp_tail256(
    float* sIN, float* sH, float* sPS, float* sPQ, float* sMu, float* sRs,
    const float* __restrict__ w1, const float* __restrict__ b1,
    const float* __restrict__ w2, const float* __restrict__ b2,
    const float* __restrict__ g, const float* __restrict__ bln,
    float* __restrict__ xo, int n0, int tid) {
  __syncthreads();
  const int tj = tid & 15, tt = tid >> 4;
  const int j0 = tj * 4, t0 = tt * 4;
  float4 a0, a1, a2, a3;
  {
    float4 bv = *(const float4*)(b1 + j0);
    a0 = a1 = a2 = a3 = bv;
    for (int k = 0; k < D; ++k) {
      float4 w = *(const float4*)(w1 + k * D + j0);
      float4 v = *(const float4*)&sIN[k * STR + t0];
      FMA4x4(v, w)
    }
  }
  HSTORE_RELU(sH)
  __syncthreads();
  {
    float4 bv = *(const float4*)(b2 + j0);
    a0 = a1 = a2 = a3 = bv;
    for (int k = 0; k < D; ++k) {
      float4 w = *(const float4*)(w2 + k * D + j0);
      float4 v = *(const float4*)&sH[k * STR + t0];
      FMA4x4(v, w)
    }
  }
  __syncthreads();
  *(float4*)&sH[(t0 + 0) * STR + j0] = a0;
  *(float4*)&sH[(t0 + 1) * STR + j0] = a1;
  *(float4*)&sH[(t0 + 2) * STR + j0] = a2;
  *(float4*)&sH[(t0 + 3) * STR + j0] = a3;
  __syncthreads();
  {
    const int t = tid & 63, p = tid >> 6;
    const float* r = &sH[t * STR + p * 16];
    float s = 0.f, q = 0.f;
#pragma unroll
    for (int i = 0; i < 16; ++i) { float v = r[i]; s += v; q = fmaf(v, v, q); }
    sPS[p * 64 + t] = s;
    sPQ[p * 64 + t] = q;
  }
  __syncthreads();
  if (tid < 64) {
    float s = sPS[tid] + sPS[64 + tid] + sPS[128 + tid] + sPS[192 + tid];
    float q = sPQ[tid] + sPQ[64 + tid] + sPQ[128 + tid] + sPQ[192 + tid];
    float mu = s * (1.f / 64.f);
    float var = q * (1.f / 64.f) - mu * mu;
    sMu[tid] = mu;
    sRs[tid] = rsqrtf(var + LNEPS);
  }
  __syncthreads();
  {
    const int t = tid >> 2, c = (tid & 3) * 16;
    int node = n0 + t;
    if (node < NN) {
      float mu = sMu[t], rs = sRs[t];
      float* o = xo + (size_t)node * D + c;
#pragma unroll
      for (int i = 0; i < 4; ++i) {
        float4 v = *(const float4*)&sH[t * STR + c + i * 4];
        float4 gv = *(const float4*)(g + c + i * 4);
        float4 bv = *(const float4*)(bln + c + i * 4);
        float4 r;
        r.x = fmaxf(fmaf((v.x - mu) * rs, gv.x, bv.x), 0.f);
        r.y = fmaxf(fmaf((v.y - mu) * rs, gv.y, bv.y), 0.f);
        r.z = fmaxf(fmaf((v.z - mu) * rs, gv.z, bv.z), 0.f);
        r.w = fmaxf(fmaf((v.w - mu) * rs, gv.w, bv.w), 0.f);
        ((float4*)o)[i] = r;
      }
    }
  }
}

__global__ __launch_bounds__(256) void node_mlp_kernel(
    const float* __restrict__ x, const float* __restrict__ agg,
    const float* __restrict__ w1, const float* __restrict__ b1,
    const float* __restrict__ w2, const float* __restrict__ b2,
    const float* __restrict__ g, const float* __restrict__ bln,
    float* __restrict__ xo) {
  __shared__ float sIN[D * STR];
  __shared__ float sH[D * STR];
  __shared__ float sPS[256], sPQ[256], sMu[64], sRs[64];
  const int tid = threadIdx.x;
  const int n0 = blockIdx.x * 64;
  {
    const int t = tid & 63, p = tid >> 6;
    int node = n0 + t;
    int cn = node < NN ? node : 0;
    const float* xr = x + (size_t)cn * D + p * 16;
    const float* ar = agg + (size_t)cn * D + p * 16;
#pragma unroll
    for (int i = 0; i < 4; ++i) {
      float4 xv = ((const float4*)xr)[i];
      float4 av = ((const float4*)ar)[i];
      int k = p * 16 + i * 4;
      sIN[(k + 0) * STR + t] = xv.x + av.x;
      sIN[(k + 1) * STR + t] = xv.y + av.y;
      sIN[(k + 2) * STR + t] = xv.z + av.z;
      sIN[(k + 3) * STR + t] = xv.w + av.w;
    }
  }
  mlp_tail256(sIN, sH, sPS, sPQ, sMu, sRs, w1, b1, w2, b2, g, bln, xo, n0, tid);
}

__global__ __launch_bounds__(256) void edge_mfma_atomic_kernel(
    const float* __restrict__ x, const float* __restrict__ e,
    const int* __restrict__ src, const int* __restrict__ dst,
    const unsigned short* __restrict__ wB1, const float* __restrict__ b1,
    const unsigned short* __restrict__ wB2, const float* __restrict__ b2,
    float* __restrict__ agg) {
  __shared__ unsigned short sIN[64 * SINB];
  __shared__ unsigned short sH[64 * SHB];
  __shared__ float sE[64 * SEB];
  const int tid = threadIdx.x;
  const int e0 = blockIdx.x * 64;
  const int lane = tid & 63;
  const int mt = tid >> 6;
  const int hl = lane >> 4;
  const int ll = lane & 15;
  {
    const int t = tid & 63, p = tid >> 6;
    int eid = e0 + t;
    int sN = src[eid], dN = dst[eid];
    const float* g0 = x + (size_t)sN * D + p * 16;
    const float* g1 = x + (size_t)dN * D + p * 16;
    const float* g2 = e + (size_t)eid * D + p * 16;
    unsigned short* row = sIN + t * SINB + p * 16;
#pragma unroll
    for (int i = 0; i < 4; ++i) {
      float4 v0 = ((const float4*)g0)[i];
      float4 v1 = ((const float4*)g1)[i];
      float4 v2 = ((const float4*)g2)[i];
      uint2 u;
      u.x = (unsigned)f2bf(v0.x) | ((unsigned)f2bf(v0.y) << 16);
      u.y = (unsigned)f2bf(v0.z) | ((unsigned)f2bf(v0.w) << 16);
      *(uint2*)(row + i * 4) = u;
      u.x = (unsigned)f2bf(v1.x) | ((unsigned)f2bf(v1.y) << 16);
      u.y = (unsigned)f2bf(v1.z) | ((unsigned)f2bf(v1.w) << 16);
      *(uint2*)(row + 64 + i * 4) = u;
      u.x = (unsigned)f2bf(v2.x) | ((unsigned)f2bf(v2.y) << 16);
      u.y = (unsigned)f2bf(v2.z) | ((unsigned)f2bf(v2.w) << 16);
      *(uint2*)(row + 128 + i * 4) = u;
      *(float4*)&sE[t * SEB + p * 16 + i * 4] = v2;
    }
  }
  __syncthreads();
  f32x4 acc[4];
#pragma unroll
  for (int nt = 0; nt < 4; ++nt) {
    float b = b1[nt * 16 + ll];
    acc[nt].x = b; acc[nt].y = b; acc[nt].z = b; acc[nt].w = b;
  }
  {
    const unsigned short* aBase = sIN + (mt * 16 + ll) * SINB + hl * 8;
#pragma unroll
    for (int kk = 0; kk < 6; ++kk) {
      bf16x8 af = *(const bf16x8*)(aBase + kk * 32);
#pragma unroll
      for (int nt = 0; nt < 4; ++nt) {
        bf16x8 bf = *(const bf16x8*)(wB1 + ((size_t)(nt * 6 + kk) * 64 + lane) * 8);
        acc[nt] = __builtin_amdgcn_mfma_f32_16x16x32_bf16(af, bf, acc[nt], 0, 0, 0);
      }
    }
  }
#pragma unroll
  for (int nt = 0; nt < 4; ++nt)
#pragma unroll
    for (int r = 0; r < 4; ++r)
      sH[(mt * 16 + hl * 4 + r) * SHB + nt * 16 + ll] = f2bf(fmaxf(acc[nt][r], 0.f));
  __syncthreads();
  f32x4 acc2[4];
#pragma unroll
  for (int nt = 0; nt < 4; ++nt) {
    float b = b2[nt * 16 + ll];
    acc2[nt].x = b; acc2[nt].y = b; acc2[nt].z = b; acc2[nt].w = b;
  }
  {
    const unsigned short* hBase = sH + (mt * 16 + ll) * SHB + hl * 8;
#pragma unroll
    for (int kk = 0; kk < 2; ++kk) {
      bf16x8 af = *(const bf16x8*)(hBase + kk * 32);
#pragma unroll
      for (int nt = 0; nt < 4; ++nt) {
        bf16x8 bf = *(const bf16x8*)(wB2 + ((size_t)(nt * 2 + kk) * 64 + lane) * 8);
        acc2[nt] = __builtin_amdgcn_mfma_f32_16x16x32_bf16(af, bf, acc2[nt], 0, 0, 0);
      }
    }
  }
#pragma unroll
  for (int r = 0; r < 4; ++r) {
    int t = mt * 16 + hl * 4 + r;
    int eid = e0 + t;
    int sN = src[eid], dN = dst[eid];
    const float* xr = x + (size_t)sN * D;
    const float* er = &sE[t * SEB];
    float* ar = agg + (size_t)dN * D;
#pragma unroll
    for (int nt = 0; nt < 4; ++nt) {
      int j = nt * 16 + ll;
      atomicAdd(ar + j, fmaxf(xr[j] + fmaf(0.5f, acc2[nt][r], er[j]), 0.f));
    }
  }
}

// ---------------- head ----------------
__global__ __launch_bounds__(256) void head_kernel(
    const float* __restrict__ x, const float* __restrict__ w,
    const float* __restrict__ b, float* __restrict__ out) {
  int nid = blockIdx.x * blockDim.x + threadIdx.x;
  if (nid >= NN) return;
  const float* xr = x + (size_t)nid * D;
  float a0 = b[0], a1 = b[1];
  for (int k = 0; k < D; ++k) {
    float v = xr[k];
    a0 = fmaf(v, w[k * 2 + 0], a0);
    a1 = fmaf(v, w[k * 2 + 1], a1);
  }
  out[nid * 2 + 0] = a0;
  out[nid * 2 + 1] = a1;
}

extern "C" void kernel_launch(void* const* d_in, const int* in_sizes, int n_in,
                              void* d_out, int out_size, void* d_ws, size_t ws_size,
                              hipStream_t stream) {
  const float* x0  = (const float*)d_in[0];
  const float* e0  = (const float*)d_in[1];
  const int*   ei  = (const int*)d_in[2];
  const float* gw1 = (const float*)d_in[3];
  const float* gb1 = (const float*)d_in[4];
  const float* gw2 = (const float*)d_in[5];
  const float* gb2 = (const float*)d_in[6];
  const float* ew1 = (const float*)d_in[7];
  const float* eb1 = (const float*)d_in[8];
  const float* ew2 = (const float*)d_in[9];
  const float* eb2 = (const float*)d_in[10];
  const float* lng = (const float*)d_in[11];
  const float* lnb = (const float*)d_in[12];
  const float* hw  = (const float*)d_in[13];
  const float* hb  = (const float*)d_in[14];
  float* out = (float*)d_out;

  char* ws = (char*)d_ws;
  const size_t SZ_X     = (size_t)NN * D * 4;          // 12.8 MB
  const size_t OFF_X1   = 0;
  const size_t OFF_X2   = OFF_X1 + SZ_X;
  const size_t OFF_WB1  = OFF_X2 + SZ_X;
  const size_t OFF_WB2  = OFF_WB1 + 24576;
  const size_t OFF_DEG  = OFF_WB2 + 8192;
  const size_t OFF_OFFS = OFF_DEG + 200704;
  const size_t OFF_CUR  = OFF_OFFS + 200704;
  const size_t OFF_BSUM = OFF_CUR + 200704;
  const size_t OFF_EIDX = OFF_BSUM + 512;
  const size_t OFF_GSRC = OFF_EIDX + (size_t)NE * 4;
  const size_t OFF_MSG  = OFF_GSRC + (size_t)NE * 4;
  const size_t NEED_A   = OFF_MSG + (size_t)NE * D * 4;  // ~237.4 MB

  float* x1   = (float*)(ws + OFF_X1);
  float* x2   = (float*)(ws + OFF_X2);
  unsigned short* wB1 = (unsigned short*)(ws + OFF_WB1);
  unsigned short* wB2 = (unsigned short*)(ws + OFF_WB2);
  int* deg  = (int*)(ws + OFF_DEG);
  int* offs = (int*)(ws + OFF_OFFS);
  int* cur  = (int*)(ws + OFF_CUR);
  int* bsum = (int*)(ws + OFF_BSUM);
  int* eidx = (int*)(ws + OFF_EIDX);
  int* gsrc = (int*)(ws + OFF_GSRC);
  float* msg = (float*)(ws + OFF_MSG);

  const int* src = ei;
  const int* dst = ei + NE;

  const int nodeBlocks = (NN + 63) / 64;     // 782
  const int edgeBlocks = NE / 64;            // 12500
  const int scanBlocks = (NN + 1023) / 1024; // 49

  pack_weights_kernel<<<8, 256, 0, stream>>>(ew1, ew2, wB1, wB2);

  if (ws_size >= NEED_A) {
    // ---- CSR build (by dst) ----
    hipMemsetAsync(deg, 0, (size_t)NN * 4, stream);
    count_kernel<<<(NE + 255) / 256, 256, 0, stream>>>(dst, deg);
    scan_reduce_kernel<<<scanBlocks, 1024, 0, stream>>>(deg, bsum);
    scan_final_kernel<<<scanBlocks, 1024, 0, stream>>>(deg, bsum, offs, cur);
    fill_kernel<<<(NE + 255) / 256, 256, 0, stream>>>(src, dst, cur, eidx, gsrc);

    // ---- layer 0: fused gather + node MLP ----
    node_mlp_g0_kernel<<<nodeBlocks, 512, 0, stream>>>(
        x0, e0, gsrc, eidx, offs, gw1, gb1, gw2, gb2, lng, lnb, x1);

    // ---- layer-0 edge update (MFMA) over CSR slots ----
    edge_mfma_csr_kernel<<<edgeBlocks, 256, 0, stream>>>(
        x1, e0, eidx, gsrc, dst, wB1, eb1, wB2, eb2, msg);

    // ---- layer 1: fused streaming gather + node MLP ----
    node_mlp_g1_kernel<<<nodeBlocks, 512, 0, stream>>>(
        x1, msg, offs, gw1 + D * D, gb1 + D, gw2 + D * D, gb2 + D,
        lng + D, lnb + D, x2);
  } else {
    // ---- fallback: atomic path (no CSR) ----
    float* agg = (float*)(ws + OFF_EIDX);
    hipMemsetAsync(agg, 0, SZ_X, stream);
    scatter_kernel<<<(NE * 16 + 255) / 256, 256, 0, stream>>>(x0, e0, src, dst, agg);
    node_mlp_kernel<<<nodeBlocks, 256, 0, stream>>>(
        x0, agg, gw1, gb1, gw2, gb2, lng, lnb, x1);
    hipMemsetAsync(agg, 0, SZ_X, stream);
    edge_mfma_atomic_kernel<<<edgeBlocks, 256, 0, stream>>>(
        x1, e0, src, dst, wB1, eb1, wB2, eb2, agg);
    node_mlp_kernel<<<nodeBlocks, 256, 0, stream>>>(
        x1, agg, gw1 + D * D, gb1 + D, gw2 + D * D, gb2 + D, lng + D, lnb + D, x2);
  }

  // ---- head ----
  head_kernel<<<(NN + 255) / 256, 256, 0, stream>>>(x2, hw, hb, out);
}

// Round 7
// 469.246 us; speedup vs baseline: 8.5196x; 1.0557x over previous
//
#include <hip/hip_runtime.h>

#define NN 50000
#define NE 800000
#define D 64
#define K3 (3 * D)
#define LNEPS 1e-5f
#define STR 68    // f32 LDS row stride (node kernels)
#define SINB 200  // bf16 LDS row stride, edge input tile
#define SHB 72    // bf16 LDS row stride, edge hidden tile
#define SEB 68    // f32 LDS row stride (fallback edge kernel)

typedef __attribute__((ext_vector_type(8))) short bf16x8;
typedef __attribute__((ext_vector_type(4))) float f32x4;

__device__ __forceinline__ unsigned short f2bf(float f) {
  unsigned u = __float_as_uint(f);
  u += 0x7FFF + ((u >> 16) & 1);  // RNE
  return (unsigned short)(u >> 16);
}
__device__ __forceinline__ float bf2f(unsigned short s) {
  return __uint_as_float((unsigned)s << 16);
}

#define FMA4x4(v, w)                                                  \
  a0.x = fmaf(v.x, w.x, a0.x); a0.y = fmaf(v.x, w.y, a0.y);           \
  a0.z = fmaf(v.x, w.z, a0.z); a0.w = fmaf(v.x, w.w, a0.w);           \
  a1.x = fmaf(v.y, w.x, a1.x); a1.y = fmaf(v.y, w.y, a1.y);           \
  a1.z = fmaf(v.y, w.z, a1.z); a1.w = fmaf(v.y, w.w, a1.w);           \
  a2.x = fmaf(v.z, w.x, a2.x); a2.y = fmaf(v.z, w.y, a2.y);           \
  a2.z = fmaf(v.z, w.z, a2.z); a2.w = fmaf(v.z, w.w, a2.w);           \
  a3.x = fmaf(v.w, w.x, a3.x); a3.y = fmaf(v.w, w.y, a3.y);           \
  a3.z = fmaf(v.w, w.z, a3.z); a3.w = fmaf(v.w, w.w, a3.w);

#define FMA2x4(v, w)                                                  \
  a0.x = fmaf(v.x, w.x, a0.x); a0.y = fmaf(v.x, w.y, a0.y);           \
  a0.z = fmaf(v.x, w.z, a0.z); a0.w = fmaf(v.x, w.w, a0.w);           \
  a1.x = fmaf(v.y, w.x, a1.x); a1.y = fmaf(v.y, w.y, a1.y);           \
  a1.z = fmaf(v.y, w.z, a1.z); a1.w = fmaf(v.y, w.w, a1.w);

#define HSTORE_RELU(buf)                                              \
  buf[(j0+0)*STR + t0+0] = fmaxf(a0.x, 0.f);                          \
  buf[(j0+1)*STR + t0+0] = fmaxf(a0.y, 0.f);                          \
  buf[(j0+2)*STR + t0+0] = fmaxf(a0.z, 0.f);                          \
  buf[(j0+3)*STR + t0+0] = fmaxf(a0.w, 0.f);                          \
  buf[(j0+0)*STR + t0+1] = fmaxf(a1.x, 0.f);                          \
  buf[(j0+1)*STR + t0+1] = fmaxf(a1.y, 0.f);                          \
  buf[(j0+2)*STR + t0+1] = fmaxf(a1.z, 0.f);                          \
  buf[(j0+3)*STR + t0+1] = fmaxf(a1.w, 0.f);                          \
  buf[(j0+0)*STR + t0+2] = fmaxf(a2.x, 0.f);                          \
  buf[(j0+1)*STR + t0+2] = fmaxf(a2.y, 0.f);                          \
  buf[(j0+2)*STR + t0+2] = fmaxf(a2.z, 0.f);                          \
  buf[(j0+3)*STR + t0+2] = fmaxf(a2.w, 0.f);                          \
  buf[(j0+0)*STR + t0+3] = fmaxf(a3.x, 0.f);                          \
  buf[(j0+1)*STR + t0+3] = fmaxf(a3.y, 0.f);                          \
  buf[(j0+2)*STR + t0+3] = fmaxf(a3.z, 0.f);                          \
  buf[(j0+3)*STR + t0+3] = fmaxf(a3.w, 0.f);

// ---------------- CSR build ----------------
__global__ __launch_bounds__(256) void count_kernel(
    const int* __restrict__ dst, int* __restrict__ deg) {
  int e = blockIdx.x * 256 + threadIdx.x;
  if (e < NE) atomicAdd(&deg[dst[e]], 1);
}

__global__ __launch_bounds__(1024) void scan_reduce_kernel(
    const int* __restrict__ deg, int* __restrict__ bsum) {
  __shared__ int sS[16];
  int i = blockIdx.x * 1024 + threadIdx.x;
  int v = (i < NN) ? deg[i] : 0;
#pragma unroll
  for (int o = 32; o > 0; o >>= 1) v += __shfl_down(v, o, 64);
  if ((threadIdx.x & 63) == 0) sS[threadIdx.x >> 6] = v;
  __syncthreads();
  if (threadIdx.x == 0) {
    int s = 0;
#pragma unroll
    for (int k = 0; k < 16; ++k) s += sS[k];
    bsum[blockIdx.x] = s;
  }
}

__global__ __launch_bounds__(1024) void scan_final_kernel(
    const int* __restrict__ deg, const int* __restrict__ bsum,
    int* __restrict__ off, int* __restrict__ cur) {
  __shared__ int sD[1024];
  __shared__ int sOfs;
  const int t = threadIdx.x;
  const int b = blockIdx.x;
  int i = b * 1024 + t;
  int v = (i < NN) ? deg[i] : 0;
  sD[t] = v;
  if (t == 0) {
    int o = 0;
    for (int k = 0; k < b; ++k) o += bsum[k];
    sOfs = o;
  }
  __syncthreads();
  for (int st = 1; st < 1024; st <<= 1) {
    int add = (t >= st) ? sD[t - st] : 0;
    __syncthreads();
    sD[t] += add;
    __syncthreads();
  }
  if (i < NN) {
    int excl = sOfs + sD[t] - v;
    off[i] = excl;
    cur[i] = excl;
    if (i == NN - 1) off[NN] = NE;
  }
}

// epair[p] = {eid, src[eid]} in CSR slot order
__global__ __launch_bounds__(256) void fill_kernel(
    const int* __restrict__ src, const int* __restrict__ dst,
    int* __restrict__ cur, int2* __restrict__ epair) {
  int e = blockIdx.x * 256 + threadIdx.x;
  if (e < NE) {
    int p = atomicAdd(&cur[dst[e]], 1);
    epair[p] = make_int2(e, src[e]);
  }
}

// ---------------- pack edge-MLP weights into bf16 MFMA B-fragment order ----------------
__global__ __launch_bounds__(256) void pack_weights_kernel(
    const float* __restrict__ w1, const float* __restrict__ w2,
    unsigned short* __restrict__ wB1, unsigned short* __restrict__ wB2) {
  int tid = blockIdx.x * 256 + threadIdx.x;
  const float* wsrc;
  unsigned short* wdst;
  int kb, j, slot;
  if (tid < 1536) {
    int nt = tid / 384, kk = (tid / 64) % 6, l = tid & 63;
    kb = kk * 32 + (l >> 4) * 8;
    j = nt * 16 + (l & 15);
    wsrc = w1; wdst = wB1; slot = tid;
  } else {
    int t = tid - 1536;
    int nt = t / 128, kk = (t / 64) & 1, l = t & 63;
    kb = kk * 32 + (l >> 4) * 8;
    j = nt * 16 + (l & 15);
    wsrc = w2; wdst = wB2; slot = t;
  }
  unsigned short b[8];
#pragma unroll
  for (int i = 0; i < 8; ++i) b[i] = f2bf(wsrc[(kb + i) * D + j]);
  uint4 v;
  v.x = (unsigned)b[0] | ((unsigned)b[1] << 16);
  v.y = (unsigned)b[2] | ((unsigned)b[3] << 16);
  v.z = (unsigned)b[4] | ((unsigned)b[5] << 16);
  v.w = (unsigned)b[6] | ((unsigned)b[7] << 16);
  *(uint4*)(wdst + (size_t)slot * 8) = v;
}

// ---------------- 512-thread MLP tail ----------------
__device__ __forceinline__ void mlp_tail512(
    float* sIN, float* sH, float* sPS, float* sPQ, float* sMu, float* sRs,
    const float* __restrict__ w1, const float* __restrict__ b1,
    const float* __restrict__ w2, const float* __restrict__ b2,
    const float* __restrict__ g, const float* __restrict__ bln,
    float* __restrict__ xo, int n0, int tid) {
  __syncthreads();
  const int tj = tid & 15, tt = tid >> 4;   // 16 x 32
  const int j0 = tj * 4, t0 = tt * 2;
  float4 a0, a1;

  {
    float4 bv = *(const float4*)(b1 + j0);
    a0 = a1 = bv;
    for (int k = 0; k < D; ++k) {
      float4 w = *(const float4*)(w1 + k * D + j0);
      float2 v = *(const float2*)&sIN[k * STR + t0];
      FMA2x4(v, w)
    }
  }
  sH[(j0 + 0) * STR + t0 + 0] = fmaxf(a0.x, 0.f);
  sH[(j0 + 1) * STR + t0 + 0] = fmaxf(a0.y, 0.f);
  sH[(j0 + 2) * STR + t0 + 0] = fmaxf(a0.z, 0.f);
  sH[(j0 + 3) * STR + t0 + 0] = fmaxf(a0.w, 0.f);
  sH[(j0 + 0) * STR + t0 + 1] = fmaxf(a1.x, 0.f);
  sH[(j0 + 1) * STR + t0 + 1] = fmaxf(a1.y, 0.f);
  sH[(j0 + 2) * STR + t0 + 1] = fmaxf(a1.z, 0.f);
  sH[(j0 + 3) * STR + t0 + 1] = fmaxf(a1.w, 0.f);
  __syncthreads();

  {
    float4 bv = *(const float4*)(b2 + j0);
    a0 = a1 = bv;
    for (int k = 0; k < D; ++k) {
      float4 w = *(const float4*)(w2 + k * D + j0);
      float2 v = *(const float2*)&sH[k * STR + t0];
      FMA2x4(v, w)
    }
  }
  __syncthreads();
  *(float4*)&sH[(t0 + 0) * STR + j0] = a0;
  *(float4*)&sH[(t0 + 1) * STR + j0] = a1;
  __syncthreads();

  {
    const int t = tid & 63, p = tid >> 6;
    const float* r = &sH[t * STR + p * 8];
    float s = 0.f, q = 0.f;
#pragma unroll
    for (int i = 0; i < 8; ++i) { float v = r[i]; s += v; q = fmaf(v, v, q); }
    sPS[p * 64 + t] = s;
    sPQ[p * 64 + t] = q;
  }
  __syncthreads();
  if (tid < 64) {
    float s = 0.f, q = 0.f;
#pragma unroll
    for (int p = 0; p < 8; ++p) { s += sPS[p * 64 + tid]; q += sPQ[p * 64 + tid]; }
    float mu = s * (1.f / 64.f);
    float var = q * (1.f / 64.f) - mu * mu;
    sMu[tid] = mu;
    sRs[tid] = rsqrtf(var + LNEPS);
  }
  __syncthreads();

  {
    const int t = tid >> 3, c = (tid & 7) * 8;
    int node = n0 + t;
    if (node < NN) {
      float mu = sMu[t], rs = sRs[t];
      float* o = xo + (size_t)node * D + c;
#pragma unroll
      for (int i = 0; i < 2; ++i) {
        float4 v = *(const float4*)&sH[t * STR + c + i * 4];
        float4 gv = *(const float4*)(g + c + i * 4);
        float4 bv = *(const float4*)(bln + c + i * 4);
        float4 r;
        r.x = fmaxf(fmaf((v.x - mu) * rs, gv.x, bv.x), 0.f);
        r.y = fmaxf(fmaf((v.y - mu) * rs, gv.y, bv.y), 0.f);
        r.z = fmaxf(fmaf((v.z - mu) * rs, gv.z, bv.z), 0.f);
        r.w = fmaxf(fmaf((v.w - mu) * rs, gv.w, bv.w), 0.f);
        ((float4*)o)[i] = r;
      }
    }
  }
}

// ---------------- layer-0: fused CSR gather + node MLP (512 threads) ----------------
__global__ __launch_bounds__(512) void node_mlp_g0_kernel(
    const float* __restrict__ x, const float* __restrict__ e,
    const int2* __restrict__ epair, const int* __restrict__ off,
    const float* __restrict__ w1, const float* __restrict__ b1,
    const float* __restrict__ w2, const float* __restrict__ b2,
    const float* __restrict__ g, const float* __restrict__ bln,
    float* __restrict__ xo) {
  __shared__ float sIN[D * STR];
  __shared__ float sH[D * STR];
  __shared__ float sPS[512], sPQ[512], sMu[64], sRs[64];
  const int tid = threadIdx.x;
  const int n0 = blockIdx.x * 64;
  const int wv = tid >> 6, lane = tid & 63;
  for (int q = 0; q < 8; ++q) {
    int t = wv * 8 + q;
    int node = n0 + t;
    float acc = 0.f;
    if (node < NN) {
      acc = x[(size_t)node * D + lane];  // self term
      int beg = off[node], end = off[node + 1];
      int i = beg;
      for (; i + 1 < end; i += 2) {
        int2 ea = epair[i];
        int2 eb = epair[i + 1];
        float xa = x[(size_t)ea.y * D + lane];
        float va = e[(size_t)ea.x * D + lane];
        float xb = x[(size_t)eb.y * D + lane];
        float vb = e[(size_t)eb.x * D + lane];
        acc += fmaxf(xa + va, 0.f) + fmaxf(xb + vb, 0.f);
      }
      if (i < end) {
        int2 ea = epair[i];
        acc += fmaxf(x[(size_t)ea.y * D + lane] + e[(size_t)ea.x * D + lane], 0.f);
      }
    }
    sIN[lane * STR + t] = acc;
  }
  mlp_tail512(sIN, sH, sPS, sPQ, sMu, sRs, w1, b1, w2, b2, g, bln, xo, n0, tid);
}

// ---------------- layer-1: fused streaming gather (bf16 msg) + node MLP ----------------
__global__ __launch_bounds__(512) void node_mlp_g1_kernel(
    const float* __restrict__ x, const unsigned short* __restrict__ msg,
    const int* __restrict__ off,
    const float* __restrict__ w1, const float* __restrict__ b1,
    const float* __restrict__ w2, const float* __restrict__ b2,
    const float* __restrict__ g, const float* __restrict__ bln,
    float* __restrict__ xo) {
  __shared__ float sIN[D * STR];
  __shared__ float sH[D * STR];
  __shared__ float sPS[512], sPQ[512], sMu[64], sRs[64];
  const int tid = threadIdx.x;
  const int n0 = blockIdx.x * 64;
  const int wv = tid >> 6, lane = tid & 63;
  for (int q = 0; q < 8; ++q) {
    int t = wv * 8 + q;
    int node = n0 + t;
    float acc = 0.f;
    if (node < NN) {
      acc = x[(size_t)node * D + lane];
      int beg = off[node], end = off[node + 1];
      const unsigned short* mr = msg + (size_t)beg * D + lane;
      int cnt = end - beg, i = 0;
      for (; i + 3 < cnt; i += 4) {
        float m0 = bf2f(mr[(size_t)(i + 0) * D]);
        float m1 = bf2f(mr[(size_t)(i + 1) * D]);
        float m2 = bf2f(mr[(size_t)(i + 2) * D]);
        float m3 = bf2f(mr[(size_t)(i + 3) * D]);
        acc += (m0 + m1) + (m2 + m3);
      }
      for (; i < cnt; ++i) acc += bf2f(mr[(size_t)i * D]);
    }
    sIN[lane * STR + t] = acc;
  }
  mlp_tail512(sIN, sH, sPS, sPQ, sMu, sRs, w1, b1, w2, b2, g, bln, xo, n0, tid);
}

// ---------------- MFMA edge MLP over CSR slots; bf16 msg[slot] ----------------
__global__ __launch_bounds__(256) void edge_mfma_csr_kernel(
    const float* __restrict__ x, const float* __restrict__ e,
    const int2* __restrict__ epair, const int* __restrict__ dst,
    const unsigned short* __restrict__ wB1, const float* __restrict__ b1,
    const unsigned short* __restrict__ wB2, const float* __restrict__ b2,
    unsigned short* __restrict__ msg) {
  __shared__ unsigned short sIN[64 * SINB];  // 25600 B: bf16 cat inputs [t][k]
  __shared__ unsigned short sH[64 * SHB];    //  9216 B: bf16 relu(h) [t][k2]
  __shared__ int sSrc[64];                   //   256 B

  const int tid = threadIdx.x;
  const int e0 = blockIdx.x * 64;  // CSR slot base
  const int lane = tid & 63;
  const int mt = tid >> 6;
  const int hl = lane >> 4;
  const int ll = lane & 15;

  {
    const int t = tid & 63, p = tid >> 6;
    int slot = e0 + t;
    int2 ep = epair[slot];
    int eid = ep.x, sN = ep.y;
    int dN = dst[eid];
    if (p == 0) sSrc[t] = sN;
    const float* g0 = x + (size_t)sN * D + p * 16;
    const float* g1 = x + (size_t)dN * D + p * 16;
    const float* g2 = e + (size_t)eid * D + p * 16;
    unsigned short* row = sIN + t * SINB + p * 16;
#pragma unroll
    for (int i = 0; i < 4; ++i) {
      float4 v0 = ((const float4*)g0)[i];
      float4 v1 = ((const float4*)g1)[i];
      float4 v2 = ((const float4*)g2)[i];
      uint2 u;
      u.x = (unsigned)f2bf(v0.x) | ((unsigned)f2bf(v0.y) << 16);
      u.y = (unsigned)f2bf(v0.z) | ((unsigned)f2bf(v0.w) << 16);
      *(uint2*)(row + i * 4) = u;
      u.x = (unsigned)f2bf(v1.x) | ((unsigned)f2bf(v1.y) << 16);
      u.y = (unsigned)f2bf(v1.z) | ((unsigned)f2bf(v1.w) << 16);
      *(uint2*)(row + 64 + i * 4) = u;
      u.x = (unsigned)f2bf(v2.x) | ((unsigned)f2bf(v2.y) << 16);
      u.y = (unsigned)f2bf(v2.z) | ((unsigned)f2bf(v2.w) << 16);
      *(uint2*)(row + 128 + i * 4) = u;
    }
  }
  __syncthreads();

  f32x4 acc[4];
#pragma unroll
  for (int nt = 0; nt < 4; ++nt) {
    float b = b1[nt * 16 + ll];
    acc[nt].x = b; acc[nt].y = b; acc[nt].z = b; acc[nt].w = b;
  }
  {
    const unsigned short* aBase = sIN + (mt * 16 + ll) * SINB + hl * 8;
#pragma unroll
    for (int kk = 0; kk < 6; ++kk) {
      bf16x8 af = *(const bf16x8*)(aBase + kk * 32);
#pragma unroll
      for (int nt = 0; nt < 4; ++nt) {
        bf16x8 bf = *(const bf16x8*)(wB1 + ((size_t)(nt * 6 + kk) * 64 + lane) * 8);
        acc[nt] = __builtin_amdgcn_mfma_f32_16x16x32_bf16(af, bf, acc[nt], 0, 0, 0);
      }
    }
  }
#pragma unroll
  for (int nt = 0; nt < 4; ++nt)
#pragma unroll
    for (int r = 0; r < 4; ++r)
      sH[(mt * 16 + hl * 4 + r) * SHB + nt * 16 + ll] = f2bf(fmaxf(acc[nt][r], 0.f));
  __syncthreads();

  f32x4 acc2[4];
#pragma unroll
  for (int nt = 0; nt < 4; ++nt) {
    float b = b2[nt * 16 + ll];
    acc2[nt].x = b; acc2[nt].y = b; acc2[nt].z = b; acc2[nt].w = b;
  }
  {
    const unsigned short* hBase = sH + (mt * 16 + ll) * SHB + hl * 8;
#pragma unroll
    for (int kk = 0; kk < 2; ++kk) {
      bf16x8 af = *(const bf16x8*)(hBase + kk * 32);
#pragma unroll
      for (int nt = 0; nt < 4; ++nt) {
        bf16x8 bf = *(const bf16x8*)(wB2 + ((size_t)(nt * 2 + kk) * 64 + lane) * 8);
        acc2[nt] = __builtin_amdgcn_mfma_f32_16x16x32_bf16(af, bf, acc2[nt], 0, 0, 0);
      }
    }
  }

  // epilogue: msg = relu(x[src] + e + 0.5*o); e read back as bf16 from sIN
#pragma unroll
  for (int r = 0; r < 4; ++r) {
    int t = mt * 16 + hl * 4 + r;
    int slot = e0 + t;
    int sN = sSrc[t];
    const float* xr = x + (size_t)sN * D;
    const unsigned short* er = sIN + t * SINB + 128;
    unsigned short* mr = msg + (size_t)slot * D;
#pragma unroll
    for (int nt = 0; nt < 4; ++nt) {
      int j = nt * 16 + ll;
      float ef = bf2f(er[j]);
      mr[j] = f2bf(fmaxf(xr[j] + fmaf(0.5f, acc2[nt][r], ef), 0.f));
    }
  }
}

// ---------------- legacy kernels (fallback tier) ----------------
__global__ __launch_bounds__(256) void scatter_kernel(
    const float* __restrict__ x, const float* __restrict__ e,
    const int* __restrict__ src, const int* __restrict__ dst,
    float* __restrict__ agg) {
  int tid = blockIdx.x * blockDim.x + threadIdx.x;
  if (tid >= NE * 16) return;
  int eid = tid >> 4, q = tid & 15;
  int s = src[eid], d = dst[eid];
  float4 xv = ((const float4*)(x + (size_t)s * D))[q];
  float4 ev = ((const float4*)(e + (size_t)eid * D))[q];
  float* a = agg + (size_t)d * D + q * 4;
  atomicAdd(a + 0, fmaxf(xv.x + ev.x, 0.f));
  atomicAdd(a + 1, fmaxf(xv.y + ev.y, 0.f));
  atomicAdd(a + 2, fmaxf(xv.z + ev.z, 0.f));
  atomicAdd(a + 3, fmaxf(xv.w + ev.w, 0.f));
}

__device__ __forceinline__ void mlp_tail256(
    float* sIN, float* sH, float* sPS, float* sPQ, float* sMu, float* sRs,
    const float* __restrict__ w1, const float* __restrict__ b1,
    const float* __restrict__ w2, const float* __restrict__ b2,
    const float* __restrict__ g, const float* __restrict__ bln,
    float* __restrict__ xo, int n0, int tid) {
  __syncthreads();
  const int tj = tid & 15, tt = tid >> 4;
  const int j0 = tj * 4, t0 = tt * 4;
  float4 a0, a1, a2, a3;
  {
    float4 bv = *(const float4*)(b1 + j0);
    a0 = a1 = a2 = a3 = bv;
    for (int k = 0; k < D; ++k) {
      float4 w = *(const float4*)(w1 + k * D + j0);
      float4 v = *(const float4*)&sIN[k * STR + t0];
      FMA4x4(v, w)
    }
  }
  HSTORE_RELU(sH)
  __syncthreads();
  {
    float4 bv = *(const float4*)(b2 + j0);
    a0 = a1 = a2 = a3 = bv;
    for (int k = 0; k < D; ++k) {
      float4 w = *(const float4*)(w2 + k * D + j0);
      float4 v = *(const float4*)&sH[k * STR + t0];
      FMA4x4(v, w)
    }
  }
  __syncthreads();
  *(float4*)&sH[(t0 + 0) * STR + j0] = a0;
  *(float4*)&sH[(t0 + 1) * STR + j0] = a1;
  *(float4*)&sH[(t0 + 2) * STR + j0] = a2;
  *(float4*)&sH[(t0 + 3) * STR + j0] = a3;
  __syncthreads();
  {
    const int t = tid & 63, p = tid >> 6;
    const float* r = &sH[t * STR + p * 16];
    float s = 0.f, q = 0.f;
#pragma unroll
    for (int i = 0; i < 16; ++i) { float v = r[i]; s += v; q = fmaf(v, v, q); }
    sPS[p * 64 + t] = s;
    sPQ[p * 64 + t] = q;
  }
  __syncthreads();
  if (tid < 64) {
    float s = sPS[tid] + sPS[64 + tid] + sPS[128 + tid] + sPS[192 + tid];
    float q = sPQ[tid] + sPQ[64 + tid] + sPQ[128 + tid] + sPQ[192 + tid];
    float mu = s * (1.f / 64.f);
    float var = q * (1.f / 64.f) - mu * mu;
    sMu[tid] = mu;
    sRs[tid] = rsqrtf(var + LNEPS);
  }
  __syncthreads();
  {
    const int t = tid >> 2, c = (tid & 3) * 16;
    int node = n0 + t;
    if (node < NN) {
      float mu = sMu[t], rs = sRs[t];
      float* o = xo + (size_t)node * D + c;
#pragma unroll
      for (int i = 0; i < 4; ++i) {
        float4 v = *(const float4*)&sH[t * STR + c + i * 4];
        float4 gv = *(const float4*)(g + c + i * 4);
        float4 bv = *(const float4*)(bln + c + i * 4);
        float4 r;
        r.x = fmaxf(fmaf((v.x - mu) * rs, gv.x, bv.x), 0.f);
        r.y = fmaxf(fmaf((v.y - mu) * rs, gv.y, bv.y), 0.f);
        r.z = fmaxf(fmaf((v.z - mu) * rs, gv.z, bv.z), 0.f);
        r.w = fmaxf(fmaf((v.w - mu) * rs, gv.w, bv.w), 0.f);
        ((float4*)o)[i] = r;
      }
    }
  }
}

__global__ __launch_bounds__(256) void node_mlp_kernel(
    const float* __restrict__ x, const float* __restrict__ agg,
    const float* __restrict__ w1, const float* __restrict__ b1,
    const float* __restrict__ w2, const float* __restrict__ b2,
    const float* __restrict__ g, const float* __restrict__ bln,
    float* __restrict__ xo) {
  __shared__ float sIN[D * STR];
  __shared__ float sH[D * STR];
  __shared__ float sPS[256], sPQ[256], sMu[64], sRs[64];
  const int tid = threadIdx.x;
  const int n0 = blockIdx.x * 64;
  {
    const int t = tid & 63, p = tid >> 6;
    int node = n0 + t;
    int cn = node < NN ? node : 0;
    const float* xr = x + (size_t)cn * D + p * 16;
    const float* ar = agg + (size_t)cn * D + p * 16;
#pragma unroll
    for (int i = 0; i < 4; ++i) {
      float4 xv = ((const float4*)xr)[i];
      float4 av = ((const float4*)ar)[i];
      int k = p * 16 + i * 4;
      sIN[(k + 0) * STR + t] = xv.x + av.x;
      sIN[(k + 1) * STR + t] = xv.y + av.y;
      sIN[(k + 2) * STR + t] = xv.z + av.z;
      sIN[(k + 3) * STR + t] = xv.w + av.w;
    }
  }
  mlp_tail256(sIN, sH, sPS, sPQ, sMu, sRs, w1, b1, w2, b2, g, bln, xo, n0, tid);
}

__global__ __launch_bounds__(256) void edge_mfma_atomic_kernel(
    const float* __restrict__ x, const float* __restrict__ e,
    const int* __restrict__ src, const int* __restrict__ dst,
    const unsigned short* __restrict__ wB1, const float* __restrict__ b1,
    const unsigned short* __restrict__ wB2, const float* __restrict__ b2,
    float* __restrict__ agg) {
  __shared__ unsigned short sIN[64 * SINB];
  __shared__ unsigned short sH[64 * SHB];
  __shared__ float sE[64 * SEB];
  const int tid = threadIdx.x;
  const int e0 = blockIdx.x * 64;
  const int lane = tid & 63;
  const int mt = tid >> 6;
  const int hl = lane >> 4;
  const int ll = lane & 15;
  {
    const int t = tid & 63, p = tid >> 6;
    int eid = e0 + t;
    int sN = src[eid], dN = dst[eid];
    const float* g0 = x + (size_t)sN * D + p * 16;
    const float* g1 = x + (size_t)dN * D + p * 16;
    const float* g2 = e + (size_t)eid * D + p * 16;
    unsigned short* row = sIN + t * SINB + p * 16;
#pragma unroll
    for (int i = 0; i < 4; ++i) {
      float4 v0 = ((const float4*)g0)[i];
      float4 v1 = ((const float4*)g1)[i];
      float4 v2 = ((const float4*)g2)[i];
      uint2 u;
      u.x = (unsigned)f2bf(v0.x) | ((unsigned)f2bf(v0.y) << 16);
      u.y = (unsigned)f2bf(v0.z) | ((unsigned)f2bf(v0.w) << 16);
      *(uint2*)(row + i * 4) = u;
      u.x = (unsigned)f2bf(v1.x) | ((unsigned)f2bf(v1.y) << 16);
      u.y = (unsigned)f2bf(v1.z) | ((unsigned)f2bf(v1.w) << 16);
      *(uint2*)(row + 64 + i * 4) = u;
      u.x = (unsigned)f2bf(v2.x) | ((unsigned)f2bf(v2.y) << 16);
      u.y = (unsigned)f2bf(v2.z) | ((unsigned)f2bf(v2.w) << 16);
      *(uint2*)(row + 128 + i * 4) = u;
      *(float4*)&sE[t * SEB + p * 16 + i * 4] = v2;
    }
  }
  __syncthreads();
  f32x4 acc[4];
#pragma unroll
  for (int nt = 0; nt < 4; ++nt) {
    float b = b1[nt * 16 + ll];
    acc[nt].x = b; acc[nt].y = b; acc[nt].z = b; acc[nt].w = b;
  }
  {
    const unsigned short* aBase = sIN + (mt * 16 + ll) * SINB + hl * 8;
#pragma unroll
    for (int kk = 0; kk < 6; ++kk) {
      bf16x8 af = *(const bf16x8*)(aBase + kk * 32);
#pragma unroll
      for (int nt = 0; nt < 4; ++nt) {
        bf16x8 bf = *(const bf16x8*)(wB1 + ((size_t)(nt * 6 + kk) * 64 + lane) * 8);
        acc[nt] = __builtin_amdgcn_mfma_f32_16x16x32_bf16(af, bf, acc[nt], 0, 0, 0);
      }
    }
  }
#pragma unroll
  for (int nt = 0; nt < 4; ++nt)
#pragma unroll
    for (int r = 0; r < 4; ++r)
      sH[(mt * 16 + hl * 4 + r) * SHB + nt * 16 + ll] = f2bf(fmaxf(acc[nt][r], 0.f));
  __syncthreads();
  f32x4 acc2[4];
#pragma unroll
  for (int nt = 0; nt < 4; ++nt) {
    float b = b2[nt * 16 + ll];
    acc2[nt].x = b; acc2[nt].y = b; acc2[nt].z = b; acc2[nt].w = b;
  }
  {
    const unsigned short* hBase = sH + (mt * 16 + ll) * SHB + hl * 8;
#pragma unroll
    for (int kk = 0; kk < 2; ++kk) {
      bf16x8 af = *(const bf16x8*)(hBase + kk * 32);
#pragma unroll
      for (int nt = 0; nt < 4; ++nt) {
        bf16x8 bf = *(const bf16x8*)(wB2 + ((size_t)(nt * 2 + kk) * 64 + lane) * 8);
        acc2[nt] = __builtin_amdgcn_mfma_f32_16x16x32_bf16(af, bf, acc2[nt], 0, 0, 0);
      }
    }
  }
#pragma unroll
  for (int r = 0; r < 4; ++r) {
    int t = mt * 16 + hl * 4 + r;
    int eid = e0 + t;
    int sN = src[eid], dN = dst[eid];
    const float* xr = x + (size_t)sN * D;
    const float* er = &sE[t * SEB];
    float* ar = agg + (size_t)dN * D;
#pragma unroll
    for (int nt = 0; nt < 4; ++nt) {
      int j = nt * 16 + ll;
      atomicAdd(ar + j, fmaxf(xr[j] + fmaf(0.5f, acc2[nt][r], er[j]), 0.f));
    }
  }
}

// ---------------- head ----------------
__global__ __launch_bounds__(256) void head_kernel(
    const float* __restrict__ x, const float* __restrict__ w,
    const float* __restrict__ b, float* __restrict__ out) {
  int nid = blockIdx.x * blockDim.x + threadIdx.x;
  if (nid >= NN) return;
  const float* xr = x + (size_t)nid * D;
  float a0 = b[0], a1 = b[1];
  for (int k = 0; k < D; ++k) {
    float v = xr[k];
    a0 = fmaf(v, w[k * 2 + 0], a0);
    a1 = fmaf(v, w[k * 2 + 1], a1);
  }
  out[nid * 2 + 0] = a0;
  out[nid * 2 + 1] = a1;
}

extern "C" void kernel_launch(void* const* d_in, const int* in_sizes, int n_in,
                              void* d_out, int out_size, void* d_ws, size_t ws_size,
                              hipStream_t stream) {
  const float* x0  = (const float*)d_in[0];
  const float* e0  = (const float*)d_in[1];
  const int*   ei  = (const int*)d_in[2];
  const float* gw1 = (const float*)d_in[3];
  const float* gb1 = (const float*)d_in[4];
  const float* gw2 = (const float*)d_in[5];
  const float* gb2 = (const float*)d_in[6];
  const float* ew1 = (const float*)d_in[7];
  const float* eb1 = (const float*)d_in[8];
  const float* ew2 = (const float*)d_in[9];
  const float* eb2 = (const float*)d_in[10];
  const float* lng = (const float*)d_in[11];
  const float* lnb = (const float*)d_in[12];
  const float* hw  = (const float*)d_in[13];
  const float* hb  = (const float*)d_in[14];
  float* out = (float*)d_out;

  char* ws = (char*)d_ws;
  const size_t SZ_X     = (size_t)NN * D * 4;          // 12.8 MB
  const size_t OFF_X1   = 0;
  const size_t OFF_X2   = OFF_X1 + SZ_X;
  const size_t OFF_WB1  = OFF_X2 + SZ_X;
  const size_t OFF_WB2  = OFF_WB1 + 24576;
  const size_t OFF_DEG  = OFF_WB2 + 8192;
  const size_t OFF_OFFS = OFF_DEG + 200704;
  const size_t OFF_CUR  = OFF_OFFS + 200704;
  const size_t OFF_BSUM = OFF_CUR + 200704;
  const size_t OFF_EPAIR= OFF_BSUM + 512;
  const size_t OFF_MSG  = OFF_EPAIR + (size_t)NE * 8;
  const size_t NEED_A   = OFF_MSG + (size_t)NE * D * 2;  // ~134 MB

  float* x1   = (float*)(ws + OFF_X1);
  float* x2   = (float*)(ws + OFF_X2);
  unsigned short* wB1 = (unsigned short*)(ws + OFF_WB1);
  unsigned short* wB2 = (unsigned short*)(ws + OFF_WB2);
  int* deg  = (int*)(ws + OFF_DEG);
  int* offs = (int*)(ws + OFF_OFFS);
  int* cur  = (int*)(ws + OFF_CUR);
  int* bsum = (int*)(ws + OFF_BSUM);
  int2* epair = (int2*)(ws + OFF_EPAIR);
  unsigned short* msg = (unsigned short*)(ws + OFF_MSG);

  const int* src = ei;
  const int* dst = ei + NE;

  const int nodeBlocks = (NN + 63) / 64;     // 782
  const int edgeBlocks = NE / 64;            // 12500
  const int scanBlocks = (NN + 1023) / 1024; // 49

  pack_weights_kernel<<<8, 256, 0, stream>>>(ew1, ew2, wB1, wB2);

  if (ws_size >= NEED_A) {
    // ---- CSR build (by dst) ----
    hipMemsetAsync(deg, 0, (size_t)NN * 4, stream);
    count_kernel<<<(NE + 255) / 256, 256, 0, stream>>>(dst, deg);
    scan_reduce_kernel<<<scanBlocks, 1024, 0, stream>>>(deg, bsum);
    scan_final_kernel<<<scanBlocks, 1024, 0, stream>>>(deg, bsum, offs, cur);
    fill_kernel<<<(NE + 255) / 256, 256, 0, stream>>>(src, dst, cur, epair);

    // ---- layer 0: fused gather + node MLP ----
    node_mlp_g0_kernel<<<nodeBlocks, 512, 0, stream>>>(
        x0, e0, epair, offs, gw1, gb1, gw2, gb2, lng, lnb, x1);

    // ---- layer-0 edge update (MFMA) over CSR slots, bf16 msg ----
    edge_mfma_csr_kernel<<<edgeBlocks, 256, 0, stream>>>(
        x1, e0, epair, dst, wB1, eb1, wB2, eb2, msg);

    // ---- layer 1: fused streaming gather + node MLP ----
    node_mlp_g1_kernel<<<nodeBlocks, 512, 0, stream>>>(
        x1, msg, offs, gw1 + D * D, gb1 + D, gw2 + D * D, gb2 + D,
        lng + D, lnb + D, x2);
  } else {
    // ---- fallback: atomic path (no CSR) ----
    float* agg = (float*)(ws + OFF_EPAIR);
    hipMemsetAsync(agg, 0, SZ_X, stream);
    scatter_kernel<<<(NE * 16 + 255) / 256, 256, 0, stream>>>(x0, e0, src, dst, agg);
    node_mlp_kernel<<<nodeBlocks, 256, 0, stream>>>(
        x0, agg, gw1, gb1, gw2, gb2, lng, lnb, x1);
    hipMemsetAsync(agg, 0, SZ_X, stream);
    edge_mfma_atomic_kernel<<<edgeBlocks, 256, 0, stream>>>(
        x1, e0, src, dst, wB1, eb1, wB2, eb2, agg);
    node_mlp_kernel<<<nodeBlocks, 256, 0, stream>>>(
        x1, agg, gw1 + D * D, gb1 + D, gw2 + D * D, gb2 + D, lng + D, lnb + D, x2);
  }

  // ---- head ----
  head_kernel<<<(NN + 255) / 256, 256, 0, stream>>>(x2, hw, hb, out);
}

// Round 8
// 438.848 us; speedup vs baseline: 9.1098x; 1.0693x over previous
//
#include <hip/hip_runtime.h>
#include <hip/hip_bf16.h>

#define NN 50000
#define NE 800000
#define D 64
#define K3 (3 * D)
#define LNEPS 1e-5f
#define STR 68    // f32 LDS row stride (node kernels)
#define SINB 200  // bf16 LDS row stride, edge input tile
#define SHB 72    // bf16 LDS row stride, edge hidden tile
#define SEB 68    // f32 LDS row stride (fallback edge kernel)

typedef __attribute__((ext_vector_type(8))) short bf16x8;
typedef __attribute__((ext_vector_type(4))) float f32x4;

// hardware bf16 conversions (RNE) -- let the compiler emit v_cvt_pk_bf16_f32
__device__ __forceinline__ unsigned cvt2(float lo, float hi) {
  __hip_bfloat162 h = __float22bfloat162_rn(make_float2(lo, hi));
  return *(unsigned*)&h;
}
__device__ __forceinline__ unsigned short f2bf(float f) {
  __hip_bfloat16 h = __float2bfloat16(f);
  return *(unsigned short*)&h;
}
__device__ __forceinline__ float bf2f(unsigned short s) {
  return __uint_as_float((unsigned)s << 16);
}

#define FMA4x4(v, w)                                                  \
  a0.x = fmaf(v.x, w.x, a0.x); a0.y = fmaf(v.x, w.y, a0.y);           \
  a0.z = fmaf(v.x, w.z, a0.z); a0.w = fmaf(v.x, w.w, a0.w);           \
  a1.x = fmaf(v.y, w.x, a1.x); a1.y = fmaf(v.y, w.y, a1.y);           \
  a1.z = fmaf(v.y, w.z, a1.z); a1.w = fmaf(v.y, w.w, a1.w);           \
  a2.x = fmaf(v.z, w.x, a2.x); a2.y = fmaf(v.z, w.y, a2.y);           \
  a2.z = fmaf(v.z, w.z, a2.z); a2.w = fmaf(v.z, w.w, a2.w);           \
  a3.x = fmaf(v.w, w.x, a3.x); a3.y = fmaf(v.w, w.y, a3.y);           \
  a3.z = fmaf(v.w, w.z, a3.z); a3.w = fmaf(v.w, w.w, a3.w);

#define FMA2x4(v, w)                                                  \
  a0.x = fmaf(v.x, w.x, a0.x); a0.y = fmaf(v.x, w.y, a0.y);           \
  a0.z = fmaf(v.x, w.z, a0.z); a0.w = fmaf(v.x, w.w, a0.w);           \
  a1.x = fmaf(v.y, w.x, a1.x); a1.y = fmaf(v.y, w.y, a1.y);           \
  a1.z = fmaf(v.y, w.z, a1.z); a1.w = fmaf(v.y, w.w, a1.w);

#define HSTORE_RELU(buf)                                              \
  buf[(j0+0)*STR + t0+0] = fmaxf(a0.x, 0.f);                          \
  buf[(j0+1)*STR + t0+0] = fmaxf(a0.y, 0.f);                          \
  buf[(j0+2)*STR + t0+0] = fmaxf(a0.z, 0.f);                          \
  buf[(j0+3)*STR + t0+0] = fmaxf(a0.w, 0.f);                          \
  buf[(j0+0)*STR + t0+1] = fmaxf(a1.x, 0.f);                          \
  buf[(j0+1)*STR + t0+1] = fmaxf(a1.y, 0.f);                          \
  buf[(j0+2)*STR + t0+1] = fmaxf(a1.z, 0.f);                          \
  buf[(j0+3)*STR + t0+1] = fmaxf(a1.w, 0.f);                          \
  buf[(j0+0)*STR + t0+2] = fmaxf(a2.x, 0.f);                          \
  buf[(j0+1)*STR + t0+2] = fmaxf(a2.y, 0.f);                          \
  buf[(j0+2)*STR + t0+2] = fmaxf(a2.z, 0.f);                          \
  buf[(j0+3)*STR + t0+2] = fmaxf(a2.w, 0.f);                          \
  buf[(j0+0)*STR + t0+3] = fmaxf(a3.x, 0.f);                          \
  buf[(j0+1)*STR + t0+3] = fmaxf(a3.y, 0.f);                          \
  buf[(j0+2)*STR + t0+3] = fmaxf(a3.z, 0.f);                          \
  buf[(j0+3)*STR + t0+3] = fmaxf(a3.w, 0.f);

// ---------------- CSR build ----------------
__global__ __launch_bounds__(256) void count_kernel(
    const int* __restrict__ dst, int* __restrict__ deg) {
  int e = blockIdx.x * 256 + threadIdx.x;
  if (e < NE) atomicAdd(&deg[dst[e]], 1);
}

__global__ __launch_bounds__(1024) void scan_reduce_kernel(
    const int* __restrict__ deg, int* __restrict__ bsum) {
  __shared__ int sS[16];
  int i = blockIdx.x * 1024 + threadIdx.x;
  int v = (i < NN) ? deg[i] : 0;
#pragma unroll
  for (int o = 32; o > 0; o >>= 1) v += __shfl_down(v, o, 64);
  if ((threadIdx.x & 63) == 0) sS[threadIdx.x >> 6] = v;
  __syncthreads();
  if (threadIdx.x == 0) {
    int s = 0;
#pragma unroll
    for (int k = 0; k < 16; ++k) s += sS[k];
    bsum[blockIdx.x] = s;
  }
}

__global__ __launch_bounds__(1024) void scan_final_kernel(
    const int* __restrict__ deg, const int* __restrict__ bsum,
    int* __restrict__ off, int* __restrict__ cur) {
  __shared__ int sD[1024];
  __shared__ int sOfs;
  const int t = threadIdx.x;
  const int b = blockIdx.x;
  int i = b * 1024 + t;
  int v = (i < NN) ? deg[i] : 0;
  sD[t] = v;
  if (t == 0) {
    int o = 0;
    for (int k = 0; k < b; ++k) o += bsum[k];
    sOfs = o;
  }
  __syncthreads();
  for (int st = 1; st < 1024; st <<= 1) {
    int add = (t >= st) ? sD[t - st] : 0;
    __syncthreads();
    sD[t] += add;
    __syncthreads();
  }
  if (i < NN) {
    int excl = sOfs + sD[t] - v;
    off[i] = excl;
    cur[i] = excl;
    if (i == NN - 1) off[NN] = NE;
  }
}

// epair[p] = {eid, src[eid]} in CSR slot order
__global__ __launch_bounds__(256) void fill_kernel(
    const int* __restrict__ src, const int* __restrict__ dst,
    int* __restrict__ cur, int2* __restrict__ epair) {
  int e = blockIdx.x * 256 + threadIdx.x;
  if (e < NE) {
    int p = atomicAdd(&cur[dst[e]], 1);
    epair[p] = make_int2(e, src[e]);
  }
}

// ---------------- pack edge-MLP weights into bf16 MFMA B-fragment order ----------------
__global__ __launch_bounds__(256) void pack_weights_kernel(
    const float* __restrict__ w1, const float* __restrict__ w2,
    unsigned short* __restrict__ wB1, unsigned short* __restrict__ wB2) {
  int tid = blockIdx.x * 256 + threadIdx.x;
  const float* wsrc;
  unsigned short* wdst;
  int kb, j, slot;
  if (tid < 1536) {
    int nt = tid / 384, kk = (tid / 64) % 6, l = tid & 63;
    kb = kk * 32 + (l >> 4) * 8;
    j = nt * 16 + (l & 15);
    wsrc = w1; wdst = wB1; slot = tid;
  } else {
    int t = tid - 1536;
    int nt = t / 128, kk = (t / 64) & 1, l = t & 63;
    kb = kk * 32 + (l >> 4) * 8;
    j = nt * 16 + (l & 15);
    wsrc = w2; wdst = wB2; slot = t;
  }
  unsigned short b[8];
#pragma unroll
  for (int i = 0; i < 8; ++i) b[i] = f2bf(wsrc[(kb + i) * D + j]);
  uint4 v;
  v.x = (unsigned)b[0] | ((unsigned)b[1] << 16);
  v.y = (unsigned)b[2] | ((unsigned)b[3] << 16);
  v.z = (unsigned)b[4] | ((unsigned)b[5] << 16);
  v.w = (unsigned)b[6] | ((unsigned)b[7] << 16);
  *(uint4*)(wdst + (size_t)slot * 8) = v;
}

// ---------------- 512-thread MLP tail ----------------
__device__ __forceinline__ void mlp_tail512(
    float* sIN, float* sH, float* sPS, float* sPQ, float* sMu, float* sRs,
    const float* __restrict__ w1, const float* __restrict__ b1,
    const float* __restrict__ w2, const float* __restrict__ b2,
    const float* __restrict__ g, const float* __restrict__ bln,
    float* __restrict__ xo, int n0, int tid) {
  __syncthreads();
  const int tj = tid & 15, tt = tid >> 4;   // 16 x 32
  const int j0 = tj * 4, t0 = tt * 2;
  float4 a0, a1;

  {
    float4 bv = *(const float4*)(b1 + j0);
    a0 = a1 = bv;
    for (int k = 0; k < D; ++k) {
      float4 w = *(const float4*)(w1 + k * D + j0);
      float2 v = *(const float2*)&sIN[k * STR + t0];
      FMA2x4(v, w)
    }
  }
  sH[(j0 + 0) * STR + t0 + 0] = fmaxf(a0.x, 0.f);
  sH[(j0 + 1) * STR + t0 + 0] = fmaxf(a0.y, 0.f);
  sH[(j0 + 2) * STR + t0 + 0] = fmaxf(a0.z, 0.f);
  sH[(j0 + 3) * STR + t0 + 0] = fmaxf(a0.w, 0.f);
  sH[(j0 + 0) * STR + t0 + 1] = fmaxf(a1.x, 0.f);
  sH[(j0 + 1) * STR + t0 + 1] = fmaxf(a1.y, 0.f);
  sH[(j0 + 2) * STR + t0 + 1] = fmaxf(a1.z, 0.f);
  sH[(j0 + 3) * STR + t0 + 1] = fmaxf(a1.w, 0.f);
  __syncthreads();

  {
    float4 bv = *(const float4*)(b2 + j0);
    a0 = a1 = bv;
    for (int k = 0; k < D; ++k) {
      float4 w = *(const float4*)(w2 + k * D + j0);
      float2 v = *(const float2*)&sH[k * STR + t0];
      FMA2x4(v, w)
    }
  }
  __syncthreads();
  *(float4*)&sH[(t0 + 0) * STR + j0] = a0;
  *(float4*)&sH[(t0 + 1) * STR + j0] = a1;
  __syncthreads();

  {
    const int t = tid & 63, p = tid >> 6;
    const float* r = &sH[t * STR + p * 8];
    float s = 0.f, q = 0.f;
#pragma unroll
    for (int i = 0; i < 8; ++i) { float v = r[i]; s += v; q = fmaf(v, v, q); }
    sPS[p * 64 + t] = s;
    sPQ[p * 64 + t] = q;
  }
  __syncthreads();
  if (tid < 64) {
    float s = 0.f, q = 0.f;
#pragma unroll
    for (int p = 0; p < 8; ++p) { s += sPS[p * 64 + tid]; q += sPQ[p * 64 + tid]; }
    float mu = s * (1.f / 64.f);
    float var = q * (1.f / 64.f) - mu * mu;
    sMu[tid] = mu;
    sRs[tid] = rsqrtf(var + LNEPS);
  }
  __syncthreads();

  {
    const int t = tid >> 3, c = (tid & 7) * 8;
    int node = n0 + t;
    if (node < NN) {
      float mu = sMu[t], rs = sRs[t];
      float* o = xo + (size_t)node * D + c;
#pragma unroll
      for (int i = 0; i < 2; ++i) {
        float4 v = *(const float4*)&sH[t * STR + c + i * 4];
        float4 gv = *(const float4*)(g + c + i * 4);
        float4 bv = *(const float4*)(bln + c + i * 4);
        float4 r;
        r.x = fmaxf(fmaf((v.x - mu) * rs, gv.x, bv.x), 0.f);
        r.y = fmaxf(fmaf((v.y - mu) * rs, gv.y, bv.y), 0.f);
        r.z = fmaxf(fmaf((v.z - mu) * rs, gv.z, bv.z), 0.f);
        r.w = fmaxf(fmaf((v.w - mu) * rs, gv.w, bv.w), 0.f);
        ((float4*)o)[i] = r;
      }
    }
  }
}

// ---------------- layer-0: fused CSR gather + node MLP (512 threads) ----------------
__global__ __launch_bounds__(512) void node_mlp_g0_kernel(
    const float* __restrict__ x, const float* __restrict__ e,
    const int2* __restrict__ epair, const int* __restrict__ off,
    const float* __restrict__ w1, const float* __restrict__ b1,
    const float* __restrict__ w2, const float* __restrict__ b2,
    const float* __restrict__ g, const float* __restrict__ bln,
    float* __restrict__ xo) {
  __shared__ float sIN[D * STR];
  __shared__ float sH[D * STR];
  __shared__ float sPS[512], sPQ[512], sMu[64], sRs[64];
  const int tid = threadIdx.x;
  const int n0 = blockIdx.x * 64;
  const int wv = tid >> 6, lane = tid & 63;
  for (int q = 0; q < 8; ++q) {
    int t = wv * 8 + q;
    int node = n0 + t;
    float acc = 0.f;
    if (node < NN) {
      acc = x[(size_t)node * D + lane];  // self term
      int beg = off[node], end = off[node + 1];
      int i = beg;
      for (; i + 3 < end; i += 4) {
        int2 pa = epair[i],     pb = epair[i + 1];
        int2 pc = epair[i + 2], pd = epair[i + 3];
        float xa = x[(size_t)pa.y * D + lane];
        float va = e[(size_t)pa.x * D + lane];
        float xb = x[(size_t)pb.y * D + lane];
        float vb = e[(size_t)pb.x * D + lane];
        float xc = x[(size_t)pc.y * D + lane];
        float vc = e[(size_t)pc.x * D + lane];
        float xd = x[(size_t)pd.y * D + lane];
        float vd = e[(size_t)pd.x * D + lane];
        acc += (fmaxf(xa + va, 0.f) + fmaxf(xb + vb, 0.f)) +
               (fmaxf(xc + vc, 0.f) + fmaxf(xd + vd, 0.f));
      }
      for (; i < end; ++i) {
        int2 pa = epair[i];
        acc += fmaxf(x[(size_t)pa.y * D + lane] + e[(size_t)pa.x * D + lane], 0.f);
      }
    }
    sIN[lane * STR + t] = acc;
  }
  mlp_tail512(sIN, sH, sPS, sPQ, sMu, sRs, w1, b1, w2, b2, g, bln, xo, n0, tid);
}

// ---------------- layer-1: fused streaming gather (bf16 msg) + node MLP ----------------
__global__ __launch_bounds__(512) void node_mlp_g1_kernel(
    const float* __restrict__ x, const unsigned short* __restrict__ msg,
    const int* __restrict__ off,
    const float* __restrict__ w1, const float* __restrict__ b1,
    const float* __restrict__ w2, const float* __restrict__ b2,
    const float* __restrict__ g, const float* __restrict__ bln,
    float* __restrict__ xo) {
  __shared__ float sIN[D * STR];
  __shared__ float sH[D * STR];
  __shared__ float sPS[512], sPQ[512], sMu[64], sRs[64];
  const int tid = threadIdx.x;
  const int n0 = blockIdx.x * 64;
  const int wv = tid >> 6, lane = tid & 63;
  for (int q = 0; q < 8; ++q) {
    int t = wv * 8 + q;
    int node = n0 + t;
    float acc = 0.f;
    if (node < NN) {
      acc = x[(size_t)node * D + lane];
      int beg = off[node], end = off[node + 1];
      const unsigned short* mr = msg + (size_t)beg * D + lane;
      int cnt = end - beg, i = 0;
      for (; i + 3 < cnt; i += 4) {
        float m0 = bf2f(mr[(size_t)(i + 0) * D]);
        float m1 = bf2f(mr[(size_t)(i + 1) * D]);
        float m2 = bf2f(mr[(size_t)(i + 2) * D]);
        float m3 = bf2f(mr[(size_t)(i + 3) * D]);
        acc += (m0 + m1) + (m2 + m3);
      }
      for (; i < cnt; ++i) acc += bf2f(mr[(size_t)i * D]);
    }
    sIN[lane * STR + t] = acc;
  }
  mlp_tail512(sIN, sH, sPS, sPQ, sMu, sRs, w1, b1, w2, b2, g, bln, xo, n0, tid);
}

// ---------------- MFMA edge MLP over CSR slots; bf16 msg[slot] ----------------
__global__ __launch_bounds__(256) void edge_mfma_csr_kernel(
    const float* __restrict__ x, const float* __restrict__ e,
    const int2* __restrict__ epair, const int* __restrict__ dst,
    const unsigned short* __restrict__ wB1, const float* __restrict__ b1,
    const unsigned short* __restrict__ wB2, const float* __restrict__ b2,
    unsigned short* __restrict__ msg) {
  __shared__ unsigned short sIN[64 * SINB];  // 25600 B: bf16 cat inputs [t][k]
  __shared__ unsigned short sH[64 * SHB];    //  9216 B: bf16 relu(h) [t][k2]

  const int tid = threadIdx.x;
  const int e0 = blockIdx.x * 64;  // CSR slot base
  const int lane = tid & 63;
  const int mt = tid >> 6;
  const int hl = lane >> 4;
  const int ll = lane & 15;

  {
    const int t = tid & 63, p = tid >> 6;
    int slot = e0 + t;
    int2 ep = epair[slot];
    int eid = ep.x, sN = ep.y;
    int dN = dst[eid];
    const float* g0 = x + (size_t)sN * D + p * 16;
    const float* g1 = x + (size_t)dN * D + p * 16;
    const float* g2 = e + (size_t)eid * D + p * 16;
    unsigned short* row = sIN + t * SINB + p * 16;
#pragma unroll
    for (int i = 0; i < 4; ++i) {
      float4 v0 = ((const float4*)g0)[i];
      float4 v1 = ((const float4*)g1)[i];
      float4 v2 = ((const float4*)g2)[i];
      uint2 u;
      u.x = cvt2(v0.x, v0.y); u.y = cvt2(v0.z, v0.w);
      *(uint2*)(row + i * 4) = u;
      u.x = cvt2(v1.x, v1.y); u.y = cvt2(v1.z, v1.w);
      *(uint2*)(row + 64 + i * 4) = u;
      u.x = cvt2(v2.x, v2.y); u.y = cvt2(v2.z, v2.w);
      *(uint2*)(row + 128 + i * 4) = u;
    }
  }
  __syncthreads();

  f32x4 acc[4];
#pragma unroll
  for (int nt = 0; nt < 4; ++nt) {
    float b = b1[nt * 16 + ll];
    acc[nt].x = b; acc[nt].y = b; acc[nt].z = b; acc[nt].w = b;
  }
  {
    const unsigned short* aBase = sIN + (mt * 16 + ll) * SINB + hl * 8;
#pragma unroll
    for (int kk = 0; kk < 6; ++kk) {
      bf16x8 af = *(const bf16x8*)(aBase + kk * 32);
#pragma unroll
      for (int nt = 0; nt < 4; ++nt) {
        bf16x8 bf = *(const bf16x8*)(wB1 + ((size_t)(nt * 6 + kk) * 64 + lane) * 8);
        acc[nt] = __builtin_amdgcn_mfma_f32_16x16x32_bf16(af, bf, acc[nt], 0, 0, 0);
      }
    }
  }
#pragma unroll
  for (int nt = 0; nt < 4; ++nt)
#pragma unroll
    for (int r = 0; r < 4; ++r)
      sH[(mt * 16 + hl * 4 + r) * SHB + nt * 16 + ll] = f2bf(fmaxf(acc[nt][r], 0.f));
  __syncthreads();

  f32x4 acc2[4];
#pragma unroll
  for (int nt = 0; nt < 4; ++nt) {
    float b = b2[nt * 16 + ll];
    acc2[nt].x = b; acc2[nt].y = b; acc2[nt].z = b; acc2[nt].w = b;
  }
  {
    const unsigned short* hBase = sH + (mt * 16 + ll) * SHB + hl * 8;
#pragma unroll
    for (int kk = 0; kk < 2; ++kk) {
      bf16x8 af = *(const bf16x8*)(hBase + kk * 32);
#pragma unroll
      for (int nt = 0; nt < 4; ++nt) {
        bf16x8 bf = *(const bf16x8*)(wB2 + ((size_t)(nt * 2 + kk) * 64 + lane) * 8);
        acc2[nt] = __builtin_amdgcn_mfma_f32_16x16x32_bf16(af, bf, acc2[nt], 0, 0, 0);
      }
    }
  }

  // epilogue: msg = relu(x[src] + e + 0.5*o); x,e read back as bf16 from sIN
#pragma unroll
  for (int r = 0; r < 4; ++r) {
    int t = mt * 16 + hl * 4 + r;
    int slot = e0 + t;
    const unsigned short* xr = sIN + t * SINB;        // bf16 x[src], cols 0..63
    const unsigned short* er = sIN + t * SINB + 128;  // bf16 e, cols 128..191
    unsigned short* mr = msg + (size_t)slot * D;
#pragma unroll
    for (int nt = 0; nt < 4; ++nt) {
      int j = nt * 16 + ll;
      float xf = bf2f(xr[j]);
      float ef = bf2f(er[j]);
      mr[j] = f2bf(fmaxf(xf + fmaf(0.5f, acc2[nt][r], ef), 0.f));
    }
  }
}

// ---------------- legacy kernels (fallback tier) ----------------
__global__ __launch_bounds__(256) void scatter_kernel(
    const float* __restrict__ x, const float* __restrict__ e,
    const int* __restrict__ src, const int* __restrict__ dst,
    float* __restrict__ agg) {
  int tid = blockIdx.x * blockDim.x + threadIdx.x;
  if (tid >= NE * 16) return;
  int eid = tid >> 4, q = tid & 15;
  int s = src[eid], d = dst[eid];
  float4 xv = ((const float4*)(x + (size_t)s * D))[q];
  float4 ev = ((const float4*)(e + (size_t)eid * D))[q];
  float* a = agg + (size_t)d * D + q * 4;
  atomicAdd(a + 0, fmaxf(xv.x + ev.x, 0.f));
  atomicAdd(a + 1, fmaxf(xv.y + ev.y, 0.f));
  atomicAdd(a + 2, fmaxf(xv.z + ev.z, 0.f));
  atomicAdd(a + 3, fmaxf(xv.w + ev.w, 0.f));
}

__device__ __forceinline__ void mlp_tail256(
    float* sIN, float* sH, float* sPS, float* sPQ, float* sMu, float* sRs,
    const float* __restrict__ w1, const float* __restrict__ b1,
    const float* __restrict__ w2, const float* __restrict__ b2,
    const float* __restrict__ g, const float* __restrict__ bln,
    float* __restrict__ xo, int n0, int tid) {
  __syncthreads();
  const int tj = tid & 15, tt = tid >> 4;
  const int j0 = tj * 4, t0 = tt * 4;
  float4 a0, a1, a2, a3;
  {
    float4 bv = *(const float4*)(b1 + j0);
    a0 = a1 = a2 = a3 = bv;
    for (int k = 0; k < D; ++k) {
      float4 w = *(const float4*)(w1 + k * D + j0);
      float4 v = *(const float4*)&sIN[k * STR + t0];
      FMA4x4(v, w)
    }
  }
  HSTORE_RELU(sH)
  __syncthreads();
  {
    float4 bv = *(const float4*)(b2 + j0);
    a0 = a1 = a2 = a3 = bv;
    for (int k = 0; k < D; ++k) {
      float4 w = *(const float4*)(w2 + k * D + j0);
      float4 v = *(const float4*)&sH[k * STR + t0];
      FMA4x4(v, w)
    }
  }
  __syncthreads();
  *(float4*)&sH[(t0 + 0) * STR + j0] = a0;
  *(float4*)&sH[(t0 + 1) * STR + j0] = a1;
  *(float4*)&sH[(t0 + 2) * STR + j0] = a2;
  *(float4*)&sH[(t0 + 3) * STR + j0] = a3;
  __syncthreads();
  {
    const int t = tid & 63, p = tid >> 6;
    const float* r = &sH[t * STR + p * 16];
    float s = 0.f, q = 0.f;
#pragma unroll
    for (int i = 0; i < 16; ++i) { float v = r[i]; s += v; q = fmaf(v, v, q); }
    sPS[p * 64 + t] = s;
    sPQ[p * 64 + t] = q;
  }
  __syncthreads();
  if (tid < 64) {
    float s = sPS[tid] + sPS[64 + tid] + sPS[128 + tid] + sPS[192 + tid];
    float q = sPQ[tid] + sPQ[64 + tid] + sPQ[128 + tid] + sPQ[192 + tid];
    float mu = s * (1.f / 64.f);
    float var = q * (1.f / 64.f) - mu * mu;
    sMu[tid] = mu;
    sRs[tid] = rsqrtf(var + LNEPS);
  }
  __syncthreads();
  {
    const int t = tid >> 2, c = (tid & 3) * 16;
    int node = n0 + t;
    if (node < NN) {
      float mu = sMu[t], rs = sRs[t];
      float* o = xo + (size_t)node * D + c;
#pragma unroll
      for (int i = 0; i < 4; ++i) {
        float4 v = *(const float4*)&sH[t * STR + c + i * 4];
        float4 gv = *(const float4*)(g + c + i * 4);
        float4 bv = *(const float4*)(bln + c + i * 4);
        float4 r;
        r.x = fmaxf(fmaf((v.x - mu) * rs, gv.x, bv.x), 0.f);
        r.y = fmaxf(fmaf((v.y - mu) * rs, gv.y, bv.y), 0.f);
        r.z = fmaxf(fmaf((v.z - mu) * rs, gv.z, bv.z), 0.f);
        r.w = fmaxf(fmaf((v.w - mu) * rs, gv.w, bv.w), 0.f);
        ((float4*)o)[i] = r;
      }
    }
  }
}

__global__ __launch_bounds__(256) void node_mlp_kernel(
    const float* __restrict__ x, const float* __restrict__ agg,
    const float* __restrict__ w1, const float* __restrict__ b1,
    const float* __restrict__ w2, const float* __restrict__ b2,
    const float* __restrict__ g, const float* __restrict__ bln,
    float* __restrict__ xo) {
  __shared__ float sIN[D * STR];
  __shared__ float sH[D * STR];
  __shared__ float sPS[256], sPQ[256], sMu[64], sRs[64];
  const int tid = threadIdx.x;
  const int n0 = blockIdx.x * 64;
  {
    const int t = tid & 63, p = tid >> 6;
    int node = n0 + t;
    int cn = node < NN ? node : 0;
    const float* xr = x + (size_t)cn * D + p * 16;
    const float* ar = agg + (size_t)cn * D + p * 16;
#pragma unroll
    for (int i = 0; i < 4; ++i) {
      float4 xv = ((const float4*)xr)[i];
      float4 av = ((const float4*)ar)[i];
      int k = p * 16 + i * 4;
      sIN[(k + 0) * STR + t] = xv.x + av.x;
      sIN[(k + 1) * STR + t] = xv.y + av.y;
      sIN[(k + 2) * STR + t] = xv.z + av.z;
      sIN[(k + 3) * STR + t] = xv.w + av.w;
    }
  }
  mlp_tail256(sIN, sH, sPS, sPQ, sMu, sRs, w1, b1, w2, b2, g, bln, xo, n0, tid);
}

__global__ __launch_bounds__(256) void edge_mfma_atomic_kernel(
    const float* __restrict__ x, const float* __restrict__ e,
    const int* __restrict__ src, const int* __restrict__ dst,
    const unsigned short* __restrict__ wB1, const float* __restrict__ b1,
    const unsigned short* __restrict__ wB2, const float* __restrict__ b2,
    float* __restrict__ agg) {
  __shared__ unsigned short sIN[64 * SINB];
  __shared__ unsigned short sH[64 * SHB];
  __shared__ float sE[64 * SEB];
  const int tid = threadIdx.x;
  const int e0 = blockIdx.x * 64;
  const int lane = tid & 63;
  const int mt = tid >> 6;
  const int hl = lane >> 4;
  const int ll = lane & 15;
  {
    const int t = tid & 63, p = tid >> 6;
    int eid = e0 + t;
    int sN = src[eid], dN = dst[eid];
    const float* g0 = x + (size_t)sN * D + p * 16;
    const float* g1 = x + (size_t)dN * D + p * 16;
    const float* g2 = e + (size_t)eid * D + p * 16;
    unsigned short* row = sIN + t * SINB + p * 16;
#pragma unroll
    for (int i = 0; i < 4; ++i) {
      float4 v0 = ((const float4*)g0)[i];
      float4 v1 = ((const float4*)g1)[i];
      float4 v2 = ((const float4*)g2)[i];
      uint2 u;
      u.x = cvt2(v0.x, v0.y); u.y = cvt2(v0.z, v0.w);
      *(uint2*)(row + i * 4) = u;
      u.x = cvt2(v1.x, v1.y); u.y = cvt2(v1.z, v1.w);
      *(uint2*)(row + 64 + i * 4) = u;
      u.x = cvt2(v2.x, v2.y); u.y = cvt2(v2.z, v2.w);
      *(uint2*)(row + 128 + i * 4) = u;
      *(float4*)&sE[t * SEB + p * 16 + i * 4] = v2;
    }
  }
  __syncthreads();
  f32x4 acc[4];
#pragma unroll
  for (int nt = 0; nt < 4; ++nt) {
    float b = b1[nt * 16 + ll];
    acc[nt].x = b; acc[nt].y = b; acc[nt].z = b; acc[nt].w = b;
  }
  {
    const unsigned short* aBase = sIN + (mt * 16 + ll) * SINB + hl * 8;
#pragma unroll
    for (int kk = 0; kk < 6; ++kk) {
      bf16x8 af = *(const bf16x8*)(aBase + kk * 32);
#pragma unroll
      for (int nt = 0; nt < 4; ++nt) {
        bf16x8 bf = *(const bf16x8*)(wB1 + ((size_t)(nt * 6 + kk) * 64 + lane) * 8);
        acc[nt] = __builtin_amdgcn_mfma_f32_16x16x32_bf16(af, bf, acc[nt], 0, 0, 0);
      }
    }
  }
#pragma unroll
  for (int nt = 0; nt < 4; ++nt)
#pragma unroll
    for (int r = 0; r < 4; ++r)
      sH[(mt * 16 + hl * 4 + r) * SHB + nt * 16 + ll] = f2bf(fmaxf(acc[nt][r], 0.f));
  __syncthreads();
  f32x4 acc2[4];
#pragma unroll
  for (int nt = 0; nt < 4; ++nt) {
    float b = b2[nt * 16 + ll];
    acc2[nt].x = b; acc2[nt].y = b; acc2[nt].z = b; acc2[nt].w = b;
  }
  {
    const unsigned short* hBase = sH + (mt * 16 + ll) * SHB + hl * 8;
#pragma unroll
    for (int kk = 0; kk < 2; ++kk) {
      bf16x8 af = *(const bf16x8*)(hBase + kk * 32);
#pragma unroll
      for (int nt = 0; nt < 4; ++nt) {
        bf16x8 bf = *(const bf16x8*)(wB2 + ((size_t)(nt * 2 + kk) * 64 + lane) * 8);
        acc2[nt] = __builtin_amdgcn_mfma_f32_16x16x32_bf16(af, bf, acc2[nt], 0, 0, 0);
      }
    }
  }
#pragma unroll
  for (int r = 0; r < 4; ++r) {
    int t = mt * 16 + hl * 4 + r;
    int eid = e0 + t;
    int sN = src[eid], dN = dst[eid];
    const float* xr = x + (size_t)sN * D;
    const float* er = &sE[t * SEB];
    float* ar = agg + (size_t)dN * D;
#pragma unroll
    for (int nt = 0; nt < 4; ++nt) {
      int j = nt * 16 + ll;
      atomicAdd(ar + j, fmaxf(xr[j] + fmaf(0.5f, acc2[nt][r], er[j]), 0.f));
    }
  }
}

// ---------------- head ----------------
__global__ __launch_bounds__(256) void head_kernel(
    const float* __restrict__ x, const float* __restrict__ w,
    const float* __restrict__ b, float* __restrict__ out) {
  int nid = blockIdx.x * blockDim.x + threadIdx.x;
  if (nid >= NN) return;
  const float* xr = x + (size_t)nid * D;
  float a0 = b[0], a1 = b[1];
  for (int k = 0; k < D; ++k) {
    float v = xr[k];
    a0 = fmaf(v, w[k * 2 + 0], a0);
    a1 = fmaf(v, w[k * 2 + 1], a1);
  }
  out[nid * 2 + 0] = a0;
  out[nid * 2 + 1] = a1;
}

extern "C" void kernel_launch(void* const* d_in, const int* in_sizes, int n_in,
                              void* d_out, int out_size, void* d_ws, size_t ws_size,
                              hipStream_t stream) {
  const float* x0  = (const float*)d_in[0];
  const float* e0  = (const float*)d_in[1];
  const int*   ei  = (const int*)d_in[2];
  const float* gw1 = (const float*)d_in[3];
  const float* gb1 = (const float*)d_in[4];
  const float* gw2 = (const float*)d_in[5];
  const float* gb2 = (const float*)d_in[6];
  const float* ew1 = (const float*)d_in[7];
  const float* eb1 = (const float*)d_in[8];
  const float* ew2 = (const float*)d_in[9];
  const float* eb2 = (const float*)d_in[10];
  const float* lng = (const float*)d_in[11];
  const float* lnb = (const float*)d_in[12];
  const float* hw  = (const float*)d_in[13];
  const float* hb  = (const float*)d_in[14];
  float* out = (float*)d_out;

  char* ws = (char*)d_ws;
  const size_t SZ_X     = (size_t)NN * D * 4;          // 12.8 MB
  const size_t OFF_X1   = 0;
  const size_t OFF_X2   = OFF_X1 + SZ_X;
  const size_t OFF_WB1  = OFF_X2 + SZ_X;
  const size_t OFF_WB2  = OFF_WB1 + 24576;
  const size_t OFF_DEG  = OFF_WB2 + 8192;
  const size_t OFF_OFFS = OFF_DEG + 200704;
  const size_t OFF_CUR  = OFF_OFFS + 200704;
  const size_t OFF_BSUM = OFF_CUR + 200704;
  const size_t OFF_EPAIR= OFF_BSUM + 512;
  const size_t OFF_MSG  = OFF_EPAIR + (size_t)NE * 8;
  const size_t NEED_A   = OFF_MSG + (size_t)NE * D * 2;  // ~134 MB

  float* x1   = (float*)(ws + OFF_X1);
  float* x2   = (float*)(ws + OFF_X2);
  unsigned short* wB1 = (unsigned short*)(ws + OFF_WB1);
  unsigned short* wB2 = (unsigned short*)(ws + OFF_WB2);
  int* deg  = (int*)(ws + OFF_DEG);
  int* offs = (int*)(ws + OFF_OFFS);
  int* cur  = (int*)(ws + OFF_CUR);
  int* bsum = (int*)(ws + OFF_BSUM);
  int2* epair = (int2*)(ws + OFF_EPAIR);
  unsigned short* msg = (unsigned short*)(ws + OFF_MSG);

  const int* src = ei;
  const int* dst = ei + NE;

  const int nodeBlocks = (NN + 63) / 64;     // 782
  const int edgeBlocks = NE / 64;            // 12500
  const int scanBlocks = (NN + 1023) / 1024; // 49

  pack_weights_kernel<<<8, 256, 0, stream>>>(ew1, ew2, wB1, wB2);

  if (ws_size >= NEED_A) {
    // ---- CSR build (by dst) ----
    hipMemsetAsync(deg, 0, (size_t)NN * 4, stream);
    count_kernel<<<(NE + 255) / 256, 256, 0, stream>>>(dst, deg);
    scan_reduce_kernel<<<scanBlocks, 1024, 0, stream>>>(deg, bsum);
    scan_final_kernel<<<scanBlocks, 1024, 0, stream>>>(deg, bsum, offs, cur);
    fill_kernel<<<(NE + 255) / 256, 256, 0, stream>>>(src, dst, cur, epair);

    // ---- layer 0: fused gather + node MLP ----
    node_mlp_g0_kernel<<<nodeBlocks, 512, 0, stream>>>(
        x0, e0, epair, offs, gw1, gb1, gw2, gb2, lng, lnb, x1);

    // ---- layer-0 edge update (MFMA) over CSR slots, bf16 msg ----
    edge_mfma_csr_kernel<<<edgeBlocks, 256, 0, stream>>>(
        x1, e0, epair, dst, wB1, eb1, wB2, eb2, msg);

    // ---- layer 1: fused streaming gather + node MLP ----
    node_mlp_g1_kernel<<<nodeBlocks, 512, 0, stream>>>(
        x1, msg, offs, gw1 + D * D, gb1 + D, gw2 + D * D, gb2 + D,
        lng + D, lnb + D, x2);
  } else {
    // ---- fallback: atomic path (no CSR) ----
    float* agg = (float*)(ws + OFF_EPAIR);
    hipMemsetAsync(agg, 0, SZ_X, stream);
    scatter_kernel<<<(NE * 16 + 255) / 256, 256, 0, stream>>>(x0, e0, src, dst, agg);
    node_mlp_kernel<<<nodeBlocks, 256, 0, stream>>>(
        x0, agg, gw1, gb1, gw2, gb2, lng, lnb, x1);
    hipMemsetAsync(agg, 0, SZ_X, stream);
    edge_mfma_atomic_kernel<<<edgeBlocks, 256, 0, stream>>>(
        x1, e0, src, dst, wB1, eb1, wB2, eb2, agg);
    node_mlp_kernel<<<nodeBlocks, 256, 0, stream>>>(
        x1, agg, gw1 + D * D, gb1 + D, gw2 + D * D, gb2 + D, lng + D, lnb + D, x2);
  }

  // ---- head ----
  head_kernel<<<(NN + 255) / 256, 256, 0, stream>>>(x2, hw, hb, out);
}

// Round 9
// 395.013 us; speedup vs baseline: 10.1207x; 1.1110x over previous
//
#include <hip/hip_runtime.h>
#include <hip/hip_bf16.h>

#define NN 50000
#define NE 800000
#define D 64
#define K3 (3 * D)
#define LNEPS 1e-5f
#define STR 68    // f32 LDS row stride (node kernels)
#define SINB 200  // bf16 LDS row stride, edge input tile
#define SHB 72    // bf16 LDS row stride, edge hidden tile
#define SEB 68    // f32 LDS row stride (fallback edge kernel)

typedef __attribute__((ext_vector_type(8))) short bf16x8;
typedef __attribute__((ext_vector_type(4))) float f32x4;

// hardware bf16 conversions (RNE)
__device__ __forceinline__ unsigned cvt2(float lo, float hi) {
  __hip_bfloat162 h = __float22bfloat162_rn(make_float2(lo, hi));
  return *(unsigned*)&h;
}
__device__ __forceinline__ unsigned short f2bf(float f) {
  __hip_bfloat16 h = __float2bfloat16(f);
  return *(unsigned short*)&h;
}
__device__ __forceinline__ float bf2f(unsigned short s) {
  return __uint_as_float((unsigned)s << 16);
}

#define FMA4x4(v, w)                                                  \
  a0.x = fmaf(v.x, w.x, a0.x); a0.y = fmaf(v.x, w.y, a0.y);           \
  a0.z = fmaf(v.x, w.z, a0.z); a0.w = fmaf(v.x, w.w, a0.w);           \
  a1.x = fmaf(v.y, w.x, a1.x); a1.y = fmaf(v.y, w.y, a1.y);           \
  a1.z = fmaf(v.y, w.z, a1.z); a1.w = fmaf(v.y, w.w, a1.w);           \
  a2.x = fmaf(v.z, w.x, a2.x); a2.y = fmaf(v.z, w.y, a2.y);           \
  a2.z = fmaf(v.z, w.z, a2.z); a2.w = fmaf(v.z, w.w, a2.w);           \
  a3.x = fmaf(v.w, w.x, a3.x); a3.y = fmaf(v.w, w.y, a3.y);           \
  a3.z = fmaf(v.w, w.z, a3.z); a3.w = fmaf(v.w, w.w, a3.w);

#define FMA2x4(v, w)                                                  \
  a0.x = fmaf(v.x, w.x, a0.x); a0.y = fmaf(v.x, w.y, a0.y);           \
  a0.z = fmaf(v.x, w.z, a0.z); a0.w = fmaf(v.x, w.w, a0.w);           \
  a1.x = fmaf(v.y, w.x, a1.x); a1.y = fmaf(v.y, w.y, a1.y);           \
  a1.z = fmaf(v.y, w.z, a1.z); a1.w = fmaf(v.y, w.w, a1.w);

#define HSTORE_RELU(buf)                                              \
  buf[(j0+0)*STR + t0+0] = fmaxf(a0.x, 0.f);                          \
  buf[(j0+1)*STR + t0+0] = fmaxf(a0.y, 0.f);                          \
  buf[(j0+2)*STR + t0+0] = fmaxf(a0.z, 0.f);                          \
  buf[(j0+3)*STR + t0+0] = fmaxf(a0.w, 0.f);                          \
  buf[(j0+0)*STR + t0+1] = fmaxf(a1.x, 0.f);                          \
  buf[(j0+1)*STR + t0+1] = fmaxf(a1.y, 0.f);                          \
  buf[(j0+2)*STR + t0+1] = fmaxf(a1.z, 0.f);                          \
  buf[(j0+3)*STR + t0+1] = fmaxf(a1.w, 0.f);                          \
  buf[(j0+0)*STR + t0+2] = fmaxf(a2.x, 0.f);                          \
  buf[(j0+1)*STR + t0+2] = fmaxf(a2.y, 0.f);                          \
  buf[(j0+2)*STR + t0+2] = fmaxf(a2.z, 0.f);                          \
  buf[(j0+3)*STR + t0+2] = fmaxf(a2.w, 0.f);                          \
  buf[(j0+0)*STR + t0+3] = fmaxf(a3.x, 0.f);                          \
  buf[(j0+1)*STR + t0+3] = fmaxf(a3.y, 0.f);                          \
  buf[(j0+2)*STR + t0+3] = fmaxf(a3.z, 0.f);                          \
  buf[(j0+3)*STR + t0+3] = fmaxf(a3.w, 0.f);

// ---------------- CSR build ----------------
__global__ __launch_bounds__(256) void count_kernel(
    const int* __restrict__ dst, int* __restrict__ deg) {
  int e = blockIdx.x * 256 + threadIdx.x;
  if (e < NE) atomicAdd(&deg[dst[e]], 1);
}

__global__ __launch_bounds__(1024) void scan_reduce_kernel(
    const int* __restrict__ deg, int* __restrict__ bsum) {
  __shared__ int sS[16];
  int i = blockIdx.x * 1024 + threadIdx.x;
  int v = (i < NN) ? deg[i] : 0;
#pragma unroll
  for (int o = 32; o > 0; o >>= 1) v += __shfl_down(v, o, 64);
  if ((threadIdx.x & 63) == 0) sS[threadIdx.x >> 6] = v;
  __syncthreads();
  if (threadIdx.x == 0) {
    int s = 0;
#pragma unroll
    for (int k = 0; k < 16; ++k) s += sS[k];
    bsum[blockIdx.x] = s;
  }
}

__global__ __launch_bounds__(1024) void scan_final_kernel(
    const int* __restrict__ deg, const int* __restrict__ bsum,
    int* __restrict__ off, int* __restrict__ cur) {
  __shared__ int sD[1024];
  __shared__ int sOfs;
  const int t = threadIdx.x;
  const int b = blockIdx.x;
  int i = b * 1024 + t;
  int v = (i < NN) ? deg[i] : 0;
  sD[t] = v;
  if (t == 0) {
    int o = 0;
    for (int k = 0; k < b; ++k) o += bsum[k];
    sOfs = o;
  }
  __syncthreads();
  for (int st = 1; st < 1024; st <<= 1) {
    int add = (t >= st) ? sD[t - st] : 0;
    __syncthreads();
    sD[t] += add;
    __syncthreads();
  }
  if (i < NN) {
    int excl = sOfs + sD[t] - v;
    off[i] = excl;
    cur[i] = excl;
    if (i == NN - 1) off[NN] = NE;
  }
}

// epair[p] = {eid, src[eid]}, dcsr[p] = dst[eid], CSR slot order
__global__ __launch_bounds__(256) void fill_kernel(
    const int* __restrict__ src, const int* __restrict__ dst,
    int* __restrict__ cur, int2* __restrict__ epair, int* __restrict__ dcsr) {
  int e = blockIdx.x * 256 + threadIdx.x;
  if (e < NE) {
    int d = dst[e];
    int p = atomicAdd(&cur[d], 1);
    epair[p] = make_int2(e, src[e]);
    dcsr[p] = d;
  }
}

// ---------------- pack edge-MLP weights into bf16 MFMA B-fragment order ----------------
__global__ __launch_bounds__(256) void pack_weights_kernel(
    const float* __restrict__ w1, const float* __restrict__ w2,
    unsigned short* __restrict__ wB1, unsigned short* __restrict__ wB2) {
  int tid = blockIdx.x * 256 + threadIdx.x;
  const float* wsrc;
  unsigned short* wdst;
  int kb, j, slot;
  if (tid < 1536) {
    int nt = tid / 384, kk = (tid / 64) % 6, l = tid & 63;
    kb = kk * 32 + (l >> 4) * 8;
    j = nt * 16 + (l & 15);
    wsrc = w1; wdst = wB1; slot = tid;
  } else {
    int t = tid - 1536;
    int nt = t / 128, kk = (t / 64) & 1, l = t & 63;
    kb = kk * 32 + (l >> 4) * 8;
    j = nt * 16 + (l & 15);
    wsrc = w2; wdst = wB2; slot = t;
  }
  unsigned short b[8];
#pragma unroll
  for (int i = 0; i < 8; ++i) b[i] = f2bf(wsrc[(kb + i) * D + j]);
  uint4 v;
  v.x = (unsigned)b[0] | ((unsigned)b[1] << 16);
  v.y = (unsigned)b[2] | ((unsigned)b[3] << 16);
  v.z = (unsigned)b[4] | ((unsigned)b[5] << 16);
  v.w = (unsigned)b[6] | ((unsigned)b[7] << 16);
  *(uint4*)(wdst + (size_t)slot * 8) = v;
}

// ---------------- 512-thread MLP tail (optional bf16 mirror output) ----------------
__device__ __forceinline__ void mlp_tail512(
    float* sIN, float* sH, float* sPS, float* sPQ, float* sMu, float* sRs,
    const float* __restrict__ w1, const float* __restrict__ b1,
    const float* __restrict__ w2, const float* __restrict__ b2,
    const float* __restrict__ g, const float* __restrict__ bln,
    float* __restrict__ xo, unsigned short* __restrict__ xob,
    int n0, int tid) {
  __syncthreads();
  const int tj = tid & 15, tt = tid >> 4;   // 16 x 32
  const int j0 = tj * 4, t0 = tt * 2;
  float4 a0, a1;

  {
    float4 bv = *(const float4*)(b1 + j0);
    a0 = a1 = bv;
    for (int k = 0; k < D; ++k) {
      float4 w = *(const float4*)(w1 + k * D + j0);
      float2 v = *(const float2*)&sIN[k * STR + t0];
      FMA2x4(v, w)
    }
  }
  sH[(j0 + 0) * STR + t0 + 0] = fmaxf(a0.x, 0.f);
  sH[(j0 + 1) * STR + t0 + 0] = fmaxf(a0.y, 0.f);
  sH[(j0 + 2) * STR + t0 + 0] = fmaxf(a0.z, 0.f);
  sH[(j0 + 3) * STR + t0 + 0] = fmaxf(a0.w, 0.f);
  sH[(j0 + 0) * STR + t0 + 1] = fmaxf(a1.x, 0.f);
  sH[(j0 + 1) * STR + t0 + 1] = fmaxf(a1.y, 0.f);
  sH[(j0 + 2) * STR + t0 + 1] = fmaxf(a1.z, 0.f);
  sH[(j0 + 3) * STR + t0 + 1] = fmaxf(a1.w, 0.f);
  __syncthreads();

  {
    float4 bv = *(const float4*)(b2 + j0);
    a0 = a1 = bv;
    for (int k = 0; k < D; ++k) {
      float4 w = *(const float4*)(w2 + k * D + j0);
      float2 v = *(const float2*)&sH[k * STR + t0];
      FMA2x4(v, w)
    }
  }
  __syncthreads();
  *(float4*)&sH[(t0 + 0) * STR + j0] = a0;
  *(float4*)&sH[(t0 + 1) * STR + j0] = a1;
  __syncthreads();

  {
    const int t = tid & 63, p = tid >> 6;
    const float* r = &sH[t * STR + p * 8];
    float s = 0.f, q = 0.f;
#pragma unroll
    for (int i = 0; i < 8; ++i) { float v = r[i]; s += v; q = fmaf(v, v, q); }
    sPS[p * 64 + t] = s;
    sPQ[p * 64 + t] = q;
  }
  __syncthreads();
  if (tid < 64) {
    float s = 0.f, q = 0.f;
#pragma unroll
    for (int p = 0; p < 8; ++p) { s += sPS[p * 64 + tid]; q += sPQ[p * 64 + tid]; }
    float mu = s * (1.f / 64.f);
    float var = q * (1.f / 64.f) - mu * mu;
    sMu[tid] = mu;
    sRs[tid] = rsqrtf(var + LNEPS);
  }
  __syncthreads();

  {
    const int t = tid >> 3, c = (tid & 7) * 8;
    int node = n0 + t;
    if (node < NN) {
      float mu = sMu[t], rs = sRs[t];
      float* o = xo + (size_t)node * D + c;
      float4 v0 = *(const float4*)&sH[t * STR + c + 0];
      float4 v1 = *(const float4*)&sH[t * STR + c + 4];
      float4 g0v = *(const float4*)(g + c + 0);
      float4 g1v = *(const float4*)(g + c + 4);
      float4 b0v = *(const float4*)(bln + c + 0);
      float4 b1v = *(const float4*)(bln + c + 4);
      float4 r0, r1;
      r0.x = fmaxf(fmaf((v0.x - mu) * rs, g0v.x, b0v.x), 0.f);
      r0.y = fmaxf(fmaf((v0.y - mu) * rs, g0v.y, b0v.y), 0.f);
      r0.z = fmaxf(fmaf((v0.z - mu) * rs, g0v.z, b0v.z), 0.f);
      r0.w = fmaxf(fmaf((v0.w - mu) * rs, g0v.w, b0v.w), 0.f);
      r1.x = fmaxf(fmaf((v1.x - mu) * rs, g1v.x, b1v.x), 0.f);
      r1.y = fmaxf(fmaf((v1.y - mu) * rs, g1v.y, b1v.y), 0.f);
      r1.z = fmaxf(fmaf((v1.z - mu) * rs, g1v.z, b1v.z), 0.f);
      r1.w = fmaxf(fmaf((v1.w - mu) * rs, g1v.w, b1v.w), 0.f);
      ((float4*)o)[0] = r0;
      ((float4*)o)[1] = r1;
      if (xob) {
        uint4 u;
        u.x = cvt2(r0.x, r0.y); u.y = cvt2(r0.z, r0.w);
        u.z = cvt2(r1.x, r1.y); u.w = cvt2(r1.z, r1.w);
        *(uint4*)(xob + (size_t)node * D + c) = u;
      }
    }
  }
}

// ---------------- layer-0: fused CSR gather + node MLP; also emits ecsr + x1b ----------------
__global__ __launch_bounds__(512) void node_mlp_g0_kernel(
    const float* __restrict__ x, const float* __restrict__ e,
    const int2* __restrict__ epair, const int* __restrict__ off,
    const float* __restrict__ w1, const float* __restrict__ b1,
    const float* __restrict__ w2, const float* __restrict__ b2,
    const float* __restrict__ g, const float* __restrict__ bln,
    float* __restrict__ xo, unsigned short* __restrict__ xob,
    unsigned short* __restrict__ ecsr) {
  __shared__ float sIN[D * STR];
  __shared__ float sH[D * STR];
  __shared__ float sPS[512], sPQ[512], sMu[64], sRs[64];
  const int tid = threadIdx.x;
  const int n0 = blockIdx.x * 64;
  const int wv = tid >> 6, lane = tid & 63;
  for (int q = 0; q < 8; ++q) {
    int t = wv * 8 + q;
    int node = n0 + t;
    float acc = 0.f;
    if (node < NN) {
      acc = x[(size_t)node * D + lane];  // self term
      int beg = off[node], end = off[node + 1];
      int i = beg;
      for (; i + 3 < end; i += 4) {
        int2 pa = epair[i],     pb = epair[i + 1];
        int2 pc = epair[i + 2], pd = epair[i + 3];
        float xa = x[(size_t)pa.y * D + lane];
        float va = e[(size_t)pa.x * D + lane];
        float xb = x[(size_t)pb.y * D + lane];
        float vb = e[(size_t)pb.x * D + lane];
        float xc = x[(size_t)pc.y * D + lane];
        float vc = e[(size_t)pc.x * D + lane];
        float xd = x[(size_t)pd.y * D + lane];
        float vd = e[(size_t)pd.x * D + lane];
        ecsr[(size_t)(i + 0) * D + lane] = f2bf(va);
        ecsr[(size_t)(i + 1) * D + lane] = f2bf(vb);
        ecsr[(size_t)(i + 2) * D + lane] = f2bf(vc);
        ecsr[(size_t)(i + 3) * D + lane] = f2bf(vd);
        acc += (fmaxf(xa + va, 0.f) + fmaxf(xb + vb, 0.f)) +
               (fmaxf(xc + vc, 0.f) + fmaxf(xd + vd, 0.f));
      }
      for (; i < end; ++i) {
        int2 pa = epair[i];
        float va = e[(size_t)pa.x * D + lane];
        ecsr[(size_t)i * D + lane] = f2bf(va);
        acc += fmaxf(x[(size_t)pa.y * D + lane] + va, 0.f);
      }
    }
    sIN[lane * STR + t] = acc;
  }
  mlp_tail512(sIN, sH, sPS, sPQ, sMu, sRs, w1, b1, w2, b2, g, bln, xo, xob, n0, tid);
}

// ---------------- layer-1: fused streaming gather (bf16 msg) + node MLP ----------------
__global__ __launch_bounds__(512) void node_mlp_g1_kernel(
    const float* __restrict__ x, const unsigned short* __restrict__ msg,
    const int* __restrict__ off,
    const float* __restrict__ w1, const float* __restrict__ b1,
    const float* __restrict__ w2, const float* __restrict__ b2,
    const float* __restrict__ g, const float* __restrict__ bln,
    float* __restrict__ xo) {
  __shared__ float sIN[D * STR];
  __shared__ float sH[D * STR];
  __shared__ float sPS[512], sPQ[512], sMu[64], sRs[64];
  const int tid = threadIdx.x;
  const int n0 = blockIdx.x * 64;
  const int wv = tid >> 6, lane = tid & 63;
  for (int q = 0; q < 8; ++q) {
    int t = wv * 8 + q;
    int node = n0 + t;
    float acc = 0.f;
    if (node < NN) {
      acc = x[(size_t)node * D + lane];
      int beg = off[node], end = off[node + 1];
      const unsigned short* mr = msg + (size_t)beg * D + lane;
      int cnt = end - beg, i = 0;
      for (; i + 7 < cnt; i += 8) {
        float m0 = bf2f(mr[(size_t)(i + 0) * D]);
        float m1 = bf2f(mr[(size_t)(i + 1) * D]);
        float m2 = bf2f(mr[(size_t)(i + 2) * D]);
        float m3 = bf2f(mr[(size_t)(i + 3) * D]);
        float m4 = bf2f(mr[(size_t)(i + 4) * D]);
        float m5 = bf2f(mr[(size_t)(i + 5) * D]);
        float m6 = bf2f(mr[(size_t)(i + 6) * D]);
        float m7 = bf2f(mr[(size_t)(i + 7) * D]);
        acc += ((m0 + m1) + (m2 + m3)) + ((m4 + m5) + (m6 + m7));
      }
      for (; i < cnt; ++i) acc += bf2f(mr[(size_t)i * D]);
    }
    sIN[lane * STR + t] = acc;
  }
  mlp_tail512(sIN, sH, sPS, sPQ, sMu, sRs, w1, b1, w2, b2, g, bln, xo, nullptr, n0, tid);
}

// ---------------- MFMA edge MLP over CSR slots; pure bf16-copy stage ----------------
__global__ __launch_bounds__(256) void edge_mfma_csr_kernel(
    const unsigned short* __restrict__ x1b, const unsigned short* __restrict__ ecsr,
    const int2* __restrict__ epair, const int* __restrict__ dcsr,
    const unsigned short* __restrict__ wB1, const float* __restrict__ b1,
    const unsigned short* __restrict__ wB2, const float* __restrict__ b2,
    unsigned short* __restrict__ msg) {
  __shared__ unsigned short sIN[64 * SINB];  // 25600 B: bf16 cat inputs [t][k]
  __shared__ unsigned short sH[64 * SHB];    //  9216 B: bf16 relu(h) [t][k2]

  const int tid = threadIdx.x;
  const int e0 = blockIdx.x * 64;  // CSR slot base
  const int lane = tid & 63;
  const int mt = tid >> 6;
  const int hl = lane >> 4;
  const int ll = lane & 15;

  // ---- stage: pure 16B copies, no conversion
  {
    const int t = tid & 63, p = tid >> 6;
    int slot = e0 + t;
    int sN = epair[slot].y;
    int dN = dcsr[slot];
    const uint4* xs = (const uint4*)(x1b + (size_t)sN * D + p * 16);
    const uint4* xd = (const uint4*)(x1b + (size_t)dN * D + p * 16);
    const uint4* ec = (const uint4*)(ecsr + (size_t)slot * D + p * 16);
    uint4* r0 = (uint4*)(sIN + t * SINB + p * 16);
    uint4* r1 = (uint4*)(sIN + t * SINB + 64 + p * 16);
    uint4* r2 = (uint4*)(sIN + t * SINB + 128 + p * 16);
    uint4 a0v = xs[0], a1v = xs[1];
    uint4 b0v = xd[0], b1v = xd[1];
    uint4 c0v = ec[0], c1v = ec[1];
    r0[0] = a0v; r0[1] = a1v;
    r1[0] = b0v; r1[1] = b1v;
    r2[0] = c0v; r2[1] = c1v;
  }
  __syncthreads();

  f32x4 acc[4];
#pragma unroll
  for (int nt = 0; nt < 4; ++nt) {
    float b = b1[nt * 16 + ll];
    acc[nt].x = b; acc[nt].y = b; acc[nt].z = b; acc[nt].w = b;
  }
  {
    const unsigned short* aBase = sIN + (mt * 16 + ll) * SINB + hl * 8;
#pragma unroll
    for (int kk = 0; kk < 6; ++kk) {
      bf16x8 af = *(const bf16x8*)(aBase + kk * 32);
#pragma unroll
      for (int nt = 0; nt < 4; ++nt) {
        bf16x8 bf = *(const bf16x8*)(wB1 + ((size_t)(nt * 6 + kk) * 64 + lane) * 8);
        acc[nt] = __builtin_amdgcn_mfma_f32_16x16x32_bf16(af, bf, acc[nt], 0, 0, 0);
      }
    }
  }
#pragma unroll
  for (int nt = 0; nt < 4; ++nt)
#pragma unroll
    for (int r = 0; r < 4; ++r)
      sH[(mt * 16 + hl * 4 + r) * SHB + nt * 16 + ll] = f2bf(fmaxf(acc[nt][r], 0.f));
  __syncthreads();

  f32x4 acc2[4];
#pragma unroll
  for (int nt = 0; nt < 4; ++nt) {
    float b = b2[nt * 16 + ll];
    acc2[nt].x = b; acc2[nt].y = b; acc2[nt].z = b; acc2[nt].w = b;
  }
  {
    const unsigned short* hBase = sH + (mt * 16 + ll) * SHB + hl * 8;
#pragma unroll
    for (int kk = 0; kk < 2; ++kk) {
      bf16x8 af = *(const bf16x8*)(hBase + kk * 32);
#pragma unroll
      for (int nt = 0; nt < 4; ++nt) {
        bf16x8 bf = *(const bf16x8*)(wB2 + ((size_t)(nt * 2 + kk) * 64 + lane) * 8);
        acc2[nt] = __builtin_amdgcn_mfma_f32_16x16x32_bf16(af, bf, acc2[nt], 0, 0, 0);
      }
    }
  }

  // epilogue: msg = relu(x[src] + e + 0.5*o); x,e read back as bf16 from sIN
#pragma unroll
  for (int r = 0; r < 4; ++r) {
    int t = mt * 16 + hl * 4 + r;
    int slot = e0 + t;
    const unsigned short* xr = sIN + t * SINB;        // bf16 x[src], cols 0..63
    const unsigned short* er = sIN + t * SINB + 128;  // bf16 e, cols 128..191
    unsigned short* mr = msg + (size_t)slot * D;
#pragma unroll
    for (int nt = 0; nt < 4; ++nt) {
      int j = nt * 16 + ll;
      float xf = bf2f(xr[j]);
      float ef = bf2f(er[j]);
      mr[j] = f2bf(fmaxf(xf + fmaf(0.5f, acc2[nt][r], ef), 0.f));
    }
  }
}

// ---------------- legacy kernels (fallback tier) ----------------
__global__ __launch_bounds__(256) void scatter_kernel(
    const float* __restrict__ x, const float* __restrict__ e,
    const int* __restrict__ src, const int* __restrict__ dst,
    float* __restrict__ agg) {
  int tid = blockIdx.x * blockDim.x + threadIdx.x;
  if (tid >= NE * 16) return;
  int eid = tid >> 4, q = tid & 15;
  int s = src[eid], d = dst[eid];
  float4 xv = ((const float4*)(x + (size_t)s * D))[q];
  float4 ev = ((const float4*)(e + (size_t)eid * D))[q];
  float* a = agg + (size_t)d * D + q * 4;
  atomicAdd(a + 0, fmaxf(xv.x + ev.x, 0.f));
  atomicAdd(a + 1, fmaxf(xv.y + ev.y, 0.f));
  atomicAdd(a + 2, fmaxf(xv.z + ev.z, 0.f));
  atomicAdd(a + 3, fmaxf(xv.w + ev.w, 0.f));
}

__device__ __forceinline__ void mlp_tail256(
    float* sIN, float* sH, float* sPS, float* sPQ, float* sMu, float* sRs,
    const float* __restrict__ w1, const float* __restrict__ b1,
    const float* __restrict__ w2, const float* __restrict__ b2,
    const float* __restrict__ g, const float* __restrict__ bln,
    float* __restrict__ xo, int n0, int tid) {
  __syncthreads();
  const int tj = tid & 15, tt = tid >> 4;
  const int j0 = tj * 4, t0 = tt * 4;
  float4 a0, a1, a2, a3;
  {
    float4 bv = *(const float4*)(b1 + j0);
    a0 = a1 = a2 = a3 = bv;
    for (int k = 0; k < D; ++k) {
      float4 w = *(const float4*)(w1 + k * D + j0);
      float4 v = *(const float4*)&sIN[k * STR + t0];
      FMA4x4(v, w)
    }
  }
  HSTORE_RELU(sH)
  __syncthreads();
  {
    float4 bv = *(const float4*)(b2 + j0);
    a0 = a1 = a2 = a3 = bv;
    for (int k = 0; k < D; ++k) {
      float4 w = *(const float4*)(w2 + k * D + j0);
      float4 v = *(const float4*)&sH[k * STR + t0];
      FMA4x4(v, w)
    }
  }
  __syncthreads();
  *(float4*)&sH[(t0 + 0) * STR + j0] = a0;
  *(float4*)&sH[(t0 + 1) * STR + j0] = a1;
  *(float4*)&sH[(t0 + 2) * STR + j0] = a2;
  *(float4*)&sH[(t0 + 3) * STR + j0] = a3;
  __syncthreads();
  {
    const int t = tid & 63, p = tid >> 6;
    const float* r = &sH[t * STR + p * 16];
    float s = 0.f, q = 0.f;
#pragma unroll
    for (int i = 0; i < 16; ++i) { float v = r[i]; s += v; q = fmaf(v, v, q); }
    sPS[p * 64 + t] = s;
    sPQ[p * 64 + t] = q;
  }
  __syncthreads();
  if (tid < 64) {
    float s = sPS[tid] + sPS[64 + tid] + sPS[128 + tid] + sPS[192 + tid];
    float q = sPQ[tid] + sPQ[64 + tid] + sPQ[128 + tid] + sPQ[192 + tid];
    float mu = s * (1.f / 64.f);
    float var = q * (1.f / 64.f) - mu * mu;
    sMu[tid] = mu;
    sRs[tid] = rsqrtf(var + LNEPS);
  }
  __syncthreads();
  {
    const int t = tid >> 2, c = (tid & 3) * 16;
    int node = n0 + t;
    if (node < NN) {
      float mu = sMu[t], rs = sRs[t];
      float* o = xo + (size_t)node * D + c;
#pragma unroll
      for (int i = 0; i < 4; ++i) {
        float4 v = *(const float4*)&sH[t * STR + c + i * 4];
        float4 gv = *(const float4*)(g + c + i * 4);
        float4 bv = *(const float4*)(bln + c + i * 4);
        float4 r;
        r.x = fmaxf(fmaf((v.x - mu) * rs, gv.x, bv.x), 0.f);
        r.y = fmaxf(fmaf((v.y - mu) * rs, gv.y, bv.y), 0.f);
        r.z = fmaxf(fmaf((v.z - mu) * rs, gv.z, bv.z), 0.f);
        r.w = fmaxf(fmaf((v.w - mu) * rs, gv.w, bv.w), 0.f);
        ((float4*)o)[i] = r;
      }
    }
  }
}

__global__ __launch_bounds__(256) void node_mlp_kernel(
    const float* __restrict__ x, const float* __restrict__ agg,
    const float* __restrict__ w1, const float* __restrict__ b1,
    const float* __restrict__ w2, const float* __restrict__ b2,
    const float* __restrict__ g, const float* __restrict__ bln,
    float* __restrict__ xo) {
  __shared__ float sIN[D * STR];
  __shared__ float sH[D * STR];
  __shared__ float sPS[256], sPQ[256], sMu[64], sRs[64];
  const int tid = threadIdx.x;
  const int n0 = blockIdx.x * 64;
  {
    const int t = tid & 63, p = tid >> 6;
    int node = n0 + t;
    int cn = node < NN ? node : 0;
    const float* xr = x + (size_t)cn * D + p * 16;
    const float* ar = agg + (size_t)cn * D + p * 16;
#pragma unroll
    for (int i = 0; i < 4; ++i) {
      float4 xv = ((const float4*)xr)[i];
      float4 av = ((const float4*)ar)[i];
      int k = p * 16 + i * 4;
      sIN[(k + 0) * STR + t] = xv.x + av.x;
      sIN[(k + 1) * STR + t] = xv.y + av.y;
      sIN[(k + 2) * STR + t] = xv.z + av.z;
      sIN[(k + 3) * STR + t] = xv.w + av.w;
    }
  }
  mlp_tail256(sIN, sH, sPS, sPQ, sMu, sRs, w1, b1, w2, b2, g, bln, xo, n0, tid);
}

__global__ __launch_bounds__(256) void edge_mfma_atomic_kernel(
    const float* __restrict__ x, const float* __restrict__ e,
    const int* __restrict__ src, const int* __restrict__ dst,
    const unsigned short* __restrict__ wB1, const float* __restrict__ b1,
    const unsigned short* __restrict__ wB2, const float* __restrict__ b2,
    float* __restrict__ agg) {
  __shared__ unsigned short sIN[64 * SINB];
  __shared__ unsigned short sH[64 * SHB];
  __shared__ float sE[64 * SEB];
  const int tid = threadIdx.x;
  const int e0 = blockIdx.x * 64;
  const int lane = tid & 63;
  const int mt = tid >> 6;
  const int hl = lane >> 4;
  const int ll = lane & 15;
  {
    const int t = tid & 63, p = tid >> 6;
    int eid = e0 + t;
    int sN = src[eid], dN = dst[eid];
    const float* g0 = x + (size_t)sN * D + p * 16;
    const float* g1 = x + (size_t)dN * D + p * 16;
    const float* g2 = e + (size_t)eid * D + p * 16;
    unsigned short* row = sIN + t * SINB + p * 16;
#pragma unroll
    for (int i = 0; i < 4; ++i) {
      float4 v0 = ((const float4*)g0)[i];
      float4 v1 = ((const float4*)g1)[i];
      float4 v2 = ((const float4*)g2)[i];
      uint2 u;
      u.x = cvt2(v0.x, v0.y); u.y = cvt2(v0.z, v0.w);
      *(uint2*)(row + i * 4) = u;
      u.x = cvt2(v1.x, v1.y); u.y = cvt2(v1.z, v1.w);
      *(uint2*)(row + 64 + i * 4) = u;
      u.x = cvt2(v2.x, v2.y); u.y = cvt2(v2.z, v2.w);
      *(uint2*)(row + 128 + i * 4) = u;
      *(float4*)&sE[t * SEB + p * 16 + i * 4] = v2;
    }
  }
  __syncthreads();
  f32x4 acc[4];
#pragma unroll
  for (int nt = 0; nt < 4; ++nt) {
    float b = b1[nt * 16 + ll];
    acc[nt].x = b; acc[nt].y = b; acc[nt].z = b; acc[nt].w = b;
  }
  {
    const unsigned short* aBase = sIN + (mt * 16 + ll) * SINB + hl * 8;
#pragma unroll
    for (int kk = 0; kk < 6; ++kk) {
      bf16x8 af = *(const bf16x8*)(aBase + kk * 32);
#pragma unroll
      for (int nt = 0; nt < 4; ++nt) {
        bf16x8 bf = *(const bf16x8*)(wB1 + ((size_t)(nt * 6 + kk) * 64 + lane) * 8);
        acc[nt] = __builtin_amdgcn_mfma_f32_16x16x32_bf16(af, bf, acc[nt], 0, 0, 0);
      }
    }
  }
#pragma unroll
  for (int nt = 0; nt < 4; ++nt)
#pragma unroll
    for (int r = 0; r < 4; ++r)
      sH[(mt * 16 + hl * 4 + r) * SHB + nt * 16 + ll] = f2bf(fmaxf(acc[nt][r], 0.f));
  __syncthreads();
  f32x4 acc2[4];
#pragma unroll
  for (int nt = 0; nt < 4; ++nt) {
    float b = b2[nt * 16 + ll];
    acc2[nt].x = b; acc2[nt].y = b; acc2[nt].z = b; acc2[nt].w = b;
  }
  {
    const unsigned short* hBase = sH + (mt * 16 + ll) * SHB + hl * 8;
#pragma unroll
    for (int kk = 0; kk < 2; ++kk) {
      bf16x8 af = *(const bf16x8*)(hBase + kk * 32);
#pragma unroll
      for (int nt = 0; nt < 4; ++nt) {
        bf16x8 bf = *(const bf16x8*)(wB2 + ((size_t)(nt * 2 + kk) * 64 + lane) * 8);
        acc2[nt] = __builtin_amdgcn_mfma_f32_16x16x32_bf16(af, bf, acc2[nt], 0, 0, 0);
      }
    }
  }
#pragma unroll
  for (int r = 0; r < 4; ++r) {
    int t = mt * 16 + hl * 4 + r;
    int eid = e0 + t;
    int sN = src[eid], dN = dst[eid];
    const float* xr = x + (size_t)sN * D;
    const float* er = &sE[t * SEB];
    float* ar = agg + (size_t)dN * D;
#pragma unroll
    for (int nt = 0; nt < 4; ++nt) {
      int j = nt * 16 + ll;
      atomicAdd(ar + j, fmaxf(xr[j] + fmaf(0.5f, acc2[nt][r], er[j]), 0.f));
    }
  }
}

// ---------------- head ----------------
__global__ __launch_bounds__(256) void head_kernel(
    const float* __restrict__ x, const float* __restrict__ w,
    const float* __restrict__ b, float* __restrict__ out) {
  int nid = blockIdx.x * blockDim.x + threadIdx.x;
  if (nid >= NN) return;
  const float* xr = x + (size_t)nid * D;
  float a0 = b[0], a1 = b[1];
  for (int k = 0; k < D; ++k) {
    float v = xr[k];
    a0 = fmaf(v, w[k * 2 + 0], a0);
    a1 = fmaf(v, w[k * 2 + 1], a1);
  }
  out[nid * 2 + 0] = a0;
  out[nid * 2 + 1] = a1;
}

extern "C" void kernel_launch(void* const* d_in, const int* in_sizes, int n_in,
                              void* d_out, int out_size, void* d_ws, size_t ws_size,
                              hipStream_t stream) {
  const float* x0  = (const float*)d_in[0];
  const float* e0  = (const float*)d_in[1];
  const int*   ei  = (const int*)d_in[2];
  const float* gw1 = (const float*)d_in[3];
  const float* gb1 = (const float*)d_in[4];
  const float* gw2 = (const float*)d_in[5];
  const float* gb2 = (const float*)d_in[6];
  const float* ew1 = (const float*)d_in[7];
  const float* eb1 = (const float*)d_in[8];
  const float* ew2 = (const float*)d_in[9];
  const float* eb2 = (const float*)d_in[10];
  const float* lng = (const float*)d_in[11];
  const float* lnb = (const float*)d_in[12];
  const float* hw  = (const float*)d_in[13];
  const float* hb  = (const float*)d_in[14];
  float* out = (float*)d_out;

  char* ws = (char*)d_ws;
  const size_t SZ_X     = (size_t)NN * D * 4;             // 12.8 MB
  const size_t OFF_X1   = 0;
  const size_t OFF_WB1  = OFF_X1 + SZ_X;
  const size_t OFF_WB2  = OFF_WB1 + 24576;
  const size_t OFF_DEG  = OFF_WB2 + 8192;
  const size_t OFF_OFFS = OFF_DEG + 200704;
  const size_t OFF_CUR  = OFF_OFFS + 200704;
  const size_t OFF_BSUM = OFF_CUR + 200704;
  const size_t OFF_EPAIR= OFF_BSUM + 512;                 // 6.4 MB
  const size_t OFF_DCSR = OFF_EPAIR + (size_t)NE * 8;     // 3.2 MB
  const size_t OFF_X1B  = OFF_DCSR + (size_t)NE * 4;      // 6.4 MB
  const size_t OFF_ECSR = OFF_X1B + (size_t)NN * D * 2;   // 102.4 MB
  const size_t OFF_X2   = OFF_ECSR;                       // aliased into dead ecsr
  const size_t OFF_MSG  = OFF_ECSR + (size_t)NE * D * 2;  // 102.4 MB
  const size_t NEED_A   = OFF_MSG + (size_t)NE * D * 2;   // ~234 MB

  float* x1   = (float*)(ws + OFF_X1);
  unsigned short* wB1 = (unsigned short*)(ws + OFF_WB1);
  unsigned short* wB2 = (unsigned short*)(ws + OFF_WB2);
  int* deg  = (int*)(ws + OFF_DEG);
  int* offs = (int*)(ws + OFF_OFFS);
  int* cur  = (int*)(ws + OFF_CUR);
  int* bsum = (int*)(ws + OFF_BSUM);
  int2* epair = (int2*)(ws + OFF_EPAIR);
  int* dcsr = (int*)(ws + OFF_DCSR);
  unsigned short* x1b  = (unsigned short*)(ws + OFF_X1B);
  unsigned short* ecsr = (unsigned short*)(ws + OFF_ECSR);
  unsigned short* msg  = (unsigned short*)(ws + OFF_MSG);

  const int* src = ei;
  const int* dst = ei + NE;

  const int nodeBlocks = (NN + 63) / 64;     // 782
  const int edgeBlocks = NE / 64;            // 12500
  const int scanBlocks = (NN + 1023) / 1024; // 49

  pack_weights_kernel<<<8, 256, 0, stream>>>(ew1, ew2, wB1, wB2);

  if (ws_size >= NEED_A) {
    float* x2 = (float*)(ws + OFF_X2);
    // ---- CSR build (by dst) ----
    hipMemsetAsync(deg, 0, (size_t)NN * 4, stream);
    count_kernel<<<(NE + 255) / 256, 256, 0, stream>>>(dst, deg);
    scan_reduce_kernel<<<scanBlocks, 1024, 0, stream>>>(deg, bsum);
    scan_final_kernel<<<scanBlocks, 1024, 0, stream>>>(deg, bsum, offs, cur);
    fill_kernel<<<(NE + 255) / 256, 256, 0, stream>>>(src, dst, cur, epair, dcsr);

    // ---- layer 0: fused gather + node MLP; emits ecsr (bf16, CSR order) + x1b ----
    node_mlp_g0_kernel<<<nodeBlocks, 512, 0, stream>>>(
        x0, e0, epair, offs, gw1, gb1, gw2, gb2, lng, lnb, x1, x1b, ecsr);

    // ---- layer-0 edge update (MFMA), pure-streaming stage, bf16 msg ----
    edge_mfma_csr_kernel<<<edgeBlocks, 256, 0, stream>>>(
        x1b, ecsr, epair, dcsr, wB1, eb1, wB2, eb2, msg);

    // ---- layer 1: fused streaming gather + node MLP ----
    node_mlp_g1_kernel<<<nodeBlocks, 512, 0, stream>>>(
        x1, msg, offs, gw1 + D * D, gb1 + D, gw2 + D * D, gb2 + D,
        lng + D, lnb + D, x2);

    // ---- head ----
    head_kernel<<<(NN + 255) / 256, 256, 0, stream>>>(x2, hw, hb, out);
  } else {
    // ---- fallback: atomic path (no CSR) ----
    float* agg = (float*)(ws + OFF_EPAIR);
    float* x2  = (float*)(ws + OFF_EPAIR + SZ_X);
    hipMemsetAsync(agg, 0, SZ_X, stream);
    scatter_kernel<<<(NE * 16 + 255) / 256, 256, 0, stream>>>(x0, e0, src, dst, agg);
    node_mlp_kernel<<<nodeBlocks, 256, 0, stream>>>(
        x0, agg, gw1, gb1, gw2, gb2, lng, lnb, x1);
    hipMemsetAsync(agg, 0, SZ_X, stream);
    edge_mfma_atomic_kernel<<<edgeBlocks, 256, 0, stream>>>(
        x1, e0, src, dst, wB1, eb1, wB2, eb2, agg);
    node_mlp_kernel<<<nodeBlocks, 256, 0, stream>>>(
        x1, agg, gw1 + D * D, gb1 + D, gw2 + D * D, gb2 + D, lng + D, lnb + D, x2);
    head_kernel<<<(NN + 255) / 256, 256, 0, stream>>>(x2, hw, hb, out);
  }
}